// Round 11
// baseline (1719.874 us; speedup 1.0000x reference)
//
#include <hip/hip_runtime.h>

#define N_NODES 25600
#define N_EDGES 409600
#define BGR 128
#define EFE 1024
#define DIM 128
#define NLAYERS 8
#define KPOOL 32
#define NPG 200

typedef unsigned short ushort_t;
typedef __attribute__((ext_vector_type(8))) short bf16x8;
typedef __attribute__((ext_vector_type(4))) float f32x4;

#define STG_S 144  // per-wave C-staging stride (bf16 elems)

__device__ __forceinline__ float b2f(ushort_t v) {
    return __uint_as_float(((unsigned int)v) << 16);
}
__device__ __forceinline__ float blo(unsigned int u) {
    return __uint_as_float(u << 16);
}
__device__ __forceinline__ float bhi(unsigned int u) {
    return __uint_as_float(u & 0xffff0000u);
}
__device__ __forceinline__ ushort_t f2b(float f) {
    unsigned int u = __float_as_uint(f);
    unsigned int r = (u + 0x7fffu + ((u >> 16) & 1u)) >> 16;
    return (ushort_t)r;
}
__device__ __forceinline__ uint2 pack4(float4 v) {
    uint2 p;
    p.x = (unsigned int)f2b(v.x) | ((unsigned int)f2b(v.y) << 16);
    p.y = (unsigned int)f2b(v.z) | ((unsigned int)f2b(v.w) << 16);
    return p;
}

// ---------------- W_fij -> fragment-linear bf16 (proven R6) ----------------
__global__ void wfprep(const float* __restrict__ W, ushort_t* __restrict__ Wf) {
    int idx = blockIdx.x * 256 + threadIdx.x;  // 8 * 16384
    int l = idx >> 14, rem = idx & 16383;
    int j = rem & 7, lane = (rem >> 3) & 63, nt = (rem >> 9) & 7, kc = rem >> 12;
    int q = lane >> 4, r = lane & 15;
    int k = kc * 32 + q * 8 + j, n = nt * 16 + r;
    Wf[idx] = f2b(W[l * 16384 + k * 128 + n]);
}

// W_ni / W_nj / W_node -> fragment-linear bf16, layout [m][l][16384]
__global__ void wnprep(const float* __restrict__ Wni, const float* __restrict__ Wnj,
                       const float* __restrict__ Wnode, ushort_t* __restrict__ Wn) {
    int idx = blockIdx.x * 256 + threadIdx.x;  // 3 * 8 * 16384
    int m = idx >> 17;
    int l = (idx >> 14) & 7;
    int rem = idx & 16383;
    int j = rem & 7, lane = (rem >> 3) & 63, nt = (rem >> 9) & 7, kc = rem >> 12;
    int q = lane >> 4, r = lane & 15;
    int k = kc * 32 + q * 8 + j, n = nt * 16 + r;
    const float* W = (m == 0) ? Wni : (m == 1) ? Wnj : Wnode;
    Wn[idx] = f2b(W[l * 16384 + k * 128 + n]);
}

// ---------------- zero deg ----------------
__global__ void zero_deg(int* __restrict__ deg, int n) {
    int i = blockIdx.x * 256 + threadIdx.x;
    if (i < n) deg[i] = 0;
}

// ---------------- CSR build ----------------
__global__ void count_deg(const int* __restrict__ dst, int* __restrict__ deg, int n) {
    int i = blockIdx.x * 256 + threadIdx.x;
    if (i < n) atomicAdd(&deg[dst[i]], 1);
}

// hierarchical scan
__global__ __launch_bounds__(1024) void scan_local(const int* __restrict__ deg,
                                                   int* __restrict__ off,
                                                   int* __restrict__ bsum, int n) {
    __shared__ int buf[1024];
    int b = blockIdx.x, t = threadIdx.x;
    int gi = b * 1024 + t;
    int v = (gi < n) ? deg[gi] : 0;
    buf[t] = v;
    __syncthreads();
    for (int s = 1; s < 1024; s <<= 1) {
        int x = (t >= s) ? buf[t - s] : 0;
        __syncthreads();
        buf[t] += x;
        __syncthreads();
    }
    if (gi < n) off[gi] = buf[t] - v;
    if (t == 1023) bsum[b] = buf[1023];
}

__global__ void scan_bsum(int* __restrict__ bsum, int nb) {
    if (threadIdx.x == 0) {
        int acc = 0;
        for (int i = 0; i < nb; i++) { int v = bsum[i]; bsum[i] = acc; acc += v; }
    }
}

__global__ void scan_add(int* __restrict__ off, const int* __restrict__ bsum,
                         int* __restrict__ cursor, int n, int total) {
    int i = blockIdx.x * 256 + threadIdx.x;
    if (i < n) {
        int v = off[i] + bsum[i >> 10];
        off[i] = v;
        cursor[i] = v;
    }
    if (i == 0) off[n] = total;
}

__global__ void scatter_perm(const int* __restrict__ src, const int* __restrict__ dst,
                             const int* __restrict__ tokens_e, int* __restrict__ cursor,
                             int* __restrict__ psrc, int* __restrict__ pdst,
                             int* __restrict__ ptok, int n) {
    int i = blockIdx.x * 256 + threadIdx.x;
    if (i < n) {
        int p = atomicAdd(&cursor[dst[i]], 1);
        psrc[p] = src[i];
        pdst[p] = dst[i];
        ptok[p] = tokens_e[i];
    }
}

// ---------------- init (h bf16) ----------------
__global__ void init_h(const int* __restrict__ tok, const float* __restrict__ emb,
                       ushort_t* __restrict__ h) {
    int i = blockIdx.x * 256 + threadIdx.x;
    int r = i >> 7, d = i & 127;
    float v = emb[tok[r] * DIM + d];
    h[i] = f2b(fmaxf(v, 0.f));
}

__global__ __launch_bounds__(128) void eftab_kernel(const float* __restrict__ etab,
                                                    const float* __restrict__ W,
                                                    float* __restrict__ out) {
    int r = blockIdx.x, d = threadIdx.x;
    float acc = 0.f;
    for (int k = 0; k < DIM; k++)
        acc += etab[r * DIM + k] * W[k * DIM + d];
    out[r * DIM + d] = acc;
}

// ---------------- MFMA node GEMM: grid (400, 3) ----------------
__global__ __launch_bounds__(256, 4) void node_gemm_mfma(
    const ushort_t* __restrict__ h,
    const ushort_t* __restrict__ Wn,
    ushort_t* __restrict__ C0, ushort_t* __restrict__ C1, ushort_t* __restrict__ C2) {
    __shared__ __align__(16) ushort_t wF[16384];
    int tid = threadIdx.x, wv = tid >> 6, lane = tid & 63;
    int r = lane & 15, q = lane >> 4;
    int el = lane >> 2, qq = lane & 3;
    int m = blockIdx.y;
    size_t row = (size_t)blockIdx.x * 64 + 16 * wv;

    const ushort_t* aRow = h + (row + r) * DIM + q * 8;
    bf16x8 a0 = *(const bf16x8*)(aRow);
    bf16x8 a1 = *(const bf16x8*)(aRow + 32);
    bf16x8 a2 = *(const bf16x8*)(aRow + 64);
    bf16x8 a3 = *(const bf16x8*)(aRow + 96);

    {
        const uint4* wg = (const uint4*)(Wn + (size_t)m * NLAYERS * 16384);
        uint4* ws = (uint4*)wF;
        for (int i = tid; i < 2048; i += 256) ws[i] = wg[i];
    }
    __syncthreads();

    f32x4 acc[8] = {};
    const bf16x8* wfrag = (const bf16x8*)wF;
#pragma unroll
    for (int nt = 0; nt < 8; nt++)
        acc[nt] = __builtin_amdgcn_mfma_f32_16x16x32_bf16(a0, wfrag[(0 * 8 + nt) * 64 + lane], acc[nt], 0, 0, 0);
#pragma unroll
    for (int nt = 0; nt < 8; nt++)
        acc[nt] = __builtin_amdgcn_mfma_f32_16x16x32_bf16(a1, wfrag[(1 * 8 + nt) * 64 + lane], acc[nt], 0, 0, 0);
#pragma unroll
    for (int nt = 0; nt < 8; nt++)
        acc[nt] = __builtin_amdgcn_mfma_f32_16x16x32_bf16(a2, wfrag[(2 * 8 + nt) * 64 + lane], acc[nt], 0, 0, 0);
#pragma unroll
    for (int nt = 0; nt < 8; nt++)
        acc[nt] = __builtin_amdgcn_mfma_f32_16x16x32_bf16(a3, wfrag[(3 * 8 + nt) * 64 + lane], acc[nt], 0, 0, 0);
    __syncthreads();

    ushort_t* ss = wF + wv * 16 * STG_S;
#pragma unroll
    for (int nt = 0; nt < 8; nt++)
#pragma unroll
        for (int rg = 0; rg < 4; rg++)
            ss[(q * 4 + rg) * STG_S + nt * 16 + r] = f2b(acc[nt][rg]);

    ushort_t* Cp = (m == 0) ? C0 : (m == 1) ? C1 : C2;
    const uint4* sp = (const uint4*)(ss + el * STG_S + qq * 32);
    uint4* cp = (uint4*)(Cp + (row + el) * DIM + qq * 32);
#pragma unroll
    for (int cc = 0; cc < 4; cc++) cp[cc] = sp[cc];
}

// single-W with bias + relu (final Wf): h bf16 in, fp32 out
__global__ __launch_bounds__(256) void node_gemm1(
    const ushort_t* __restrict__ A, const float* __restrict__ W,
    const float* __restrict__ bias, float* __restrict__ C) {
    __shared__ float As[64 * 128];
    __shared__ uint2 Ws4[128 * 32];
    int tid = threadIdx.x;
    size_t row0 = (size_t)blockIdx.x * 64;
    const uint2* Ag = (const uint2*)(A + row0 * DIM);
    for (int f = tid; f < 64 * 32; f += 256) {
        uint2 v = Ag[f];
        ((float4*)As)[f] = make_float4(blo(v.x), bhi(v.x), blo(v.y), bhi(v.y));
    }
    const float4* Wg = (const float4*)W;
    for (int i = tid; i < 128 * 32; i += 256) Ws4[i] = pack4(Wg[i]);
    __syncthreads();
    int cq = tid & 31, r0 = (tid >> 5) * 8, c0 = cq * 4;
    float acc[8][4] = {};
    for (int k = 0; k < 128; k++) {
        uint2 wp = Ws4[k * 32 + cq];
        float w0 = blo(wp.x), w1 = bhi(wp.x), w2 = blo(wp.y), w3 = bhi(wp.y);
#pragma unroll
        for (int i = 0; i < 8; i++) {
            float a = As[(r0 + i) * 128 + k];
            acc[i][0] += a * w0; acc[i][1] += a * w1;
            acc[i][2] += a * w2; acc[i][3] += a * w3;
        }
    }
    float b0 = bias[c0], b1 = bias[c0 + 1], b2v = bias[c0 + 2], b3v = bias[c0 + 3];
#pragma unroll
    for (int i = 0; i < 8; i++) {
        *(float4*)&C[(row0 + r0 + i) * DIM + c0] =
            make_float4(fmaxf(acc[i][0] + b0, 0.f), fmaxf(acc[i][1] + b1, 0.f),
                        fmaxf(acc[i][2] + b2v, 0.f), fmaxf(acc[i][3] + b3v, 0.f));
    }
}

// ---------------- MFMA edge GEMM: 512 threads / 8 waves / 128 edges per block ----------------
__global__ __launch_bounds__(512, 8) void edge_gemm_mfma(
    ushort_t* __restrict__ e,
    const ushort_t* __restrict__ fni, const ushort_t* __restrict__ fnj,
    const int* __restrict__ psrc, const int* __restrict__ pdst,
    const ushort_t* __restrict__ Wf,
    const float* __restrict__ attn, const float* __restrict__ bias,
    float* __restrict__ score) {
    __shared__ __align__(16) ushort_t wF[18432];  // 36.9 KB: W (32 KB) + staging overlay

    int tid = threadIdx.x;
    int wv = tid >> 6, lane = tid & 63;
    int r = lane & 15, q = lane >> 4;
    int el = lane >> 2, qq = lane & 3;
    size_t row = (size_t)blockIdx.x * 128 + 16 * wv;
    size_t eid = row + el;

    int sv = psrc[eid], dv = pdst[eid];

    const ushort_t* aRow = e + (row + r) * DIM + q * 8;
    bf16x8 a0 = *(const bf16x8*)(aRow);
    bf16x8 a1 = *(const bf16x8*)(aRow + 32);
    bf16x8 a2 = *(const bf16x8*)(aRow + 64);
    bf16x8 a3 = *(const bf16x8*)(aRow + 96);

    {
        const uint4* wg = (const uint4*)Wf;
        uint4* ws = (uint4*)wF;
        for (int i = tid; i < 2048; i += 512) ws[i] = wg[i];
    }
    __syncthreads();

    f32x4 acc[8] = {};
    const bf16x8* wfrag = (const bf16x8*)wF;
#pragma unroll
    for (int nt = 0; nt < 8; nt++)
        acc[nt] = __builtin_amdgcn_mfma_f32_16x16x32_bf16(a0, wfrag[(0 * 8 + nt) * 64 + lane], acc[nt], 0, 0, 0);
#pragma unroll
    for (int nt = 0; nt < 8; nt++)
        acc[nt] = __builtin_amdgcn_mfma_f32_16x16x32_bf16(a1, wfrag[(1 * 8 + nt) * 64 + lane], acc[nt], 0, 0, 0);
#pragma unroll
    for (int nt = 0; nt < 8; nt++)
        acc[nt] = __builtin_amdgcn_mfma_f32_16x16x32_bf16(a2, wfrag[(2 * 8 + nt) * 64 + lane], acc[nt], 0, 0, 0);
#pragma unroll
    for (int nt = 0; nt < 8; nt++)
        acc[nt] = __builtin_amdgcn_mfma_f32_16x16x32_bf16(a3, wfrag[(3 * 8 + nt) * 64 + lane], acc[nt], 0, 0, 0);
    __syncthreads();  // all wF reads done -> staging overlay

    ushort_t* ss = wF + wv * 16 * STG_S;
#pragma unroll
    for (int nt = 0; nt < 8; nt++)
#pragma unroll
        for (int rg = 0; rg < 4; rg++)
            ss[(q * 4 + rg) * STG_S + nt * 16 + r] = f2b(acc[nt][rg]);

    const uint4* nip = (const uint4*)(fni + (size_t)sv * DIM + qq * 32);
    const uint4* njp = (const uint4*)(fnj + (size_t)dv * DIM + qq * 32);
    const uint4* sp = (const uint4*)(ss + el * STG_S + qq * 32);
    uint4 outv[4];
    float p = 0.f;
#pragma unroll
    for (int cc = 0; cc < 4; cc++) {
        uint4 avq = sp[cc];
        uint4 niq = nip[cc];
        uint4 njq = njp[cc];
#pragma unroll
        for (int u = 0; u < 4; u++) {
            unsigned int aw = ((const unsigned int*)&avq)[u];
            unsigned int nw = ((const unsigned int*)&niq)[u];
            unsigned int jw = ((const unsigned int*)&njq)[u];
            int c = qq * 32 + cc * 8 + u * 2;
            float v0 = blo(aw) + blo(nw) + blo(jw) + bias[c];
            float v1 = bhi(aw) + bhi(nw) + bhi(jw) + bias[c + 1];
            v0 = v0 > 0.f ? v0 : 0.01f * v0;
            v1 = v1 > 0.f ? v1 : 0.01f * v1;
            ((unsigned int*)&outv[cc])[u] =
                (unsigned int)f2b(v0) | ((unsigned int)f2b(v1) << 16);
            p += v0 * attn[c] + v1 * attn[c + 1];
        }
    }
    uint4* ep = (uint4*)(e + eid * DIM + qq * 32);
#pragma unroll
    for (int cc = 0; cc < 4; cc++) ep[cc] = outv[cc];
    p += __shfl_xor(p, 1);
    p += __shfl_xor(p, 2);
    if (qq == 0) score[eid] = p;
}

// ---------------- layer-0 edge kernel (permuted order) ----------------
__global__ __launch_bounds__(256) void edge0(
    const int* __restrict__ ptok, const float* __restrict__ eftab,
    const ushort_t* __restrict__ fni, const ushort_t* __restrict__ fnj,
    const int* __restrict__ psrc, const int* __restrict__ pdst,
    const float* __restrict__ attn, const float* __restrict__ bias,
    ushort_t* __restrict__ e, float* __restrict__ score) {
    unsigned int gid = blockIdx.x * 256 + threadIdx.x;
    unsigned int eid = gid >> 5;
    int cq = gid & 31, c0 = cq * 4;
    int tok = ptok[eid];
    int sv = psrc[eid], dv = pdst[eid];
    float4 t = *(const float4*)&eftab[tok * DIM + c0];
    uint2 niw = *(const uint2*)(fni + (size_t)sv * DIM + c0);
    uint2 njw = *(const uint2*)(fnj + (size_t)dv * DIM + c0);
    float v0 = t.x + blo(niw.x) + blo(njw.x) + bias[c0];
    float v1 = t.y + bhi(niw.x) + bhi(njw.x) + bias[c0 + 1];
    float v2 = t.z + blo(niw.y) + blo(njw.y) + bias[c0 + 2];
    float v3 = t.w + bhi(niw.y) + bhi(njw.y) + bias[c0 + 3];
    v0 = v0 > 0.f ? v0 : 0.01f * v0;
    v1 = v1 > 0.f ? v1 : 0.01f * v1;
    v2 = v2 > 0.f ? v2 : 0.01f * v2;
    v3 = v3 > 0.f ? v3 : 0.01f * v3;
    *(uint2*)(e + (size_t)eid * DIM + c0) = pack4(make_float4(v0, v1, v2, v3));
    float p = v0 * attn[c0] + v1 * attn[c0 + 1] + v2 * attn[c0 + 2] + v3 * attn[c0 + 3];
#pragma unroll
    for (int o = 1; o < 32; o <<= 1) p += __shfl_xor(p, o);
    if (cq == 0) score[eid] = p;
}

// ---------------- wave-per-node softmax + aggregation: unroll-4 gathers ----------------
__global__ __launch_bounds__(256) void agg_wave(
    const int* __restrict__ off, const int* __restrict__ psrc,
    const float* __restrict__ score, const ushort_t* __restrict__ hs,
    ushort_t* __restrict__ h) {
    int node = blockIdx.x * 4 + (threadIdx.x >> 6);
    int lane = threadIdx.x & 63;
    int b0 = off[node];
    int deg = off[node + 1] - b0;

    float m = -1e30f;
    for (int j = lane; j < deg; j += 64) m = fmaxf(m, score[b0 + j]);
#pragma unroll
    for (int o = 32; o > 0; o >>= 1) m = fmaxf(m, __shfl_xor(m, o));
    float se = 0.f;
    for (int j = lane; j < deg; j += 64) se += __expf(score[b0 + j] - m);
#pragma unroll
    for (int o = 32; o > 0; o >>= 1) se += __shfl_xor(se, o);
    float inv = (deg > 0) ? 1.f / se : 0.f;

    float acc0 = 0.f, acc1 = 0.f;
    for (int base = 0; base < deg; base += 64) {
        int cnt = min(64, deg - base);
        float wgt = 0.f;
        int sidx = 0;
        if (lane < cnt) {
            wgt = __expf(score[b0 + base + lane] - m) * inv;
            sidx = psrc[b0 + base + lane];
        }
        int i = 0;
        for (; i + 4 <= cnt; i += 4) {
            float w0 = __shfl(wgt, i), w1 = __shfl(wgt, i + 1);
            float w2 = __shfl(wgt, i + 2), w3 = __shfl(wgt, i + 3);
            int s0 = __shfl(sidx, i), s1 = __shfl(sidx, i + 1);
            int s2 = __shfl(sidx, i + 2), s3 = __shfl(sidx, i + 3);
            unsigned int h0 = *(const unsigned int*)(hs + (size_t)s0 * DIM + lane * 2);
            unsigned int h1 = *(const unsigned int*)(hs + (size_t)s1 * DIM + lane * 2);
            unsigned int h2 = *(const unsigned int*)(hs + (size_t)s2 * DIM + lane * 2);
            unsigned int h3 = *(const unsigned int*)(hs + (size_t)s3 * DIM + lane * 2);
            acc0 += w0 * blo(h0); acc1 += w0 * bhi(h0);
            acc0 += w1 * blo(h1); acc1 += w1 * bhi(h1);
            acc0 += w2 * blo(h2); acc1 += w2 * bhi(h2);
            acc0 += w3 * blo(h3); acc1 += w3 * bhi(h3);
        }
        for (; i < cnt; i++) {
            float wi = __shfl(wgt, i);
            int si = __shfl(sidx, i);
            unsigned int hv = *(const unsigned int*)(hs + (size_t)si * DIM + lane * 2);
            acc0 += wi * blo(hv);
            acc1 += wi * bhi(hv);
        }
    }
    unsigned int outp = (unsigned int)f2b(fmaxf(acc0, 0.f)) |
                        ((unsigned int)f2b(fmaxf(acc1, 0.f)) << 16);
    *(unsigned int*)(h + (size_t)node * DIM + lane * 2) = outp;
}

// ---------------- sort each node's 128 features ascending ----------------
__global__ __launch_bounds__(128) void sort_rows(const float* __restrict__ h2,
                                                 float* __restrict__ hsort,
                                                 float* __restrict__ maxval) {
    __shared__ float buf[128];
    int n = blockIdx.x, t = threadIdx.x;
    buf[t] = h2[(size_t)n * DIM + t];
    __syncthreads();
    for (int k = 2; k <= 128; k <<= 1) {
        for (int j = k >> 1; j > 0; j >>= 1) {
            int ixj = t ^ j;
            float a = buf[t], b = buf[ixj];
            __syncthreads();
            bool up = ((t & k) == 0);
            float mn = fminf(a, b), mx = fmaxf(a, b);
            buf[t] = up ? ((t < ixj) ? mn : mx) : ((t < ixj) ? mx : mn);
            __syncthreads();
        }
    }
    hsort[(size_t)n * DIM + t] = buf[t];
    if (t == 127) maxval[n] = buf[127];
}

// ---------------- per-graph top-k + gather pooled rows ----------------
__global__ __launch_bounds__(256) void topk_pool(const float* __restrict__ maxval,
                                                 const float* __restrict__ hsort,
                                                 float* __restrict__ pooled) {
    __shared__ float v[256];
    __shared__ int id[256];
    int b = blockIdx.x, t = threadIdx.x;
    v[t] = (t < NPG) ? maxval[b * NPG + t] : -1e30f;
    id[t] = t;
    __syncthreads();
    for (int k = 2; k <= 256; k <<= 1) {
        for (int j = k >> 1; j > 0; j >>= 1) {
            int ixj = t ^ j;
            float va = v[t], vb = v[ixj];
            int ia = id[t], ib = id[ixj];
            __syncthreads();
            bool dirDesc = ((t & k) == 0);
            bool cmp = (va > vb) || (va == vb && ia < ib);
            bool takeMine = ((t < ixj) == (dirDesc == cmp));
            v[t] = takeMine ? va : vb;
            id[t] = takeMine ? ia : ib;
            __syncthreads();
        }
    }
    for (int i = t; i < KPOOL * DIM; i += 256) {
        int kk = i >> 7, d = i & 127;
        pooled[((size_t)b * KPOOL + kk) * DIM + d] = hsort[((size_t)b * NPG + id[kk]) * DIM + d];
    }
}

// ---------------- ft split-K ----------------
__global__ __launch_bounds__(256) void ft_partial(
    const float* __restrict__ pooled, const float* __restrict__ W3,
    float* __restrict__ part) {
    __shared__ float ps[512];
    __shared__ float red[256];
    int b = blockIdx.x, s = blockIdx.y;
    int t = threadIdx.x;
    int d = t & 127, half = t >> 7;
    for (int i = t; i < 512; i += 256) ps[i] = pooled[(size_t)b * 4096 + s * 512 + i];
    __syncthreads();
    float acc = 0.f;
    const float* Wp = W3 + (size_t)(s * 512 + half * 256) * DIM + d;
    const float* pp = ps + half * 256;
#pragma unroll 4
    for (int kk = 0; kk < 256; kk++) acc += pp[kk] * Wp[(size_t)kk * DIM];
    red[t] = acc;
    __syncthreads();
    if (t < 128) part[((size_t)b * 8 + s) * DIM + t] = red[t] + red[t + 128];
}

__global__ __launch_bounds__(128) void ft_reduce(
    const float* __restrict__ part, const float* __restrict__ al3,
    const float* __restrict__ ar3, float* __restrict__ ft,
    float* __restrict__ sl, float* __restrict__ sr) {
    __shared__ float r1[128], r2[128];
    int b = blockIdx.x, d = threadIdx.x;
    float acc = 0.f;
#pragma unroll
    for (int s = 0; s < 8; s++) acc += part[((size_t)b * 8 + s) * DIM + d];
    ft[b * DIM + d] = acc;
    r1[d] = acc * al3[d];
    r2[d] = acc * ar3[d];
    __syncthreads();
    for (int s = 64; s > 0; s >>= 1) {
        if (d < s) { r1[d] += r1[d + s]; r2[d] += r2[d + s]; }
        __syncthreads();
    }
    if (d == 0) { sl[b] = r1[0]; sr[b] = r2[0]; }
}

// ---------------- final-graph GAT ----------------
__global__ __launch_bounds__(128) void fg_kernel(
    const int* __restrict__ fg_src, const int* __restrict__ fg_dst,
    const float* __restrict__ sl, const float* __restrict__ sr,
    const float* __restrict__ ft, const float* __restrict__ b3,
    float* __restrict__ g) {
    __shared__ int list[EFE];
    __shared__ float wgt[EFE];
    __shared__ float red[128];
    __shared__ int cnt;
    int b = blockIdx.x, t = threadIdx.x;
    if (t == 0) cnt = 0;
    __syncthreads();
    for (int e = t; e < EFE; e += 128)
        if (fg_dst[e] == b) { int p = atomicAdd(&cnt, 1); list[p] = e; }
    __syncthreads();
    int deg = cnt;
    float srb = sr[b];
    float m = -1e30f;
    for (int j = t; j < deg; j += 128) {
        float s = sl[fg_src[list[j]]] + srb;
        s = s > 0.f ? s : 0.2f * s;
        m = fmaxf(m, s);
    }
    red[t] = m;
    __syncthreads();
    for (int s = 64; s > 0; s >>= 1) { if (t < s) red[t] = fmaxf(red[t], red[t + s]); __syncthreads(); }
    m = red[0];
    __syncthreads();
    float se = 0.f;
    for (int j = t; j < deg; j += 128) {
        float s = sl[fg_src[list[j]]] + srb;
        s = s > 0.f ? s : 0.2f * s;
        se += __expf(s - m);
    }
    red[t] = se;
    __syncthreads();
    for (int s = 64; s > 0; s >>= 1) { if (t < s) red[t] += red[t + s]; __syncthreads(); }
    float inv = (deg > 0) ? 1.f / red[0] : 0.f;
    __syncthreads();
    for (int j = t; j < deg; j += 128) {
        float s = sl[fg_src[list[j]]] + srb;
        s = s > 0.f ? s : 0.2f * s;
        wgt[j] = __expf(s - m) * inv;
    }
    __syncthreads();
    float acc = 0.f;
    for (int j = 0; j < deg; j++) acc += wgt[j] * ft[(size_t)fg_src[list[j]] * DIM + t];
    g[b * DIM + t] = fmaxf(acc + b3[t], 0.f);
}

// ---------------- g2 = relu(g @ Wl + bl) ----------------
__global__ __launch_bounds__(128) void gl_kernel(const float* __restrict__ g,
                                                 const float* __restrict__ Wl,
                                                 const float* __restrict__ bl,
                                                 float* __restrict__ g2) {
    __shared__ float gs[128];
    int b = blockIdx.x, d = threadIdx.x;
    gs[d] = g[b * DIM + d];
    __syncthreads();
    float acc = 0.f;
    for (int k = 0; k < 128; k++) acc += gs[k] * Wl[k * DIM + d];
    g2[b * DIM + d] = fmaxf(acc + bl[d], 0.f);
}

// ---------------- out = g2 @ Wc + bc ----------------
__global__ __launch_bounds__(256) void out_kernel(const float* __restrict__ g2,
                                                  const float* __restrict__ Wc,
                                                  const float* __restrict__ bc,
                                                  float* __restrict__ out) {
    int i = threadIdx.x;
    int b = i >> 1, j = i & 1;
    float acc = bc[j];
    for (int k = 0; k < 128; k++) acc += g2[b * DIM + k] * Wc[k * 2 + j];
    out[b * 2 + j] = acc;
}

extern "C" void kernel_launch(void* const* d_in, const int* in_sizes, int n_in,
                              void* d_out, int out_size, void* d_ws, size_t ws_size,
                              hipStream_t stream) {
    const int* tokens_h = (const int*)d_in[0];
    const int* tokens_e = (const int*)d_in[1];
    const int* src = (const int*)d_in[2];
    const int* dst = (const int*)d_in[3];
    const int* fg_src = (const int*)d_in[4];
    const int* fg_dst = (const int*)d_in[5];
    const float* token_emb = (const float*)d_in[6];
    const float* e_token_emb = (const float*)d_in[7];
    const float* W_ni = (const float*)d_in[8];
    const float* W_nj = (const float*)d_in[9];
    const float* W_fij = (const float*)d_in[10];
    const float* W_node = (const float*)d_in[11];
    const float* attn_e = (const float*)d_in[12];
    const float* bias_e = (const float*)d_in[13];
    const float* Wf = (const float*)d_in[14];
    const float* bf_ = (const float*)d_in[15];
    const float* W3 = (const float*)d_in[16];
    const float* al3 = (const float*)d_in[17];
    const float* ar3 = (const float*)d_in[18];
    const float* b3 = (const float*)d_in[19];
    const float* Wl = (const float*)d_in[20];
    const float* bl = (const float*)d_in[21];
    const float* Wc = (const float*)d_in[22];
    const float* bc = (const float*)d_in[23];
    float* out = (float*)d_out;

    char* w = (char*)d_ws;
    auto alloc = [&](size_t b) -> char* {
        char* p = w;
        w += (b + 255) & ~(size_t)255;
        return p;
    };
    ushort_t* h = (ushort_t*)alloc((size_t)N_NODES * DIM * 2);
    ushort_t* fni = (ushort_t*)alloc((size_t)N_NODES * DIM * 2);
    ushort_t* fnj = (ushort_t*)alloc((size_t)N_NODES * DIM * 2);
    ushort_t* hs = (ushort_t*)alloc((size_t)N_NODES * DIM * 2);
    ushort_t* e = (ushort_t*)alloc((size_t)N_EDGES * DIM * 2);
    float* score = (float*)alloc((size_t)N_EDGES * 4);
    int* deg = (int*)alloc((size_t)N_NODES * 4);
    int* off = (int*)alloc((size_t)(N_NODES + 1) * 4);
    int* cursor = (int*)alloc((size_t)N_NODES * 4);
    int* bsum = (int*)alloc(64 * 4);
    int* psrc = (int*)alloc((size_t)N_EDGES * 4);
    int* pdst = (int*)alloc((size_t)N_EDGES * 4);
    int* ptok = (int*)alloc((size_t)N_EDGES * 4);
    float* eftab = (float*)alloc(100 * DIM * 4);
    float* maxval = (float*)alloc((size_t)N_NODES * 4);
    float* pooled = (float*)alloc((size_t)BGR * KPOOL * DIM * 4);
    float* ft = (float*)alloc(BGR * DIM * 4);
    float* part = (float*)alloc((size_t)BGR * 8 * DIM * 4);
    float* sl = (float*)alloc(BGR * 4);
    float* sr = (float*)alloc(BGR * 4);
    float* g = (float*)alloc(BGR * DIM * 4);
    float* g2 = (float*)alloc(BGR * DIM * 4);
    ushort_t* Wf7 = (ushort_t*)alloc((size_t)NLAYERS * DIM * DIM * 2);
    ushort_t* Wn = (ushort_t*)alloc((size_t)3 * NLAYERS * DIM * DIM * 2);
    float* h2 = (float*)e;
    float* hsort = (float*)((char*)e + (size_t)16 * 1024 * 1024);

    // weight prep
    wfprep<<<(NLAYERS * DIM * DIM) / 256, 256, 0, stream>>>(W_fij, Wf7);
    wnprep<<<(3 * NLAYERS * DIM * DIM) / 256, 256, 0, stream>>>(W_ni, W_nj, W_node, Wn);

    // CSR build + edge permutation (dst-sorted order), hierarchical scan
    zero_deg<<<(N_NODES + 255) / 256, 256, 0, stream>>>(deg, N_NODES);
    count_deg<<<N_EDGES / 256, 256, 0, stream>>>(dst, deg, N_EDGES);
    scan_local<<<(N_NODES + 1023) / 1024, 1024, 0, stream>>>(deg, off, bsum, N_NODES);
    scan_bsum<<<1, 32, 0, stream>>>(bsum, (N_NODES + 1023) / 1024);
    scan_add<<<(N_NODES + 255) / 256, 256, 0, stream>>>(off, bsum, cursor, N_NODES, N_EDGES);
    scatter_perm<<<N_EDGES / 256, 256, 0, stream>>>(src, dst, tokens_e, cursor,
                                                    psrc, pdst, ptok, N_EDGES);

    init_h<<<(N_NODES * DIM) / 256, 256, 0, stream>>>(tokens_h, token_emb, h);
    eftab_kernel<<<100, 128, 0, stream>>>(e_token_emb, W_fij, eftab);

    for (int l = 0; l < NLAYERS; l++) {
        node_gemm_mfma<<<dim3(N_NODES / 64, 3), 256, 0, stream>>>(
            h, Wn + l * 16384, fni, fnj, hs);
        if (l == 0) {
            edge0<<<(N_EDGES * 32) / 256, 256, 0, stream>>>(
                ptok, eftab, fni, fnj, psrc, pdst, attn_e, bias_e, e, score);
        } else {
            edge_gemm_mfma<<<N_EDGES / 128, 512, 0, stream>>>(
                e, fni, fnj, psrc, pdst, Wf7 + l * DIM * DIM,
                attn_e + l * DIM, bias_e + l * DIM, score);
        }
        agg_wave<<<N_NODES / 4, 256, 0, stream>>>(off, psrc, score, hs, h);
    }

    node_gemm1<<<N_NODES / 64, 256, 0, stream>>>(h, Wf, bf_, h2);
    sort_rows<<<N_NODES, 128, 0, stream>>>(h2, hsort, maxval);
    topk_pool<<<BGR, 256, 0, stream>>>(maxval, hsort, pooled);
    ft_partial<<<dim3(BGR, 8), 256, 0, stream>>>(pooled, W3, part);
    ft_reduce<<<BGR, 128, 0, stream>>>(part, al3, ar3, ft, sl, sr);
    fg_kernel<<<BGR, 128, 0, stream>>>(fg_src, fg_dst, sl, sr, ft, b3, g);
    gl_kernel<<<BGR, 128, 0, stream>>>(g, Wl, bl, g2);
    out_kernel<<<1, 256, 0, stream>>>(g2, Wc, bc, out);
}

// Round 12
// 1376.217 us; speedup vs baseline: 1.2497x; 1.2497x over previous
//
#include <hip/hip_runtime.h>

#define N_NODES 25600
#define N_EDGES 409600
#define BGR 128
#define EFE 1024
#define DIM 128
#define NLAYERS 8
#define KPOOL 32
#define NPG 200

typedef unsigned short ushort_t;
typedef __attribute__((ext_vector_type(8))) short bf16x8;
typedef __attribute__((ext_vector_type(4))) float f32x4;

#define STG_S 144  // per-wave C-staging stride (bf16 elems)

__device__ __forceinline__ float b2f(ushort_t v) {
    return __uint_as_float(((unsigned int)v) << 16);
}
__device__ __forceinline__ float blo(unsigned int u) {
    return __uint_as_float(u << 16);
}
__device__ __forceinline__ float bhi(unsigned int u) {
    return __uint_as_float(u & 0xffff0000u);
}
__device__ __forceinline__ ushort_t f2b(float f) {
    unsigned int u = __float_as_uint(f);
    unsigned int r = (u + 0x7fffu + ((u >> 16) & 1u)) >> 16;
    return (ushort_t)r;
}
__device__ __forceinline__ uint2 pack4(float4 v) {
    uint2 p;
    p.x = (unsigned int)f2b(v.x) | ((unsigned int)f2b(v.y) << 16);
    p.y = (unsigned int)f2b(v.z) | ((unsigned int)f2b(v.w) << 16);
    return p;
}

// ---------------- W_fij -> fragment-linear bf16 (proven R6) ----------------
__global__ void wfprep(const float* __restrict__ W, ushort_t* __restrict__ Wf) {
    int idx = blockIdx.x * 256 + threadIdx.x;  // 8 * 16384
    int l = idx >> 14, rem = idx & 16383;
    int j = rem & 7, lane = (rem >> 3) & 63, nt = (rem >> 9) & 7, kc = rem >> 12;
    int q = lane >> 4, r = lane & 15;
    int k = kc * 32 + q * 8 + j, n = nt * 16 + r;
    Wf[idx] = f2b(W[l * 16384 + k * 128 + n]);
}

// W_ni / W_nj / W_node -> fragment-linear bf16, layout [m][l][16384]
__global__ void wnprep(const float* __restrict__ Wni, const float* __restrict__ Wnj,
                       const float* __restrict__ Wnode, ushort_t* __restrict__ Wn) {
    int idx = blockIdx.x * 256 + threadIdx.x;  // 3 * 8 * 16384
    int m = idx >> 17;
    int l = (idx >> 14) & 7;
    int rem = idx & 16383;
    int j = rem & 7, lane = (rem >> 3) & 63, nt = (rem >> 9) & 7, kc = rem >> 12;
    int q = lane >> 4, r = lane & 15;
    int k = kc * 32 + q * 8 + j, n = nt * 16 + r;
    const float* W = (m == 0) ? Wni : (m == 1) ? Wnj : Wnode;
    Wn[idx] = f2b(W[l * 16384 + k * 128 + n]);
}

// ---------------- zero deg ----------------
__global__ void zero_deg(int* __restrict__ deg, int n) {
    int i = blockIdx.x * 256 + threadIdx.x;
    if (i < n) deg[i] = 0;
}

// ---------------- CSR build ----------------
__global__ void count_deg(const int* __restrict__ dst, int* __restrict__ deg, int n) {
    int i = blockIdx.x * 256 + threadIdx.x;
    if (i < n) atomicAdd(&deg[dst[i]], 1);
}

// hierarchical scan
__global__ __launch_bounds__(1024) void scan_local(const int* __restrict__ deg,
                                                   int* __restrict__ off,
                                                   int* __restrict__ bsum, int n) {
    __shared__ int buf[1024];
    int b = blockIdx.x, t = threadIdx.x;
    int gi = b * 1024 + t;
    int v = (gi < n) ? deg[gi] : 0;
    buf[t] = v;
    __syncthreads();
    for (int s = 1; s < 1024; s <<= 1) {
        int x = (t >= s) ? buf[t - s] : 0;
        __syncthreads();
        buf[t] += x;
        __syncthreads();
    }
    if (gi < n) off[gi] = buf[t] - v;
    if (t == 1023) bsum[b] = buf[1023];
}

__global__ void scan_bsum(int* __restrict__ bsum, int nb) {
    if (threadIdx.x == 0) {
        int acc = 0;
        for (int i = 0; i < nb; i++) { int v = bsum[i]; bsum[i] = acc; acc += v; }
    }
}

__global__ void scan_add(int* __restrict__ off, const int* __restrict__ bsum,
                         int* __restrict__ cursor, int n, int total) {
    int i = blockIdx.x * 256 + threadIdx.x;
    if (i < n) {
        int v = off[i] + bsum[i >> 10];
        off[i] = v;
        cursor[i] = v;
    }
    if (i == 0) off[n] = total;
}

__global__ void scatter_perm(const int* __restrict__ src, const int* __restrict__ dst,
                             const int* __restrict__ tokens_e, int* __restrict__ cursor,
                             int* __restrict__ psrc, int* __restrict__ pdst,
                             int* __restrict__ ptok, int n) {
    int i = blockIdx.x * 256 + threadIdx.x;
    if (i < n) {
        int p = atomicAdd(&cursor[dst[i]], 1);
        psrc[p] = src[i];
        pdst[p] = dst[i];
        ptok[p] = tokens_e[i];
    }
}

// ---------------- init (h bf16) ----------------
__global__ void init_h(const int* __restrict__ tok, const float* __restrict__ emb,
                       ushort_t* __restrict__ h) {
    int i = blockIdx.x * 256 + threadIdx.x;
    int r = i >> 7, d = i & 127;
    float v = emb[tok[r] * DIM + d];
    h[i] = f2b(fmaxf(v, 0.f));
}

__global__ __launch_bounds__(128) void eftab_kernel(const float* __restrict__ etab,
                                                    const float* __restrict__ W,
                                                    float* __restrict__ out) {
    int r = blockIdx.x, d = threadIdx.x;
    float acc = 0.f;
    for (int k = 0; k < DIM; k++)
        acc += etab[r * DIM + k] * W[k * DIM + d];
    out[r * DIM + d] = acc;
}

// ---------------- MFMA node GEMM: grid (400, 3) ----------------
__global__ __launch_bounds__(256, 4) void node_gemm_mfma(
    const ushort_t* __restrict__ h,
    const ushort_t* __restrict__ Wn,
    ushort_t* __restrict__ C0, ushort_t* __restrict__ C1, ushort_t* __restrict__ C2) {
    __shared__ __align__(16) ushort_t wF[16384];
    int tid = threadIdx.x, wv = tid >> 6, lane = tid & 63;
    int r = lane & 15, q = lane >> 4;
    int el = lane >> 2, qq = lane & 3;
    int m = blockIdx.y;
    size_t row = (size_t)blockIdx.x * 64 + 16 * wv;

    const ushort_t* aRow = h + (row + r) * DIM + q * 8;
    bf16x8 a0 = *(const bf16x8*)(aRow);
    bf16x8 a1 = *(const bf16x8*)(aRow + 32);
    bf16x8 a2 = *(const bf16x8*)(aRow + 64);
    bf16x8 a3 = *(const bf16x8*)(aRow + 96);

    {
        const uint4* wg = (const uint4*)(Wn + (size_t)m * NLAYERS * 16384);
        uint4* ws = (uint4*)wF;
        for (int i = tid; i < 2048; i += 256) ws[i] = wg[i];
    }
    __syncthreads();

    f32x4 acc[8] = {};
    const bf16x8* wfrag = (const bf16x8*)wF;
#pragma unroll
    for (int nt = 0; nt < 8; nt++)
        acc[nt] = __builtin_amdgcn_mfma_f32_16x16x32_bf16(a0, wfrag[(0 * 8 + nt) * 64 + lane], acc[nt], 0, 0, 0);
#pragma unroll
    for (int nt = 0; nt < 8; nt++)
        acc[nt] = __builtin_amdgcn_mfma_f32_16x16x32_bf16(a1, wfrag[(1 * 8 + nt) * 64 + lane], acc[nt], 0, 0, 0);
#pragma unroll
    for (int nt = 0; nt < 8; nt++)
        acc[nt] = __builtin_amdgcn_mfma_f32_16x16x32_bf16(a2, wfrag[(2 * 8 + nt) * 64 + lane], acc[nt], 0, 0, 0);
#pragma unroll
    for (int nt = 0; nt < 8; nt++)
        acc[nt] = __builtin_amdgcn_mfma_f32_16x16x32_bf16(a3, wfrag[(3 * 8 + nt) * 64 + lane], acc[nt], 0, 0, 0);
    __syncthreads();

    ushort_t* ss = wF + wv * 16 * STG_S;
#pragma unroll
    for (int nt = 0; nt < 8; nt++)
#pragma unroll
        for (int rg = 0; rg < 4; rg++)
            ss[(q * 4 + rg) * STG_S + nt * 16 + r] = f2b(acc[nt][rg]);

    ushort_t* Cp = (m == 0) ? C0 : (m == 1) ? C1 : C2;
    const uint4* sp = (const uint4*)(ss + el * STG_S + qq * 32);
    uint4* cp = (uint4*)(Cp + (row + el) * DIM + qq * 32);
#pragma unroll
    for (int cc = 0; cc < 4; cc++) cp[cc] = sp[cc];
}

// single-W with bias + relu (final Wf): h bf16 in, fp32 out
__global__ __launch_bounds__(256) void node_gemm1(
    const ushort_t* __restrict__ A, const float* __restrict__ W,
    const float* __restrict__ bias, float* __restrict__ C) {
    __shared__ float As[64 * 128];
    __shared__ uint2 Ws4[128 * 32];
    int tid = threadIdx.x;
    size_t row0 = (size_t)blockIdx.x * 64;
    const uint2* Ag = (const uint2*)(A + row0 * DIM);
    for (int f = tid; f < 64 * 32; f += 256) {
        uint2 v = Ag[f];
        ((float4*)As)[f] = make_float4(blo(v.x), bhi(v.x), blo(v.y), bhi(v.y));
    }
    const float4* Wg = (const float4*)W;
    for (int i = tid; i < 128 * 32; i += 256) Ws4[i] = pack4(Wg[i]);
    __syncthreads();
    int cq = tid & 31, r0 = (tid >> 5) * 8, c0 = cq * 4;
    float acc[8][4] = {};
    for (int k = 0; k < 128; k++) {
        uint2 wp = Ws4[k * 32 + cq];
        float w0 = blo(wp.x), w1 = bhi(wp.x), w2 = blo(wp.y), w3 = bhi(wp.y);
#pragma unroll
        for (int i = 0; i < 8; i++) {
            float a = As[(r0 + i) * 128 + k];
            acc[i][0] += a * w0; acc[i][1] += a * w1;
            acc[i][2] += a * w2; acc[i][3] += a * w3;
        }
    }
    float b0 = bias[c0], b1 = bias[c0 + 1], b2v = bias[c0 + 2], b3v = bias[c0 + 3];
#pragma unroll
    for (int i = 0; i < 8; i++) {
        *(float4*)&C[(row0 + r0 + i) * DIM + c0] =
            make_float4(fmaxf(acc[i][0] + b0, 0.f), fmaxf(acc[i][1] + b1, 0.f),
                        fmaxf(acc[i][2] + b2v, 0.f), fmaxf(acc[i][3] + b3v, 0.f));
    }
}

// ---------------- MFMA edge GEMM: R10 shape (256 thr, 1 tile/block, 32 KB LDS) ----------------
// launch_bounds (256,5): VGPR cap ~102 >= 52 live set (no spill), 5 blocks/CU by LDS.
__global__ __launch_bounds__(256, 5) void edge_gemm_mfma(
    ushort_t* __restrict__ e,
    const ushort_t* __restrict__ fni, const ushort_t* __restrict__ fnj,
    const int* __restrict__ psrc, const int* __restrict__ pdst,
    const ushort_t* __restrict__ Wf,
    const float* __restrict__ attn, const float* __restrict__ bias,
    float* __restrict__ score) {
    __shared__ __align__(16) ushort_t wF[16384];  // 32 KB; staging overlays after barrier

    int tid = threadIdx.x;
    int wv = tid >> 6, lane = tid & 63;
    int r = lane & 15, q = lane >> 4;
    int el = lane >> 2, qq = lane & 3;
    size_t row = (size_t)blockIdx.x * 64 + 16 * wv;
    size_t eid = row + el;

    int sv = psrc[eid], dv = pdst[eid];

    const ushort_t* aRow = e + (row + r) * DIM + q * 8;
    bf16x8 a0 = *(const bf16x8*)(aRow);
    bf16x8 a1 = *(const bf16x8*)(aRow + 32);
    bf16x8 a2 = *(const bf16x8*)(aRow + 64);
    bf16x8 a3 = *(const bf16x8*)(aRow + 96);

    {
        const uint4* wg = (const uint4*)Wf;
        uint4* ws = (uint4*)wF;
        for (int i = tid; i < 2048; i += 256) ws[i] = wg[i];
    }
    __syncthreads();

    f32x4 acc[8] = {};
    const bf16x8* wfrag = (const bf16x8*)wF;
#pragma unroll
    for (int nt = 0; nt < 8; nt++)
        acc[nt] = __builtin_amdgcn_mfma_f32_16x16x32_bf16(a0, wfrag[(0 * 8 + nt) * 64 + lane], acc[nt], 0, 0, 0);
#pragma unroll
    for (int nt = 0; nt < 8; nt++)
        acc[nt] = __builtin_amdgcn_mfma_f32_16x16x32_bf16(a1, wfrag[(1 * 8 + nt) * 64 + lane], acc[nt], 0, 0, 0);
#pragma unroll
    for (int nt = 0; nt < 8; nt++)
        acc[nt] = __builtin_amdgcn_mfma_f32_16x16x32_bf16(a2, wfrag[(2 * 8 + nt) * 64 + lane], acc[nt], 0, 0, 0);
#pragma unroll
    for (int nt = 0; nt < 8; nt++)
        acc[nt] = __builtin_amdgcn_mfma_f32_16x16x32_bf16(a3, wfrag[(3 * 8 + nt) * 64 + lane], acc[nt], 0, 0, 0);
    __syncthreads();  // all wF reads done -> staging overlay

    ushort_t* ss = wF + wv * 16 * STG_S;
#pragma unroll
    for (int nt = 0; nt < 8; nt++)
#pragma unroll
        for (int rg = 0; rg < 4; rg++)
            ss[(q * 4 + rg) * STG_S + nt * 16 + r] = f2b(acc[nt][rg]);

    const uint4* nip = (const uint4*)(fni + (size_t)sv * DIM + qq * 32);
    const uint4* njp = (const uint4*)(fnj + (size_t)dv * DIM + qq * 32);
    const uint4* sp = (const uint4*)(ss + el * STG_S + qq * 32);
    uint4 outv[4];
    float p = 0.f;
#pragma unroll
    for (int cc = 0; cc < 4; cc++) {
        uint4 avq = sp[cc];
        uint4 niq = nip[cc];
        uint4 njq = njp[cc];
#pragma unroll
        for (int u = 0; u < 4; u++) {
            unsigned int aw = ((const unsigned int*)&avq)[u];
            unsigned int nw = ((const unsigned int*)&niq)[u];
            unsigned int jw = ((const unsigned int*)&njq)[u];
            int c = qq * 32 + cc * 8 + u * 2;
            float v0 = blo(aw) + blo(nw) + blo(jw) + bias[c];
            float v1 = bhi(aw) + bhi(nw) + bhi(jw) + bias[c + 1];
            v0 = v0 > 0.f ? v0 : 0.01f * v0;
            v1 = v1 > 0.f ? v1 : 0.01f * v1;
            ((unsigned int*)&outv[cc])[u] =
                (unsigned int)f2b(v0) | ((unsigned int)f2b(v1) << 16);
            p += v0 * attn[c] + v1 * attn[c + 1];
        }
    }
    uint4* ep = (uint4*)(e + eid * DIM + qq * 32);
#pragma unroll
    for (int cc = 0; cc < 4; cc++) ep[cc] = outv[cc];
    p += __shfl_xor(p, 1);
    p += __shfl_xor(p, 2);
    if (qq == 0) score[eid] = p;
}

// ---------------- layer-0 edge kernel (permuted order) ----------------
__global__ __launch_bounds__(256) void edge0(
    const int* __restrict__ ptok, const float* __restrict__ eftab,
    const ushort_t* __restrict__ fni, const ushort_t* __restrict__ fnj,
    const int* __restrict__ psrc, const int* __restrict__ pdst,
    const float* __restrict__ attn, const float* __restrict__ bias,
    ushort_t* __restrict__ e, float* __restrict__ score) {
    unsigned int gid = blockIdx.x * 256 + threadIdx.x;
    unsigned int eid = gid >> 5;
    int cq = gid & 31, c0 = cq * 4;
    int tok = ptok[eid];
    int sv = psrc[eid], dv = pdst[eid];
    float4 t = *(const float4*)&eftab[tok * DIM + c0];
    uint2 niw = *(const uint2*)(fni + (size_t)sv * DIM + c0);
    uint2 njw = *(const uint2*)(fnj + (size_t)dv * DIM + c0);
    float v0 = t.x + blo(niw.x) + blo(njw.x) + bias[c0];
    float v1 = t.y + bhi(niw.x) + bhi(njw.x) + bias[c0 + 1];
    float v2 = t.z + blo(niw.y) + blo(njw.y) + bias[c0 + 2];
    float v3 = t.w + bhi(niw.y) + bhi(njw.y) + bias[c0 + 3];
    v0 = v0 > 0.f ? v0 : 0.01f * v0;
    v1 = v1 > 0.f ? v1 : 0.01f * v1;
    v2 = v2 > 0.f ? v2 : 0.01f * v2;
    v3 = v3 > 0.f ? v3 : 0.01f * v3;
    *(uint2*)(e + (size_t)eid * DIM + c0) = pack4(make_float4(v0, v1, v2, v3));
    float p = v0 * attn[c0] + v1 * attn[c0 + 1] + v2 * attn[c0 + 2] + v3 * attn[c0 + 3];
#pragma unroll
    for (int o = 1; o < 32; o <<= 1) p += __shfl_xor(p, o);
    if (cq == 0) score[eid] = p;
}

// ---------------- wave-per-node softmax + aggregation: unroll-4 gathers ----------------
__global__ __launch_bounds__(256) void agg_wave(
    const int* __restrict__ off, const int* __restrict__ psrc,
    const float* __restrict__ score, const ushort_t* __restrict__ hs,
    ushort_t* __restrict__ h) {
    int node = blockIdx.x * 4 + (threadIdx.x >> 6);
    int lane = threadIdx.x & 63;
    int b0 = off[node];
    int deg = off[node + 1] - b0;

    float m = -1e30f;
    for (int j = lane; j < deg; j += 64) m = fmaxf(m, score[b0 + j]);
#pragma unroll
    for (int o = 32; o > 0; o >>= 1) m = fmaxf(m, __shfl_xor(m, o));
    float se = 0.f;
    for (int j = lane; j < deg; j += 64) se += __expf(score[b0 + j] - m);
#pragma unroll
    for (int o = 32; o > 0; o >>= 1) se += __shfl_xor(se, o);
    float inv = (deg > 0) ? 1.f / se : 0.f;

    float acc0 = 0.f, acc1 = 0.f;
    for (int base = 0; base < deg; base += 64) {
        int cnt = min(64, deg - base);
        float wgt = 0.f;
        int sidx = 0;
        if (lane < cnt) {
            wgt = __expf(score[b0 + base + lane] - m) * inv;
            sidx = psrc[b0 + base + lane];
        }
        int i = 0;
        for (; i + 4 <= cnt; i += 4) {
            float w0 = __shfl(wgt, i), w1 = __shfl(wgt, i + 1);
            float w2 = __shfl(wgt, i + 2), w3 = __shfl(wgt, i + 3);
            int s0 = __shfl(sidx, i), s1 = __shfl(sidx, i + 1);
            int s2 = __shfl(sidx, i + 2), s3 = __shfl(sidx, i + 3);
            unsigned int h0 = *(const unsigned int*)(hs + (size_t)s0 * DIM + lane * 2);
            unsigned int h1 = *(const unsigned int*)(hs + (size_t)s1 * DIM + lane * 2);
            unsigned int h2 = *(const unsigned int*)(hs + (size_t)s2 * DIM + lane * 2);
            unsigned int h3 = *(const unsigned int*)(hs + (size_t)s3 * DIM + lane * 2);
            acc0 += w0 * blo(h0); acc1 += w0 * bhi(h0);
            acc0 += w1 * blo(h1); acc1 += w1 * bhi(h1);
            acc0 += w2 * blo(h2); acc1 += w2 * bhi(h2);
            acc0 += w3 * blo(h3); acc1 += w3 * bhi(h3);
        }
        for (; i < cnt; i++) {
            float wi = __shfl(wgt, i);
            int si = __shfl(sidx, i);
            unsigned int hv = *(const unsigned int*)(hs + (size_t)si * DIM + lane * 2);
            acc0 += wi * blo(hv);
            acc1 += wi * bhi(hv);
        }
    }
    unsigned int outp = (unsigned int)f2b(fmaxf(acc0, 0.f)) |
                        ((unsigned int)f2b(fmaxf(acc1, 0.f)) << 16);
    *(unsigned int*)(h + (size_t)node * DIM + lane * 2) = outp;
}

// ---------------- sort each node's 128 features ascending ----------------
__global__ __launch_bounds__(128) void sort_rows(const float* __restrict__ h2,
                                                 float* __restrict__ hsort,
                                                 float* __restrict__ maxval) {
    __shared__ float buf[128];
    int n = blockIdx.x, t = threadIdx.x;
    buf[t] = h2[(size_t)n * DIM + t];
    __syncthreads();
    for (int k = 2; k <= 128; k <<= 1) {
        for (int j = k >> 1; j > 0; j >>= 1) {
            int ixj = t ^ j;
            float a = buf[t], b = buf[ixj];
            __syncthreads();
            bool up = ((t & k) == 0);
            float mn = fminf(a, b), mx = fmaxf(a, b);
            buf[t] = up ? ((t < ixj) ? mn : mx) : ((t < ixj) ? mx : mn);
            __syncthreads();
        }
    }
    hsort[(size_t)n * DIM + t] = buf[t];
    if (t == 127) maxval[n] = buf[127];
}

// ---------------- per-graph top-k + gather pooled rows ----------------
__global__ __launch_bounds__(256) void topk_pool(const float* __restrict__ maxval,
                                                 const float* __restrict__ hsort,
                                                 float* __restrict__ pooled) {
    __shared__ float v[256];
    __shared__ int id[256];
    int b = blockIdx.x, t = threadIdx.x;
    v[t] = (t < NPG) ? maxval[b * NPG + t] : -1e30f;
    id[t] = t;
    __syncthreads();
    for (int k = 2; k <= 256; k <<= 1) {
        for (int j = k >> 1; j > 0; j >>= 1) {
            int ixj = t ^ j;
            float va = v[t], vb = v[ixj];
            int ia = id[t], ib = id[ixj];
            __syncthreads();
            bool dirDesc = ((t & k) == 0);
            bool cmp = (va > vb) || (va == vb && ia < ib);
            bool takeMine = ((t < ixj) == (dirDesc == cmp));
            v[t] = takeMine ? va : vb;
            id[t] = takeMine ? ia : ib;
            __syncthreads();
        }
    }
    for (int i = t; i < KPOOL * DIM; i += 256) {
        int kk = i >> 7, d = i & 127;
        pooled[((size_t)b * KPOOL + kk) * DIM + d] = hsort[((size_t)b * NPG + id[kk]) * DIM + d];
    }
}

// ---------------- ft split-K ----------------
__global__ __launch_bounds__(256) void ft_partial(
    const float* __restrict__ pooled, const float* __restrict__ W3,
    float* __restrict__ part) {
    __shared__ float ps[512];
    __shared__ float red[256];
    int b = blockIdx.x, s = blockIdx.y;
    int t = threadIdx.x;
    int d = t & 127, half = t >> 7;
    for (int i = t; i < 512; i += 256) ps[i] = pooled[(size_t)b * 4096 + s * 512 + i];
    __syncthreads();
    float acc = 0.f;
    const float* Wp = W3 + (size_t)(s * 512 + half * 256) * DIM + d;
    const float* pp = ps + half * 256;
#pragma unroll 4
    for (int kk = 0; kk < 256; kk++) acc += pp[kk] * Wp[(size_t)kk * DIM];
    red[t] = acc;
    __syncthreads();
    if (t < 128) part[((size_t)b * 8 + s) * DIM + t] = red[t] + red[t + 128];
}

__global__ __launch_bounds__(128) void ft_reduce(
    const float* __restrict__ part, const float* __restrict__ al3,
    const float* __restrict__ ar3, float* __restrict__ ft,
    float* __restrict__ sl, float* __restrict__ sr) {
    __shared__ float r1[128], r2[128];
    int b = blockIdx.x, d = threadIdx.x;
    float acc = 0.f;
#pragma unroll
    for (int s = 0; s < 8; s++) acc += part[((size_t)b * 8 + s) * DIM + d];
    ft[b * DIM + d] = acc;
    r1[d] = acc * al3[d];
    r2[d] = acc * ar3[d];
    __syncthreads();
    for (int s = 64; s > 0; s >>= 1) {
        if (d < s) { r1[d] += r1[d + s]; r2[d] += r2[d + s]; }
        __syncthreads();
    }
    if (d == 0) { sl[b] = r1[0]; sr[b] = r2[0]; }
}

// ---------------- final-graph GAT ----------------
__global__ __launch_bounds__(128) void fg_kernel(
    const int* __restrict__ fg_src, const int* __restrict__ fg_dst,
    const float* __restrict__ sl, const float* __restrict__ sr,
    const float* __restrict__ ft, const float* __restrict__ b3,
    float* __restrict__ g) {
    __shared__ int list[EFE];
    __shared__ float wgt[EFE];
    __shared__ float red[128];
    __shared__ int cnt;
    int b = blockIdx.x, t = threadIdx.x;
    if (t == 0) cnt = 0;
    __syncthreads();
    for (int e = t; e < EFE; e += 128)
        if (fg_dst[e] == b) { int p = atomicAdd(&cnt, 1); list[p] = e; }
    __syncthreads();
    int deg = cnt;
    float srb = sr[b];
    float m = -1e30f;
    for (int j = t; j < deg; j += 128) {
        float s = sl[fg_src[list[j]]] + srb;
        s = s > 0.f ? s : 0.2f * s;
        m = fmaxf(m, s);
    }
    red[t] = m;
    __syncthreads();
    for (int s = 64; s > 0; s >>= 1) { if (t < s) red[t] = fmaxf(red[t], red[t + s]); __syncthreads(); }
    m = red[0];
    __syncthreads();
    float se = 0.f;
    for (int j = t; j < deg; j += 128) {
        float s = sl[fg_src[list[j]]] + srb;
        s = s > 0.f ? s : 0.2f * s;
        se += __expf(s - m);
    }
    red[t] = se;
    __syncthreads();
    for (int s = 64; s > 0; s >>= 1) { if (t < s) red[t] += red[t + s]; __syncthreads(); }
    float inv = (deg > 0) ? 1.f / red[0] : 0.f;
    __syncthreads();
    for (int j = t; j < deg; j += 128) {
        float s = sl[fg_src[list[j]]] + srb;
        s = s > 0.f ? s : 0.2f * s;
        wgt[j] = __expf(s - m) * inv;
    }
    __syncthreads();
    float acc = 0.f;
    for (int j = 0; j < deg; j++) acc += wgt[j] * ft[(size_t)fg_src[list[j]] * DIM + t];
    g[b * DIM + t] = fmaxf(acc + b3[t], 0.f);
}

// ---------------- g2 = relu(g @ Wl + bl) ----------------
__global__ __launch_bounds__(128) void gl_kernel(const float* __restrict__ g,
                                                 const float* __restrict__ Wl,
                                                 const float* __restrict__ bl,
                                                 float* __restrict__ g2) {
    __shared__ float gs[128];
    int b = blockIdx.x, d = threadIdx.x;
    gs[d] = g[b * DIM + d];
    __syncthreads();
    float acc = 0.f;
    for (int k = 0; k < 128; k++) acc += gs[k] * Wl[k * DIM + d];
    g2[b * DIM + d] = fmaxf(acc + bl[d], 0.f);
}

// ---------------- out = g2 @ Wc + bc ----------------
__global__ __launch_bounds__(256) void out_kernel(const float* __restrict__ g2,
                                                  const float* __restrict__ Wc,
                                                  const float* __restrict__ bc,
                                                  float* __restrict__ out) {
    int i = threadIdx.x;
    int b = i >> 1, j = i & 1;
    float acc = bc[j];
    for (int k = 0; k < 128; k++) acc += g2[b * DIM + k] * Wc[k * 2 + j];
    out[b * 2 + j] = acc;
}

extern "C" void kernel_launch(void* const* d_in, const int* in_sizes, int n_in,
                              void* d_out, int out_size, void* d_ws, size_t ws_size,
                              hipStream_t stream) {
    const int* tokens_h = (const int*)d_in[0];
    const int* tokens_e = (const int*)d_in[1];
    const int* src = (const int*)d_in[2];
    const int* dst = (const int*)d_in[3];
    const int* fg_src = (const int*)d_in[4];
    const int* fg_dst = (const int*)d_in[5];
    const float* token_emb = (const float*)d_in[6];
    const float* e_token_emb = (const float*)d_in[7];
    const float* W_ni = (const float*)d_in[8];
    const float* W_nj = (const float*)d_in[9];
    const float* W_fij = (const float*)d_in[10];
    const float* W_node = (const float*)d_in[11];
    const float* attn_e = (const float*)d_in[12];
    const float* bias_e = (const float*)d_in[13];
    const float* Wf = (const float*)d_in[14];
    const float* bf_ = (const float*)d_in[15];
    const float* W3 = (const float*)d_in[16];
    const float* al3 = (const float*)d_in[17];
    const float* ar3 = (const float*)d_in[18];
    const float* b3 = (const float*)d_in[19];
    const float* Wl = (const float*)d_in[20];
    const float* bl = (const float*)d_in[21];
    const float* Wc = (const float*)d_in[22];
    const float* bc = (const float*)d_in[23];
    float* out = (float*)d_out;

    char* w = (char*)d_ws;
    auto alloc = [&](size_t b) -> char* {
        char* p = w;
        w += (b + 255) & ~(size_t)255;
        return p;
    };
    ushort_t* h = (ushort_t*)alloc((size_t)N_NODES * DIM * 2);
    ushort_t* fni = (ushort_t*)alloc((size_t)N_NODES * DIM * 2);
    ushort_t* fnj = (ushort_t*)alloc((size_t)N_NODES * DIM * 2);
    ushort_t* hs = (ushort_t*)alloc((size_t)N_NODES * DIM * 2);
    ushort_t* e = (ushort_t*)alloc((size_t)N_EDGES * DIM * 2);
    float* score = (float*)alloc((size_t)N_EDGES * 4);
    int* deg = (int*)alloc((size_t)N_NODES * 4);
    int* off = (int*)alloc((size_t)(N_NODES + 1) * 4);
    int* cursor = (int*)alloc((size_t)N_NODES * 4);
    int* bsum = (int*)alloc(64 * 4);
    int* psrc = (int*)alloc((size_t)N_EDGES * 4);
    int* pdst = (int*)alloc((size_t)N_EDGES * 4);
    int* ptok = (int*)alloc((size_t)N_EDGES * 4);
    float* eftab = (float*)alloc(100 * DIM * 4);
    float* maxval = (float*)alloc((size_t)N_NODES * 4);
    float* pooled = (float*)alloc((size_t)BGR * KPOOL * DIM * 4);
    float* ft = (float*)alloc(BGR * DIM * 4);
    float* part = (float*)alloc((size_t)BGR * 8 * DIM * 4);
    float* sl = (float*)alloc(BGR * 4);
    float* sr = (float*)alloc(BGR * 4);
    float* g = (float*)alloc(BGR * DIM * 4);
    float* g2 = (float*)alloc(BGR * DIM * 4);
    ushort_t* Wf7 = (ushort_t*)alloc((size_t)NLAYERS * DIM * DIM * 2);
    ushort_t* Wn = (ushort_t*)alloc((size_t)3 * NLAYERS * DIM * DIM * 2);
    float* h2 = (float*)e;
    float* hsort = (float*)((char*)e + (size_t)16 * 1024 * 1024);

    // weight prep
    wfprep<<<(NLAYERS * DIM * DIM) / 256, 256, 0, stream>>>(W_fij, Wf7);
    wnprep<<<(3 * NLAYERS * DIM * DIM) / 256, 256, 0, stream>>>(W_ni, W_nj, W_node, Wn);

    // CSR build + edge permutation (dst-sorted order), hierarchical scan
    zero_deg<<<(N_NODES + 255) / 256, 256, 0, stream>>>(deg, N_NODES);
    count_deg<<<N_EDGES / 256, 256, 0, stream>>>(dst, deg, N_EDGES);
    scan_local<<<(N_NODES + 1023) / 1024, 1024, 0, stream>>>(deg, off, bsum, N_NODES);
    scan_bsum<<<1, 32, 0, stream>>>(bsum, (N_NODES + 1023) / 1024);
    scan_add<<<(N_NODES + 255) / 256, 256, 0, stream>>>(off, bsum, cursor, N_NODES, N_EDGES);
    scatter_perm<<<N_EDGES / 256, 256, 0, stream>>>(src, dst, tokens_e, cursor,
                                                    psrc, pdst, ptok, N_EDGES);

    init_h<<<(N_NODES * DIM) / 256, 256, 0, stream>>>(tokens_h, token_emb, h);
    eftab_kernel<<<100, 128, 0, stream>>>(e_token_emb, W_fij, eftab);

    for (int l = 0; l < NLAYERS; l++) {
        node_gemm_mfma<<<dim3(N_NODES / 64, 3), 256, 0, stream>>>(
            h, Wn + l * 16384, fni, fnj, hs);
        if (l == 0) {
            edge0<<<(N_EDGES * 32) / 256, 256, 0, stream>>>(
                ptok, eftab, fni, fnj, psrc, pdst, attn_e, bias_e, e, score);
        } else {
            edge_gemm_mfma<<<N_EDGES / 64, 256, 0, stream>>>(
                e, fni, fnj, psrc, pdst, Wf7 + l * DIM * DIM,
                attn_e + l * DIM, bias_e + l * DIM, score);
        }
        agg_wave<<<N_NODES / 4, 256, 0, stream>>>(off, psrc, score, hs, h);
    }

    node_gemm1<<<N_NODES / 64, 256, 0, stream>>>(h, Wf, bf_, h2);
    sort_rows<<<N_NODES, 128, 0, stream>>>(h2, hsort, maxval);
    topk_pool<<<BGR, 256, 0, stream>>>(maxval, hsort, pooled);
    ft_partial<<<dim3(BGR, 8), 256, 0, stream>>>(pooled, W3, part);
    ft_reduce<<<BGR, 128, 0, stream>>>(part, al3, ar3, ft, sl, sr);
    fg_kernel<<<BGR, 128, 0, stream>>>(fg_src, fg_dst, sl, sr, ft, b3, g);
    gl_kernel<<<BGR, 128, 0, stream>>>(g, Wl, bl, g2);
    out_kernel<<<1, 256, 0, stream>>>(g2, Wc, bc, out);
}

// Round 13
// 1296.135 us; speedup vs baseline: 1.3269x; 1.0618x over previous
//
#include <hip/hip_runtime.h>

#define N_NODES 25600
#define N_EDGES 409600
#define BGR 128
#define EFE 1024
#define DIM 128
#define NLAYERS 8
#define KPOOL 32
#define NPG 200

typedef unsigned short ushort_t;
typedef __attribute__((ext_vector_type(8))) short bf16x8;
typedef __attribute__((ext_vector_type(4))) float f32x4;

#define STG_S 144  // per-wave C-staging stride (bf16 elems)

__device__ __forceinline__ float b2f(ushort_t v) {
    return __uint_as_float(((unsigned int)v) << 16);
}
__device__ __forceinline__ float blo(unsigned int u) {
    return __uint_as_float(u << 16);
}
__device__ __forceinline__ float bhi(unsigned int u) {
    return __uint_as_float(u & 0xffff0000u);
}
__device__ __forceinline__ ushort_t f2b(float f) {
    unsigned int u = __float_as_uint(f);
    unsigned int r = (u + 0x7fffu + ((u >> 16) & 1u)) >> 16;
    return (ushort_t)r;
}
__device__ __forceinline__ uint2 pack4(float4 v) {
    uint2 p;
    p.x = (unsigned int)f2b(v.x) | ((unsigned int)f2b(v.y) << 16);
    p.y = (unsigned int)f2b(v.z) | ((unsigned int)f2b(v.w) << 16);
    return p;
}

// ---------------- W_fij -> fragment-linear bf16 (proven R6) ----------------
__global__ void wfprep(const float* __restrict__ W, ushort_t* __restrict__ Wf) {
    int idx = blockIdx.x * 256 + threadIdx.x;  // 8 * 16384
    int l = idx >> 14, rem = idx & 16383;
    int j = rem & 7, lane = (rem >> 3) & 63, nt = (rem >> 9) & 7, kc = rem >> 12;
    int q = lane >> 4, r = lane & 15;
    int k = kc * 32 + q * 8 + j, n = nt * 16 + r;
    Wf[idx] = f2b(W[l * 16384 + k * 128 + n]);
}

// W_ni / W_nj / W_node -> fragment-linear bf16, layout [m][l][16384]
__global__ void wnprep(const float* __restrict__ Wni, const float* __restrict__ Wnj,
                       const float* __restrict__ Wnode, ushort_t* __restrict__ Wn) {
    int idx = blockIdx.x * 256 + threadIdx.x;  // 3 * 8 * 16384
    int m = idx >> 17;
    int l = (idx >> 14) & 7;
    int rem = idx & 16383;
    int j = rem & 7, lane = (rem >> 3) & 63, nt = (rem >> 9) & 7, kc = rem >> 12;
    int q = lane >> 4, r = lane & 15;
    int k = kc * 32 + q * 8 + j, n = nt * 16 + r;
    const float* W = (m == 0) ? Wni : (m == 1) ? Wnj : Wnode;
    Wn[idx] = f2b(W[l * 16384 + k * 128 + n]);
}

// ---------------- zero deg ----------------
__global__ void zero_deg(int* __restrict__ deg, int n) {
    int i = blockIdx.x * 256 + threadIdx.x;
    if (i < n) deg[i] = 0;
}

// ---------------- CSR build ----------------
__global__ void count_deg(const int* __restrict__ dst, int* __restrict__ deg, int n) {
    int i = blockIdx.x * 256 + threadIdx.x;
    if (i < n) atomicAdd(&deg[dst[i]], 1);
}

// hierarchical scan
__global__ __launch_bounds__(1024) void scan_local(const int* __restrict__ deg,
                                                   int* __restrict__ off,
                                                   int* __restrict__ bsum, int n) {
    __shared__ int buf[1024];
    int b = blockIdx.x, t = threadIdx.x;
    int gi = b * 1024 + t;
    int v = (gi < n) ? deg[gi] : 0;
    buf[t] = v;
    __syncthreads();
    for (int s = 1; s < 1024; s <<= 1) {
        int x = (t >= s) ? buf[t - s] : 0;
        __syncthreads();
        buf[t] += x;
        __syncthreads();
    }
    if (gi < n) off[gi] = buf[t] - v;
    if (t == 1023) bsum[b] = buf[1023];
}

__global__ void scan_bsum(int* __restrict__ bsum, int nb) {
    if (threadIdx.x == 0) {
        int acc = 0;
        for (int i = 0; i < nb; i++) { int v = bsum[i]; bsum[i] = acc; acc += v; }
    }
}

__global__ void scan_add(int* __restrict__ off, const int* __restrict__ bsum,
                         int* __restrict__ cursor, int n, int total) {
    int i = blockIdx.x * 256 + threadIdx.x;
    if (i < n) {
        int v = off[i] + bsum[i >> 10];
        off[i] = v;
        cursor[i] = v;
    }
    if (i == 0) off[n] = total;
}

__global__ void scatter_perm(const int* __restrict__ src, const int* __restrict__ dst,
                             const int* __restrict__ tokens_e, int* __restrict__ cursor,
                             int* __restrict__ psrc, int* __restrict__ pdst,
                             int* __restrict__ ptok, int n) {
    int i = blockIdx.x * 256 + threadIdx.x;
    if (i < n) {
        int p = atomicAdd(&cursor[dst[i]], 1);
        psrc[p] = src[i];
        pdst[p] = dst[i];
        ptok[p] = tokens_e[i];
    }
}

// ---------------- init (h bf16) ----------------
__global__ void init_h(const int* __restrict__ tok, const float* __restrict__ emb,
                       ushort_t* __restrict__ h) {
    int i = blockIdx.x * 256 + threadIdx.x;
    int r = i >> 7, d = i & 127;
    float v = emb[tok[r] * DIM + d];
    h[i] = f2b(fmaxf(v, 0.f));
}

__global__ __launch_bounds__(128) void eftab_kernel(const float* __restrict__ etab,
                                                    const float* __restrict__ W,
                                                    float* __restrict__ out) {
    int r = blockIdx.x, d = threadIdx.x;
    float acc = 0.f;
    for (int k = 0; k < DIM; k++)
        acc += etab[r * DIM + k] * W[k * DIM + d];
    out[r * DIM + d] = acc;
}

// ---------------- MFMA node GEMM: grid (400, 3) ----------------
__global__ __launch_bounds__(256, 4) void node_gemm_mfma(
    const ushort_t* __restrict__ h,
    const ushort_t* __restrict__ Wn,
    ushort_t* __restrict__ C0, ushort_t* __restrict__ C1, ushort_t* __restrict__ C2) {
    __shared__ __align__(16) ushort_t wF[16384];
    int tid = threadIdx.x, wv = tid >> 6, lane = tid & 63;
    int r = lane & 15, q = lane >> 4;
    int el = lane >> 2, qq = lane & 3;
    int m = blockIdx.y;
    size_t row = (size_t)blockIdx.x * 64 + 16 * wv;

    const ushort_t* aRow = h + (row + r) * DIM + q * 8;
    bf16x8 a0 = *(const bf16x8*)(aRow);
    bf16x8 a1 = *(const bf16x8*)(aRow + 32);
    bf16x8 a2 = *(const bf16x8*)(aRow + 64);
    bf16x8 a3 = *(const bf16x8*)(aRow + 96);

    {
        const uint4* wg = (const uint4*)(Wn + (size_t)m * NLAYERS * 16384);
        uint4* ws = (uint4*)wF;
        for (int i = tid; i < 2048; i += 256) ws[i] = wg[i];
    }
    __syncthreads();

    f32x4 acc[8] = {};
    const bf16x8* wfrag = (const bf16x8*)wF;
#pragma unroll
    for (int nt = 0; nt < 8; nt++)
        acc[nt] = __builtin_amdgcn_mfma_f32_16x16x32_bf16(a0, wfrag[(0 * 8 + nt) * 64 + lane], acc[nt], 0, 0, 0);
#pragma unroll
    for (int nt = 0; nt < 8; nt++)
        acc[nt] = __builtin_amdgcn_mfma_f32_16x16x32_bf16(a1, wfrag[(1 * 8 + nt) * 64 + lane], acc[nt], 0, 0, 0);
#pragma unroll
    for (int nt = 0; nt < 8; nt++)
        acc[nt] = __builtin_amdgcn_mfma_f32_16x16x32_bf16(a2, wfrag[(2 * 8 + nt) * 64 + lane], acc[nt], 0, 0, 0);
#pragma unroll
    for (int nt = 0; nt < 8; nt++)
        acc[nt] = __builtin_amdgcn_mfma_f32_16x16x32_bf16(a3, wfrag[(3 * 8 + nt) * 64 + lane], acc[nt], 0, 0, 0);
    __syncthreads();

    ushort_t* ss = wF + wv * 16 * STG_S;
#pragma unroll
    for (int nt = 0; nt < 8; nt++)
#pragma unroll
        for (int rg = 0; rg < 4; rg++)
            ss[(q * 4 + rg) * STG_S + nt * 16 + r] = f2b(acc[nt][rg]);

    ushort_t* Cp = (m == 0) ? C0 : (m == 1) ? C1 : C2;
    const uint4* sp = (const uint4*)(ss + el * STG_S + qq * 32);
    uint4* cp = (uint4*)(Cp + (row + el) * DIM + qq * 32);
#pragma unroll
    for (int cc = 0; cc < 4; cc++) cp[cc] = sp[cc];
}

// single-W with bias + relu (final Wf): h bf16 in, fp32 out
__global__ __launch_bounds__(256) void node_gemm1(
    const ushort_t* __restrict__ A, const float* __restrict__ W,
    const float* __restrict__ bias, float* __restrict__ C) {
    __shared__ float As[64 * 128];
    __shared__ uint2 Ws4[128 * 32];
    int tid = threadIdx.x;
    size_t row0 = (size_t)blockIdx.x * 64;
    const uint2* Ag = (const uint2*)(A + row0 * DIM);
    for (int f = tid; f < 64 * 32; f += 256) {
        uint2 v = Ag[f];
        ((float4*)As)[f] = make_float4(blo(v.x), bhi(v.x), blo(v.y), bhi(v.y));
    }
    const float4* Wg = (const float4*)W;
    for (int i = tid; i < 128 * 32; i += 256) Ws4[i] = pack4(Wg[i]);
    __syncthreads();
    int cq = tid & 31, r0 = (tid >> 5) * 8, c0 = cq * 4;
    float acc[8][4] = {};
    for (int k = 0; k < 128; k++) {
        uint2 wp = Ws4[k * 32 + cq];
        float w0 = blo(wp.x), w1 = bhi(wp.x), w2 = blo(wp.y), w3 = bhi(wp.y);
#pragma unroll
        for (int i = 0; i < 8; i++) {
            float a = As[(r0 + i) * 128 + k];
            acc[i][0] += a * w0; acc[i][1] += a * w1;
            acc[i][2] += a * w2; acc[i][3] += a * w3;
        }
    }
    float b0 = bias[c0], b1 = bias[c0 + 1], b2v = bias[c0 + 2], b3v = bias[c0 + 3];
#pragma unroll
    for (int i = 0; i < 8; i++) {
        *(float4*)&C[(row0 + r0 + i) * DIM + c0] =
            make_float4(fmaxf(acc[i][0] + b0, 0.f), fmaxf(acc[i][1] + b1, 0.f),
                        fmaxf(acc[i][2] + b2v, 0.f), fmaxf(acc[i][3] + b3v, 0.f));
    }
}

// ---------------- MFMA edge GEMM: R10 proven config (256 thr, (256,4), 32 KB LDS) ----------------
__global__ __launch_bounds__(256, 4) void edge_gemm_mfma(
    ushort_t* __restrict__ e,
    const ushort_t* __restrict__ fni, const ushort_t* __restrict__ fnj,
    const int* __restrict__ psrc, const int* __restrict__ pdst,
    const ushort_t* __restrict__ Wf,
    const float* __restrict__ attn, const float* __restrict__ bias,
    float* __restrict__ score) {
    __shared__ __align__(16) ushort_t wF[16384];  // 32 KB; staging overlays after barrier

    int tid = threadIdx.x;
    int wv = tid >> 6, lane = tid & 63;
    int r = lane & 15, q = lane >> 4;
    int el = lane >> 2, qq = lane & 3;
    size_t row = (size_t)blockIdx.x * 64 + 16 * wv;
    size_t eid = row + el;

    int sv = psrc[eid], dv = pdst[eid];

    const ushort_t* aRow = e + (row + r) * DIM + q * 8;
    bf16x8 a0 = *(const bf16x8*)(aRow);
    bf16x8 a1 = *(const bf16x8*)(aRow + 32);
    bf16x8 a2 = *(const bf16x8*)(aRow + 64);
    bf16x8 a3 = *(const bf16x8*)(aRow + 96);

    {
        const uint4* wg = (const uint4*)Wf;
        uint4* ws = (uint4*)wF;
        for (int i = tid; i < 2048; i += 256) ws[i] = wg[i];
    }
    __syncthreads();

    f32x4 acc[8] = {};
    const bf16x8* wfrag = (const bf16x8*)wF;
#pragma unroll
    for (int nt = 0; nt < 8; nt++)
        acc[nt] = __builtin_amdgcn_mfma_f32_16x16x32_bf16(a0, wfrag[(0 * 8 + nt) * 64 + lane], acc[nt], 0, 0, 0);
#pragma unroll
    for (int nt = 0; nt < 8; nt++)
        acc[nt] = __builtin_amdgcn_mfma_f32_16x16x32_bf16(a1, wfrag[(1 * 8 + nt) * 64 + lane], acc[nt], 0, 0, 0);
#pragma unroll
    for (int nt = 0; nt < 8; nt++)
        acc[nt] = __builtin_amdgcn_mfma_f32_16x16x32_bf16(a2, wfrag[(2 * 8 + nt) * 64 + lane], acc[nt], 0, 0, 0);
#pragma unroll
    for (int nt = 0; nt < 8; nt++)
        acc[nt] = __builtin_amdgcn_mfma_f32_16x16x32_bf16(a3, wfrag[(3 * 8 + nt) * 64 + lane], acc[nt], 0, 0, 0);
    __syncthreads();  // all wF reads done -> staging overlay

    ushort_t* ss = wF + wv * 16 * STG_S;
#pragma unroll
    for (int nt = 0; nt < 8; nt++)
#pragma unroll
        for (int rg = 0; rg < 4; rg++)
            ss[(q * 4 + rg) * STG_S + nt * 16 + r] = f2b(acc[nt][rg]);

    const uint4* nip = (const uint4*)(fni + (size_t)sv * DIM + qq * 32);
    const uint4* njp = (const uint4*)(fnj + (size_t)dv * DIM + qq * 32);
    const uint4* sp = (const uint4*)(ss + el * STG_S + qq * 32);
    uint4 outv[4];
    float p = 0.f;
#pragma unroll
    for (int cc = 0; cc < 4; cc++) {
        uint4 avq = sp[cc];
        uint4 niq = nip[cc];
        uint4 njq = njp[cc];
#pragma unroll
        for (int u = 0; u < 4; u++) {
            unsigned int aw = ((const unsigned int*)&avq)[u];
            unsigned int nw = ((const unsigned int*)&niq)[u];
            unsigned int jw = ((const unsigned int*)&njq)[u];
            int c = qq * 32 + cc * 8 + u * 2;
            float v0 = blo(aw) + blo(nw) + blo(jw) + bias[c];
            float v1 = bhi(aw) + bhi(nw) + bhi(jw) + bias[c + 1];
            v0 = v0 > 0.f ? v0 : 0.01f * v0;
            v1 = v1 > 0.f ? v1 : 0.01f * v1;
            ((unsigned int*)&outv[cc])[u] =
                (unsigned int)f2b(v0) | ((unsigned int)f2b(v1) << 16);
            p += v0 * attn[c] + v1 * attn[c + 1];
        }
    }
    uint4* ep = (uint4*)(e + eid * DIM + qq * 32);
#pragma unroll
    for (int cc = 0; cc < 4; cc++) ep[cc] = outv[cc];
    p += __shfl_xor(p, 1);
    p += __shfl_xor(p, 2);
    if (qq == 0) score[eid] = p;
}

// ---------------- layer-0 edge kernel (permuted order) ----------------
__global__ __launch_bounds__(256) void edge0(
    const int* __restrict__ ptok, const float* __restrict__ eftab,
    const ushort_t* __restrict__ fni, const ushort_t* __restrict__ fnj,
    const int* __restrict__ psrc, const int* __restrict__ pdst,
    const float* __restrict__ attn, const float* __restrict__ bias,
    ushort_t* __restrict__ e, float* __restrict__ score) {
    unsigned int gid = blockIdx.x * 256 + threadIdx.x;
    unsigned int eid = gid >> 5;
    int cq = gid & 31, c0 = cq * 4;
    int tok = ptok[eid];
    int sv = psrc[eid], dv = pdst[eid];
    float4 t = *(const float4*)&eftab[tok * DIM + c0];
    uint2 niw = *(const uint2*)(fni + (size_t)sv * DIM + c0);
    uint2 njw = *(const uint2*)(fnj + (size_t)dv * DIM + c0);
    float v0 = t.x + blo(niw.x) + blo(njw.x) + bias[c0];
    float v1 = t.y + bhi(niw.x) + bhi(njw.x) + bias[c0 + 1];
    float v2 = t.z + blo(niw.y) + blo(njw.y) + bias[c0 + 2];
    float v3 = t.w + bhi(niw.y) + bhi(njw.y) + bias[c0 + 3];
    v0 = v0 > 0.f ? v0 : 0.01f * v0;
    v1 = v1 > 0.f ? v1 : 0.01f * v1;
    v2 = v2 > 0.f ? v2 : 0.01f * v2;
    v3 = v3 > 0.f ? v3 : 0.01f * v3;
    *(uint2*)(e + (size_t)eid * DIM + c0) = pack4(make_float4(v0, v1, v2, v3));
    float p = v0 * attn[c0] + v1 * attn[c0 + 1] + v2 * attn[c0 + 2] + v3 * attn[c0 + 3];
#pragma unroll
    for (int o = 1; o < 32; o <<= 1) p += __shfl_xor(p, o);
    if (cq == 0) score[eid] = p;
}

// ---------------- wave-per-node softmax + aggregation: unroll-4 gathers ----------------
__global__ __launch_bounds__(256) void agg_wave(
    const int* __restrict__ off, const int* __restrict__ psrc,
    const float* __restrict__ score, const ushort_t* __restrict__ hs,
    ushort_t* __restrict__ h) {
    int node = blockIdx.x * 4 + (threadIdx.x >> 6);
    int lane = threadIdx.x & 63;
    int b0 = off[node];
    int deg = off[node + 1] - b0;

    float m = -1e30f;
    for (int j = lane; j < deg; j += 64) m = fmaxf(m, score[b0 + j]);
#pragma unroll
    for (int o = 32; o > 0; o >>= 1) m = fmaxf(m, __shfl_xor(m, o));
    float se = 0.f;
    for (int j = lane; j < deg; j += 64) se += __expf(score[b0 + j] - m);
#pragma unroll
    for (int o = 32; o > 0; o >>= 1) se += __shfl_xor(se, o);
    float inv = (deg > 0) ? 1.f / se : 0.f;

    float acc0 = 0.f, acc1 = 0.f;
    for (int base = 0; base < deg; base += 64) {
        int cnt = min(64, deg - base);
        float wgt = 0.f;
        int sidx = 0;
        if (lane < cnt) {
            wgt = __expf(score[b0 + base + lane] - m) * inv;
            sidx = psrc[b0 + base + lane];
        }
        int i = 0;
        for (; i + 4 <= cnt; i += 4) {
            float w0 = __shfl(wgt, i), w1 = __shfl(wgt, i + 1);
            float w2 = __shfl(wgt, i + 2), w3 = __shfl(wgt, i + 3);
            int s0 = __shfl(sidx, i), s1 = __shfl(sidx, i + 1);
            int s2 = __shfl(sidx, i + 2), s3 = __shfl(sidx, i + 3);
            unsigned int h0 = *(const unsigned int*)(hs + (size_t)s0 * DIM + lane * 2);
            unsigned int h1 = *(const unsigned int*)(hs + (size_t)s1 * DIM + lane * 2);
            unsigned int h2 = *(const unsigned int*)(hs + (size_t)s2 * DIM + lane * 2);
            unsigned int h3 = *(const unsigned int*)(hs + (size_t)s3 * DIM + lane * 2);
            acc0 += w0 * blo(h0); acc1 += w0 * bhi(h0);
            acc0 += w1 * blo(h1); acc1 += w1 * bhi(h1);
            acc0 += w2 * blo(h2); acc1 += w2 * bhi(h2);
            acc0 += w3 * blo(h3); acc1 += w3 * bhi(h3);
        }
        for (; i < cnt; i++) {
            float wi = __shfl(wgt, i);
            int si = __shfl(sidx, i);
            unsigned int hv = *(const unsigned int*)(hs + (size_t)si * DIM + lane * 2);
            acc0 += wi * blo(hv);
            acc1 += wi * bhi(hv);
        }
    }
    unsigned int outp = (unsigned int)f2b(fmaxf(acc0, 0.f)) |
                        ((unsigned int)f2b(fmaxf(acc1, 0.f)) << 16);
    *(unsigned int*)(h + (size_t)node * DIM + lane * 2) = outp;
}

// ---------------- sort each node's 128 features ascending ----------------
__global__ __launch_bounds__(128) void sort_rows(const float* __restrict__ h2,
                                                 float* __restrict__ hsort,
                                                 float* __restrict__ maxval) {
    __shared__ float buf[128];
    int n = blockIdx.x, t = threadIdx.x;
    buf[t] = h2[(size_t)n * DIM + t];
    __syncthreads();
    for (int k = 2; k <= 128; k <<= 1) {
        for (int j = k >> 1; j > 0; j >>= 1) {
            int ixj = t ^ j;
            float a = buf[t], b = buf[ixj];
            __syncthreads();
            bool up = ((t & k) == 0);
            float mn = fminf(a, b), mx = fmaxf(a, b);
            buf[t] = up ? ((t < ixj) ? mn : mx) : ((t < ixj) ? mx : mn);
            __syncthreads();
        }
    }
    hsort[(size_t)n * DIM + t] = buf[t];
    if (t == 127) maxval[n] = buf[127];
}

// ---------------- per-graph top-k + gather pooled rows ----------------
__global__ __launch_bounds__(256) void topk_pool(const float* __restrict__ maxval,
                                                 const float* __restrict__ hsort,
                                                 float* __restrict__ pooled) {
    __shared__ float v[256];
    __shared__ int id[256];
    int b = blockIdx.x, t = threadIdx.x;
    v[t] = (t < NPG) ? maxval[b * NPG + t] : -1e30f;
    id[t] = t;
    __syncthreads();
    for (int k = 2; k <= 256; k <<= 1) {
        for (int j = k >> 1; j > 0; j >>= 1) {
            int ixj = t ^ j;
            float va = v[t], vb = v[ixj];
            int ia = id[t], ib = id[ixj];
            __syncthreads();
            bool dirDesc = ((t & k) == 0);
            bool cmp = (va > vb) || (va == vb && ia < ib);
            bool takeMine = ((t < ixj) == (dirDesc == cmp));
            v[t] = takeMine ? va : vb;
            id[t] = takeMine ? ia : ib;
            __syncthreads();
        }
    }
    for (int i = t; i < KPOOL * DIM; i += 256) {
        int kk = i >> 7, d = i & 127;
        pooled[((size_t)b * KPOOL + kk) * DIM + d] = hsort[((size_t)b * NPG + id[kk]) * DIM + d];
    }
}

// ---------------- ft split-K ----------------
__global__ __launch_bounds__(256) void ft_partial(
    const float* __restrict__ pooled, const float* __restrict__ W3,
    float* __restrict__ part) {
    __shared__ float ps[512];
    __shared__ float red[256];
    int b = blockIdx.x, s = blockIdx.y;
    int t = threadIdx.x;
    int d = t & 127, half = t >> 7;
    for (int i = t; i < 512; i += 256) ps[i] = pooled[(size_t)b * 4096 + s * 512 + i];
    __syncthreads();
    float acc = 0.f;
    const float* Wp = W3 + (size_t)(s * 512 + half * 256) * DIM + d;
    const float* pp = ps + half * 256;
#pragma unroll 4
    for (int kk = 0; kk < 256; kk++) acc += pp[kk] * Wp[(size_t)kk * DIM];
    red[t] = acc;
    __syncthreads();
    if (t < 128) part[((size_t)b * 8 + s) * DIM + t] = red[t] + red[t + 128];
}

__global__ __launch_bounds__(128) void ft_reduce(
    const float* __restrict__ part, const float* __restrict__ al3,
    const float* __restrict__ ar3, float* __restrict__ ft,
    float* __restrict__ sl, float* __restrict__ sr) {
    __shared__ float r1[128], r2[128];
    int b = blockIdx.x, d = threadIdx.x;
    float acc = 0.f;
#pragma unroll
    for (int s = 0; s < 8; s++) acc += part[((size_t)b * 8 + s) * DIM + d];
    ft[b * DIM + d] = acc;
    r1[d] = acc * al3[d];
    r2[d] = acc * ar3[d];
    __syncthreads();
    for (int s = 64; s > 0; s >>= 1) {
        if (d < s) { r1[d] += r1[d + s]; r2[d] += r2[d + s]; }
        __syncthreads();
    }
    if (d == 0) { sl[b] = r1[0]; sr[b] = r2[0]; }
}

// ---------------- final-graph GAT ----------------
__global__ __launch_bounds__(128) void fg_kernel(
    const int* __restrict__ fg_src, const int* __restrict__ fg_dst,
    const float* __restrict__ sl, const float* __restrict__ sr,
    const float* __restrict__ ft, const float* __restrict__ b3,
    float* __restrict__ g) {
    __shared__ int list[EFE];
    __shared__ float wgt[EFE];
    __shared__ float red[128];
    __shared__ int cnt;
    int b = blockIdx.x, t = threadIdx.x;
    if (t == 0) cnt = 0;
    __syncthreads();
    for (int e = t; e < EFE; e += 128)
        if (fg_dst[e] == b) { int p = atomicAdd(&cnt, 1); list[p] = e; }
    __syncthreads();
    int deg = cnt;
    float srb = sr[b];
    float m = -1e30f;
    for (int j = t; j < deg; j += 128) {
        float s = sl[fg_src[list[j]]] + srb;
        s = s > 0.f ? s : 0.2f * s;
        m = fmaxf(m, s);
    }
    red[t] = m;
    __syncthreads();
    for (int s = 64; s > 0; s >>= 1) { if (t < s) red[t] = fmaxf(red[t], red[t + s]); __syncthreads(); }
    m = red[0];
    __syncthreads();
    float se = 0.f;
    for (int j = t; j < deg; j += 128) {
        float s = sl[fg_src[list[j]]] + srb;
        s = s > 0.f ? s : 0.2f * s;
        se += __expf(s - m);
    }
    red[t] = se;
    __syncthreads();
    for (int s = 64; s > 0; s >>= 1) { if (t < s) red[t] += red[t + s]; __syncthreads(); }
    float inv = (deg > 0) ? 1.f / red[0] : 0.f;
    __syncthreads();
    for (int j = t; j < deg; j += 128) {
        float s = sl[fg_src[list[j]]] + srb;
        s = s > 0.f ? s : 0.2f * s;
        wgt[j] = __expf(s - m) * inv;
    }
    __syncthreads();
    float acc = 0.f;
    for (int j = 0; j < deg; j++) acc += wgt[j] * ft[(size_t)fg_src[list[j]] * DIM + t];
    g[b * DIM + t] = fmaxf(acc + b3[t], 0.f);
}

// ---------------- g2 = relu(g @ Wl + bl) ----------------
__global__ __launch_bounds__(128) void gl_kernel(const float* __restrict__ g,
                                                 const float* __restrict__ Wl,
                                                 const float* __restrict__ bl,
                                                 float* __restrict__ g2) {
    __shared__ float gs[128];
    int b = blockIdx.x, d = threadIdx.x;
    gs[d] = g[b * DIM + d];
    __syncthreads();
    float acc = 0.f;
    for (int k = 0; k < 128; k++) acc += gs[k] * Wl[k * DIM + d];
    g2[b * DIM + d] = fmaxf(acc + bl[d], 0.f);
}

// ---------------- out = g2 @ Wc + bc ----------------
__global__ __launch_bounds__(256) void out_kernel(const float* __restrict__ g2,
                                                  const float* __restrict__ Wc,
                                                  const float* __restrict__ bc,
                                                  float* __restrict__ out) {
    int i = threadIdx.x;
    int b = i >> 1, j = i & 1;
    float acc = bc[j];
    for (int k = 0; k < 128; k++) acc += g2[b * DIM + k] * Wc[k * 2 + j];
    out[b * 2 + j] = acc;
}

extern "C" void kernel_launch(void* const* d_in, const int* in_sizes, int n_in,
                              void* d_out, int out_size, void* d_ws, size_t ws_size,
                              hipStream_t stream) {
    const int* tokens_h = (const int*)d_in[0];
    const int* tokens_e = (const int*)d_in[1];
    const int* src = (const int*)d_in[2];
    const int* dst = (const int*)d_in[3];
    const int* fg_src = (const int*)d_in[4];
    const int* fg_dst = (const int*)d_in[5];
    const float* token_emb = (const float*)d_in[6];
    const float* e_token_emb = (const float*)d_in[7];
    const float* W_ni = (const float*)d_in[8];
    const float* W_nj = (const float*)d_in[9];
    const float* W_fij = (const float*)d_in[10];
    const float* W_node = (const float*)d_in[11];
    const float* attn_e = (const float*)d_in[12];
    const float* bias_e = (const float*)d_in[13];
    const float* Wf = (const float*)d_in[14];
    const float* bf_ = (const float*)d_in[15];
    const float* W3 = (const float*)d_in[16];
    const float* al3 = (const float*)d_in[17];
    const float* ar3 = (const float*)d_in[18];
    const float* b3 = (const float*)d_in[19];
    const float* Wl = (const float*)d_in[20];
    const float* bl = (const float*)d_in[21];
    const float* Wc = (const float*)d_in[22];
    const float* bc = (const float*)d_in[23];
    float* out = (float*)d_out;

    char* w = (char*)d_ws;
    auto alloc = [&](size_t b) -> char* {
        char* p = w;
        w += (b + 255) & ~(size_t)255;
        return p;
    };
    ushort_t* h = (ushort_t*)alloc((size_t)N_NODES * DIM * 2);
    ushort_t* fni = (ushort_t*)alloc((size_t)N_NODES * DIM * 2);
    ushort_t* fnj = (ushort_t*)alloc((size_t)N_NODES * DIM * 2);
    ushort_t* hs = (ushort_t*)alloc((size_t)N_NODES * DIM * 2);
    ushort_t* e = (ushort_t*)alloc((size_t)N_EDGES * DIM * 2);
    float* score = (float*)alloc((size_t)N_EDGES * 4);
    int* deg = (int*)alloc((size_t)N_NODES * 4);
    int* off = (int*)alloc((size_t)(N_NODES + 1) * 4);
    int* cursor = (int*)alloc((size_t)N_NODES * 4);
    int* bsum = (int*)alloc(64 * 4);
    int* psrc = (int*)alloc((size_t)N_EDGES * 4);
    int* pdst = (int*)alloc((size_t)N_EDGES * 4);
    int* ptok = (int*)alloc((size_t)N_EDGES * 4);
    float* eftab = (float*)alloc(100 * DIM * 4);
    float* maxval = (float*)alloc((size_t)N_NODES * 4);
    float* pooled = (float*)alloc((size_t)BGR * KPOOL * DIM * 4);
    float* ft = (float*)alloc(BGR * DIM * 4);
    float* part = (float*)alloc((size_t)BGR * 8 * DIM * 4);
    float* sl = (float*)alloc(BGR * 4);
    float* sr = (float*)alloc(BGR * 4);
    float* g = (float*)alloc(BGR * DIM * 4);
    float* g2 = (float*)alloc(BGR * DIM * 4);
    ushort_t* Wf7 = (ushort_t*)alloc((size_t)NLAYERS * DIM * DIM * 2);
    ushort_t* Wn = (ushort_t*)alloc((size_t)3 * NLAYERS * DIM * DIM * 2);
    float* h2 = (float*)e;
    float* hsort = (float*)((char*)e + (size_t)16 * 1024 * 1024);

    // weight prep
    wfprep<<<(NLAYERS * DIM * DIM) / 256, 256, 0, stream>>>(W_fij, Wf7);
    wnprep<<<(3 * NLAYERS * DIM * DIM) / 256, 256, 0, stream>>>(W_ni, W_nj, W_node, Wn);

    // CSR build + edge permutation (dst-sorted order), hierarchical scan
    zero_deg<<<(N_NODES + 255) / 256, 256, 0, stream>>>(deg, N_NODES);
    count_deg<<<N_EDGES / 256, 256, 0, stream>>>(dst, deg, N_EDGES);
    scan_local<<<(N_NODES + 1023) / 1024, 1024, 0, stream>>>(deg, off, bsum, N_NODES);
    scan_bsum<<<1, 32, 0, stream>>>(bsum, (N_NODES + 1023) / 1024);
    scan_add<<<(N_NODES + 255) / 256, 256, 0, stream>>>(off, bsum, cursor, N_NODES, N_EDGES);
    scatter_perm<<<N_EDGES / 256, 256, 0, stream>>>(src, dst, tokens_e, cursor,
                                                    psrc, pdst, ptok, N_EDGES);

    init_h<<<(N_NODES * DIM) / 256, 256, 0, stream>>>(tokens_h, token_emb, h);
    eftab_kernel<<<100, 128, 0, stream>>>(e_token_emb, W_fij, eftab);

    for (int l = 0; l < NLAYERS; l++) {
        node_gemm_mfma<<<dim3(N_NODES / 64, 3), 256, 0, stream>>>(
            h, Wn + l * 16384, fni, fnj, hs);
        if (l == 0) {
            edge0<<<(N_EDGES * 32) / 256, 256, 0, stream>>>(
                ptok, eftab, fni, fnj, psrc, pdst, attn_e, bias_e, e, score);
        } else {
            edge_gemm_mfma<<<N_EDGES / 64, 256, 0, stream>>>(
                e, fni, fnj, psrc, pdst, Wf7 + l * DIM * DIM,
                attn_e + l * DIM, bias_e + l * DIM, score);
        }
        agg_wave<<<N_NODES / 4, 256, 0, stream>>>(off, psrc, score, hs, h);
    }

    node_gemm1<<<N_NODES / 64, 256, 0, stream>>>(h, Wf, bf_, h2);
    sort_rows<<<N_NODES, 128, 0, stream>>>(h2, hsort, maxval);
    topk_pool<<<BGR, 256, 0, stream>>>(maxval, hsort, pooled);
    ft_partial<<<dim3(BGR, 8), 256, 0, stream>>>(pooled, W3, part);
    ft_reduce<<<BGR, 128, 0, stream>>>(part, al3, ar3, ft, sl, sr);
    fg_kernel<<<BGR, 128, 0, stream>>>(fg_src, fg_dst, sl, sr, ft, b3, g);
    gl_kernel<<<BGR, 128, 0, stream>>>(g, Wl, bl, g2);
    out_kernel<<<1, 256, 0, stream>>>(g2, Wc, bc, out);
}

// Round 14
// 1156.011 us; speedup vs baseline: 1.4878x; 1.1212x over previous
//
#include <hip/hip_runtime.h>

#define N_NODES 25600
#define N_EDGES 409600
#define BGR 128
#define EFE 1024
#define DIM 128
#define NLAYERS 8
#define KPOOL 32
#define NPG 200

typedef unsigned short ushort_t;
typedef unsigned char uchar_t;
typedef __attribute__((ext_vector_type(8))) short bf16x8;
typedef __attribute__((ext_vector_type(4))) float f32x4;

#define STG_S 144   // per-wave C-staging stride (bf16 elems)
#define ESCALE 16.0f
#define WSCALE 4.0f
#define UNSCALE 0.015625f  // 1/64

__device__ __forceinline__ float b2f(ushort_t v) {
    return __uint_as_float(((unsigned int)v) << 16);
}
__device__ __forceinline__ float blo(unsigned int u) {
    return __uint_as_float(u << 16);
}
__device__ __forceinline__ float bhi(unsigned int u) {
    return __uint_as_float(u & 0xffff0000u);
}
__device__ __forceinline__ ushort_t f2b(float f) {
    unsigned int u = __float_as_uint(f);
    unsigned int r = (u + 0x7fffu + ((u >> 16) & 1u)) >> 16;
    return (ushort_t)r;
}
__device__ __forceinline__ uint2 pack4(float4 v) {
    uint2 p;
    p.x = (unsigned int)f2b(v.x) | ((unsigned int)f2b(v.y) << 16);
    p.y = (unsigned int)f2b(v.z) | ((unsigned int)f2b(v.w) << 16);
    return p;
}
// pack 4 floats (scaled) into 4 fp8-e4m3 bytes in one dword
__device__ __forceinline__ unsigned int pk8(float v0, float v1, float v2, float v3) {
    int d = __builtin_amdgcn_cvt_pk_fp8_f32(v0, v1, 0, false);
    d = __builtin_amdgcn_cvt_pk_fp8_f32(v2, v3, d, true);
    return (unsigned int)d;
}

// ---------------- W_fij -> fragment-linear fp8 (x4 scale) ----------------
__global__ void wfprep8(const float* __restrict__ W, uchar_t* __restrict__ Wf) {
    int idx = blockIdx.x * 256 + threadIdx.x;  // 8 * 16384
    int l = idx >> 14, rem = idx & 16383;
    int j = rem & 7, lane = (rem >> 3) & 63, nt = (rem >> 9) & 7, kc = rem >> 12;
    int q = lane >> 4, r = lane & 15;
    int k = kc * 32 + q * 8 + j, n = nt * 16 + r;
    float w = W[l * 16384 + k * 128 + n] * WSCALE;
    int d = __builtin_amdgcn_cvt_pk_fp8_f32(w, w, 0, false);
    Wf[idx] = (uchar_t)(d & 0xff);
}

// W_ni / W_nj / W_node -> fragment-linear bf16, layout [m][l][16384]
__global__ void wnprep(const float* __restrict__ Wni, const float* __restrict__ Wnj,
                       const float* __restrict__ Wnode, ushort_t* __restrict__ Wn) {
    int idx = blockIdx.x * 256 + threadIdx.x;  // 3 * 8 * 16384
    int m = idx >> 17;
    int l = (idx >> 14) & 7;
    int rem = idx & 16383;
    int j = rem & 7, lane = (rem >> 3) & 63, nt = (rem >> 9) & 7, kc = rem >> 12;
    int q = lane >> 4, r = lane & 15;
    int k = kc * 32 + q * 8 + j, n = nt * 16 + r;
    const float* W = (m == 0) ? Wni : (m == 1) ? Wnj : Wnode;
    Wn[idx] = f2b(W[l * 16384 + k * 128 + n]);
}

// ---------------- zero deg ----------------
__global__ void zero_deg(int* __restrict__ deg, int n) {
    int i = blockIdx.x * 256 + threadIdx.x;
    if (i < n) deg[i] = 0;
}

// ---------------- CSR build ----------------
__global__ void count_deg(const int* __restrict__ dst, int* __restrict__ deg, int n) {
    int i = blockIdx.x * 256 + threadIdx.x;
    if (i < n) atomicAdd(&deg[dst[i]], 1);
}

__global__ __launch_bounds__(1024) void scan_local(const int* __restrict__ deg,
                                                   int* __restrict__ off,
                                                   int* __restrict__ bsum, int n) {
    __shared__ int buf[1024];
    int b = blockIdx.x, t = threadIdx.x;
    int gi = b * 1024 + t;
    int v = (gi < n) ? deg[gi] : 0;
    buf[t] = v;
    __syncthreads();
    for (int s = 1; s < 1024; s <<= 1) {
        int x = (t >= s) ? buf[t - s] : 0;
        __syncthreads();
        buf[t] += x;
        __syncthreads();
    }
    if (gi < n) off[gi] = buf[t] - v;
    if (t == 1023) bsum[b] = buf[1023];
}

__global__ void scan_bsum(int* __restrict__ bsum, int nb) {
    if (threadIdx.x == 0) {
        int acc = 0;
        for (int i = 0; i < nb; i++) { int v = bsum[i]; bsum[i] = acc; acc += v; }
    }
}

__global__ void scan_add(int* __restrict__ off, const int* __restrict__ bsum,
                         int* __restrict__ cursor, int n, int total) {
    int i = blockIdx.x * 256 + threadIdx.x;
    if (i < n) {
        int v = off[i] + bsum[i >> 10];
        off[i] = v;
        cursor[i] = v;
    }
    if (i == 0) off[n] = total;
}

__global__ void scatter_perm(const int* __restrict__ src, const int* __restrict__ dst,
                             const int* __restrict__ tokens_e, int* __restrict__ cursor,
                             int* __restrict__ psrc, int* __restrict__ pdst,
                             int* __restrict__ ptok, int n) {
    int i = blockIdx.x * 256 + threadIdx.x;
    if (i < n) {
        int p = atomicAdd(&cursor[dst[i]], 1);
        psrc[p] = src[i];
        pdst[p] = dst[i];
        ptok[p] = tokens_e[i];
    }
}

// ---------------- init (h bf16) ----------------
__global__ void init_h(const int* __restrict__ tok, const float* __restrict__ emb,
                       ushort_t* __restrict__ h) {
    int i = blockIdx.x * 256 + threadIdx.x;
    int r = i >> 7, d = i & 127;
    float v = emb[tok[r] * DIM + d];
    h[i] = f2b(fmaxf(v, 0.f));
}

__global__ __launch_bounds__(128) void eftab_kernel(const float* __restrict__ etab,
                                                    const float* __restrict__ W,
                                                    float* __restrict__ out) {
    int r = blockIdx.x, d = threadIdx.x;
    float acc = 0.f;
    for (int k = 0; k < DIM; k++)
        acc += etab[r * DIM + k] * W[k * DIM + d];
    out[r * DIM + d] = acc;
}

// ---------------- MFMA node GEMM: grid (400, 3) ----------------
__global__ __launch_bounds__(256, 4) void node_gemm_mfma(
    const ushort_t* __restrict__ h,
    const ushort_t* __restrict__ Wn,
    ushort_t* __restrict__ C0, ushort_t* __restrict__ C1, ushort_t* __restrict__ C2) {
    __shared__ __align__(16) ushort_t wF[16384];
    int tid = threadIdx.x, wv = tid >> 6, lane = tid & 63;
    int r = lane & 15, q = lane >> 4;
    int el = lane >> 2, qq = lane & 3;
    int m = blockIdx.y;
    size_t row = (size_t)blockIdx.x * 64 + 16 * wv;

    const ushort_t* aRow = h + (row + r) * DIM + q * 8;
    bf16x8 a0 = *(const bf16x8*)(aRow);
    bf16x8 a1 = *(const bf16x8*)(aRow + 32);
    bf16x8 a2 = *(const bf16x8*)(aRow + 64);
    bf16x8 a3 = *(const bf16x8*)(aRow + 96);

    {
        const uint4* wg = (const uint4*)(Wn + (size_t)m * NLAYERS * 16384);
        uint4* ws = (uint4*)wF;
        for (int i = tid; i < 2048; i += 256) ws[i] = wg[i];
    }
    __syncthreads();

    f32x4 acc[8] = {};
    const bf16x8* wfrag = (const bf16x8*)wF;
#pragma unroll
    for (int nt = 0; nt < 8; nt++)
        acc[nt] = __builtin_amdgcn_mfma_f32_16x16x32_bf16(a0, wfrag[(0 * 8 + nt) * 64 + lane], acc[nt], 0, 0, 0);
#pragma unroll
    for (int nt = 0; nt < 8; nt++)
        acc[nt] = __builtin_amdgcn_mfma_f32_16x16x32_bf16(a1, wfrag[(1 * 8 + nt) * 64 + lane], acc[nt], 0, 0, 0);
#pragma unroll
    for (int nt = 0; nt < 8; nt++)
        acc[nt] = __builtin_amdgcn_mfma_f32_16x16x32_bf16(a2, wfrag[(2 * 8 + nt) * 64 + lane], acc[nt], 0, 0, 0);
#pragma unroll
    for (int nt = 0; nt < 8; nt++)
        acc[nt] = __builtin_amdgcn_mfma_f32_16x16x32_bf16(a3, wfrag[(3 * 8 + nt) * 64 + lane], acc[nt], 0, 0, 0);
    __syncthreads();

    ushort_t* ss = wF + wv * 16 * STG_S;
#pragma unroll
    for (int nt = 0; nt < 8; nt++)
#pragma unroll
        for (int rg = 0; rg < 4; rg++)
            ss[(q * 4 + rg) * STG_S + nt * 16 + r] = f2b(acc[nt][rg]);

    ushort_t* Cp = (m == 0) ? C0 : (m == 1) ? C1 : C2;
    const uint4* sp = (const uint4*)(ss + el * STG_S + qq * 32);
    uint4* cp = (uint4*)(Cp + (row + el) * DIM + qq * 32);
#pragma unroll
    for (int cc = 0; cc < 4; cc++) cp[cc] = sp[cc];
}

// single-W with bias + relu (final Wf): h bf16 in, fp32 out
__global__ __launch_bounds__(256) void node_gemm1(
    const ushort_t* __restrict__ A, const float* __restrict__ W,
    const float* __restrict__ bias, float* __restrict__ C) {
    __shared__ float As[64 * 128];
    __shared__ uint2 Ws4[128 * 32];
    int tid = threadIdx.x;
    size_t row0 = (size_t)blockIdx.x * 64;
    const uint2* Ag = (const uint2*)(A + row0 * DIM);
    for (int f = tid; f < 64 * 32; f += 256) {
        uint2 v = Ag[f];
        ((float4*)As)[f] = make_float4(blo(v.x), bhi(v.x), blo(v.y), bhi(v.y));
    }
    const float4* Wg = (const float4*)W;
    for (int i = tid; i < 128 * 32; i += 256) Ws4[i] = pack4(Wg[i]);
    __syncthreads();
    int cq = tid & 31, r0 = (tid >> 5) * 8, c0 = cq * 4;
    float acc[8][4] = {};
    for (int k = 0; k < 128; k++) {
        uint2 wp = Ws4[k * 32 + cq];
        float w0 = blo(wp.x), w1 = bhi(wp.x), w2 = blo(wp.y), w3 = bhi(wp.y);
#pragma unroll
        for (int i = 0; i < 8; i++) {
            float a = As[(r0 + i) * 128 + k];
            acc[i][0] += a * w0; acc[i][1] += a * w1;
            acc[i][2] += a * w2; acc[i][3] += a * w3;
        }
    }
    float b0 = bias[c0], b1 = bias[c0 + 1], b2v = bias[c0 + 2], b3v = bias[c0 + 3];
#pragma unroll
    for (int i = 0; i < 8; i++) {
        *(float4*)&C[(row0 + r0 + i) * DIM + c0] =
            make_float4(fmaxf(acc[i][0] + b0, 0.f), fmaxf(acc[i][1] + b1, 0.f),
                        fmaxf(acc[i][2] + b2v, 0.f), fmaxf(acc[i][3] + b3v, 0.f));
    }
}

// ---------------- fp8 MFMA edge GEMM (layers 1..7) ----------------
// e stored fp8 (x16 scaled), W fp8 (x4 scaled); C unscaled by 1/64 into bf16 staging.
__global__ __launch_bounds__(256, 4) void edge_gemm_fp8(
    uchar_t* __restrict__ e,
    const ushort_t* __restrict__ fni, const ushort_t* __restrict__ fnj,
    const int* __restrict__ psrc, const int* __restrict__ pdst,
    const uchar_t* __restrict__ Wf,                  // fp8 fragment-linear, 16384 B
    const float* __restrict__ attn, const float* __restrict__ bias,
    float* __restrict__ score) {
    __shared__ __align__(16) char smem[4 * 16 * STG_S * 2];  // 18432 B; W uses first 16384

    int tid = threadIdx.x;
    int wv = tid >> 6, lane = tid & 63;
    int r = lane & 15, q = lane >> 4;
    int el = lane >> 2, qq = lane & 3;
    size_t row = (size_t)blockIdx.x * 64 + 16 * wv;
    size_t eid = row + el;

    int sv = psrc[eid], dv = pdst[eid];

    // A fragments: 8 fp8 bytes per MFMA per lane
    const uchar_t* aRow = e + (row + r) * DIM + q * 8;
    long long a0 = *(const long long*)(aRow);
    long long a1 = *(const long long*)(aRow + 32);
    long long a2 = *(const long long*)(aRow + 64);
    long long a3 = *(const long long*)(aRow + 96);

    {
        const uint4* wg = (const uint4*)Wf;
        uint4* ws = (uint4*)smem;
        for (int i = tid; i < 1024; i += 256) ws[i] = wg[i];
    }
    __syncthreads();

    f32x4 acc[8] = {};
    const long long* wfrag = (const long long*)smem;
#pragma unroll
    for (int nt = 0; nt < 8; nt++)
        acc[nt] = __builtin_amdgcn_mfma_f32_16x16x32_fp8_fp8(a0, wfrag[(0 * 8 + nt) * 64 + lane], acc[nt], 0, 0, 0);
#pragma unroll
    for (int nt = 0; nt < 8; nt++)
        acc[nt] = __builtin_amdgcn_mfma_f32_16x16x32_fp8_fp8(a1, wfrag[(1 * 8 + nt) * 64 + lane], acc[nt], 0, 0, 0);
#pragma unroll
    for (int nt = 0; nt < 8; nt++)
        acc[nt] = __builtin_amdgcn_mfma_f32_16x16x32_fp8_fp8(a2, wfrag[(2 * 8 + nt) * 64 + lane], acc[nt], 0, 0, 0);
#pragma unroll
    for (int nt = 0; nt < 8; nt++)
        acc[nt] = __builtin_amdgcn_mfma_f32_16x16x32_fp8_fp8(a3, wfrag[(3 * 8 + nt) * 64 + lane], acc[nt], 0, 0, 0);
    __syncthreads();  // W reads done -> staging overlay

    ushort_t* ss = (ushort_t*)smem + wv * 16 * STG_S;
#pragma unroll
    for (int nt = 0; nt < 8; nt++)
#pragma unroll
        for (int rg = 0; rg < 4; rg++)
            ss[(q * 4 + rg) * STG_S + nt * 16 + r] = f2b(acc[nt][rg] * UNSCALE);

    const uint4* nip = (const uint4*)(fni + (size_t)sv * DIM + qq * 32);
    const uint4* njp = (const uint4*)(fnj + (size_t)dv * DIM + qq * 32);
    const uint4* sp = (const uint4*)(ss + el * STG_S + qq * 32);
    unsigned int outb[8];
    float p = 0.f;
#pragma unroll
    for (int cc = 0; cc < 4; cc++) {
        uint4 avq = sp[cc];
        uint4 niq = nip[cc];
        uint4 njq = njp[cc];
        float vv[8];
#pragma unroll
        for (int u = 0; u < 4; u++) {
            unsigned int aw = ((const unsigned int*)&avq)[u];
            unsigned int nw = ((const unsigned int*)&niq)[u];
            unsigned int jw = ((const unsigned int*)&njq)[u];
            int c = qq * 32 + cc * 8 + u * 2;
            float v0 = blo(aw) + blo(nw) + blo(jw) + bias[c];
            float v1 = bhi(aw) + bhi(nw) + bhi(jw) + bias[c + 1];
            v0 = v0 > 0.f ? v0 : 0.01f * v0;
            v1 = v1 > 0.f ? v1 : 0.01f * v1;
            vv[u * 2] = v0; vv[u * 2 + 1] = v1;
            p += v0 * attn[c] + v1 * attn[c + 1];
        }
        outb[cc * 2] = pk8(vv[0] * ESCALE, vv[1] * ESCALE, vv[2] * ESCALE, vv[3] * ESCALE);
        outb[cc * 2 + 1] = pk8(vv[4] * ESCALE, vv[5] * ESCALE, vv[6] * ESCALE, vv[7] * ESCALE);
    }
    uint4* ep = (uint4*)(e + eid * DIM + qq * 32);
    ep[0] = make_uint4(outb[0], outb[1], outb[2], outb[3]);
    ep[1] = make_uint4(outb[4], outb[5], outb[6], outb[7]);
    p += __shfl_xor(p, 1);
    p += __shfl_xor(p, 2);
    if (qq == 0) score[eid] = p;
}

// ---------------- layer-0 edge kernel (fp8 e out) ----------------
__global__ __launch_bounds__(256) void edge0(
    const int* __restrict__ ptok, const float* __restrict__ eftab,
    const ushort_t* __restrict__ fni, const ushort_t* __restrict__ fnj,
    const int* __restrict__ psrc, const int* __restrict__ pdst,
    const float* __restrict__ attn, const float* __restrict__ bias,
    uchar_t* __restrict__ e, float* __restrict__ score) {
    unsigned int gid = blockIdx.x * 256 + threadIdx.x;
    unsigned int eid = gid >> 5;
    int cq = gid & 31, c0 = cq * 4;
    int tok = ptok[eid];
    int sv = psrc[eid], dv = pdst[eid];
    float4 t = *(const float4*)&eftab[tok * DIM + c0];
    uint2 niw = *(const uint2*)(fni + (size_t)sv * DIM + c0);
    uint2 njw = *(const uint2*)(fnj + (size_t)dv * DIM + c0);
    float v0 = t.x + blo(niw.x) + blo(njw.x) + bias[c0];
    float v1 = t.y + bhi(niw.x) + bhi(njw.x) + bias[c0 + 1];
    float v2 = t.z + blo(niw.y) + blo(njw.y) + bias[c0 + 2];
    float v3 = t.w + bhi(niw.y) + bhi(njw.y) + bias[c0 + 3];
    v0 = v0 > 0.f ? v0 : 0.01f * v0;
    v1 = v1 > 0.f ? v1 : 0.01f * v1;
    v2 = v2 > 0.f ? v2 : 0.01f * v2;
    v3 = v3 > 0.f ? v3 : 0.01f * v3;
    *(unsigned int*)(e + (size_t)eid * DIM + c0) =
        pk8(v0 * ESCALE, v1 * ESCALE, v2 * ESCALE, v3 * ESCALE);
    float p = v0 * attn[c0] + v1 * attn[c0 + 1] + v2 * attn[c0 + 2] + v3 * attn[c0 + 3];
#pragma unroll
    for (int o = 1; o < 32; o <<= 1) p += __shfl_xor(p, o);
    if (cq == 0) score[eid] = p;
}

// ---------------- wave-per-node softmax + aggregation: unroll-4 gathers ----------------
__global__ __launch_bounds__(256) void agg_wave(
    const int* __restrict__ off, const int* __restrict__ psrc,
    const float* __restrict__ score, const ushort_t* __restrict__ hs,
    ushort_t* __restrict__ h) {
    int node = blockIdx.x * 4 + (threadIdx.x >> 6);
    int lane = threadIdx.x & 63;
    int b0 = off[node];
    int deg = off[node + 1] - b0;

    float m = -1e30f;
    for (int j = lane; j < deg; j += 64) m = fmaxf(m, score[b0 + j]);
#pragma unroll
    for (int o = 32; o > 0; o >>= 1) m = fmaxf(m, __shfl_xor(m, o));
    float se = 0.f;
    for (int j = lane; j < deg; j += 64) se += __expf(score[b0 + j] - m);
#pragma unroll
    for (int o = 32; o > 0; o >>= 1) se += __shfl_xor(se, o);
    float inv = (deg > 0) ? 1.f / se : 0.f;

    float acc0 = 0.f, acc1 = 0.f;
    for (int base = 0; base < deg; base += 64) {
        int cnt = min(64, deg - base);
        float wgt = 0.f;
        int sidx = 0;
        if (lane < cnt) {
            wgt = __expf(score[b0 + base + lane] - m) * inv;
            sidx = psrc[b0 + base + lane];
        }
        int i = 0;
        for (; i + 4 <= cnt; i += 4) {
            float w0 = __shfl(wgt, i), w1 = __shfl(wgt, i + 1);
            float w2 = __shfl(wgt, i + 2), w3 = __shfl(wgt, i + 3);
            int s0 = __shfl(sidx, i), s1 = __shfl(sidx, i + 1);
            int s2 = __shfl(sidx, i + 2), s3 = __shfl(sidx, i + 3);
            unsigned int h0 = *(const unsigned int*)(hs + (size_t)s0 * DIM + lane * 2);
            unsigned int h1 = *(const unsigned int*)(hs + (size_t)s1 * DIM + lane * 2);
            unsigned int h2 = *(const unsigned int*)(hs + (size_t)s2 * DIM + lane * 2);
            unsigned int h3 = *(const unsigned int*)(hs + (size_t)s3 * DIM + lane * 2);
            acc0 += w0 * blo(h0); acc1 += w0 * bhi(h0);
            acc0 += w1 * blo(h1); acc1 += w1 * bhi(h1);
            acc0 += w2 * blo(h2); acc1 += w2 * bhi(h2);
            acc0 += w3 * blo(h3); acc1 += w3 * bhi(h3);
        }
        for (; i < cnt; i++) {
            float wi = __shfl(wgt, i);
            int si = __shfl(sidx, i);
            unsigned int hv = *(const unsigned int*)(hs + (size_t)si * DIM + lane * 2);
            acc0 += wi * blo(hv);
            acc1 += wi * bhi(hv);
        }
    }
    unsigned int outp = (unsigned int)f2b(fmaxf(acc0, 0.f)) |
                        ((unsigned int)f2b(fmaxf(acc1, 0.f)) << 16);
    *(unsigned int*)(h + (size_t)node * DIM + lane * 2) = outp;
}

// ---------------- wave bitonic sort of 128 features (no barriers) ----------------
// lane l holds elems i0=l (x0) and i1=l+64 (x1); ascending sort; 4 nodes/block.
__global__ __launch_bounds__(256) void sort_wave(const float* __restrict__ h2,
                                                 float* __restrict__ hsort,
                                                 float* __restrict__ maxval) {
    int node = blockIdx.x * 4 + (threadIdx.x >> 6);
    int lane = threadIdx.x & 63;
    float x0 = h2[(size_t)node * DIM + lane];
    float x1 = h2[(size_t)node * DIM + 64 + lane];
    for (int k = 2; k <= 128; k <<= 1) {
        for (int s = k >> 1; s >= 1; s >>= 1) {
            bool d0 = ((lane & k) == 0);             // dir for i0=l (k<=64: l&k; k=128: 0)
            bool d1 = (((lane + 64) & k) == 0);      // dir for i1=l+64
            if (s == 64) {
                // partner is the other register in the same lane (i0<i1)
                float mn = fminf(x0, x1), mx = fmaxf(x0, x1);
                // d0 == d1's relevant dir here is d0 (both use stage dir of their own idx;
                // for s=64 the pair is (i0,i1): position i0 keeps min iff dir ascending)
                x0 = d0 ? mn : mx;
                x1 = d0 ? mx : mn;
            } else {
                bool low = ((lane & s) == 0);
                float y0 = __shfl_xor(x0, s);
                float y1 = __shfl_xor(x1, s);
                float mn0 = fminf(x0, y0), mx0 = fmaxf(x0, y0);
                float mn1 = fminf(x1, y1), mx1 = fmaxf(x1, y1);
                x0 = (low == d0) ? mn0 : mx0;
                x1 = (low == d1) ? mn1 : mx1;
            }
        }
    }
    hsort[(size_t)node * DIM + lane] = x0;
    hsort[(size_t)node * DIM + 64 + lane] = x1;
    if (lane == 63) maxval[node] = x1;
}

// ---------------- per-graph top-k + gather pooled rows ----------------
__global__ __launch_bounds__(256) void topk_pool(const float* __restrict__ maxval,
                                                 const float* __restrict__ hsort,
                                                 float* __restrict__ pooled) {
    __shared__ float v[256];
    __shared__ int id[256];
    int b = blockIdx.x, t = threadIdx.x;
    v[t] = (t < NPG) ? maxval[b * NPG + t] : -1e30f;
    id[t] = t;
    __syncthreads();
    for (int k = 2; k <= 256; k <<= 1) {
        for (int j = k >> 1; j > 0; j >>= 1) {
            int ixj = t ^ j;
            float va = v[t], vb = v[ixj];
            int ia = id[t], ib = id[ixj];
            __syncthreads();
            bool dirDesc = ((t & k) == 0);
            bool cmp = (va > vb) || (va == vb && ia < ib);
            bool takeMine = ((t < ixj) == (dirDesc == cmp));
            v[t] = takeMine ? va : vb;
            id[t] = takeMine ? ia : ib;
            __syncthreads();
        }
    }
    for (int i = t; i < KPOOL * DIM; i += 256) {
        int kk = i >> 7, d = i & 127;
        pooled[((size_t)b * KPOOL + kk) * DIM + d] = hsort[((size_t)b * NPG + id[kk]) * DIM + d];
    }
}

// ---------------- ft split-K ----------------
__global__ __launch_bounds__(256) void ft_partial(
    const float* __restrict__ pooled, const float* __restrict__ W3,
    float* __restrict__ part) {
    __shared__ float ps[512];
    __shared__ float red[256];
    int b = blockIdx.x, s = blockIdx.y;
    int t = threadIdx.x;
    int d = t & 127, half = t >> 7;
    for (int i = t; i < 512; i += 256) ps[i] = pooled[(size_t)b * 4096 + s * 512 + i];
    __syncthreads();
    float acc = 0.f;
    const float* Wp = W3 + (size_t)(s * 512 + half * 256) * DIM + d;
    const float* pp = ps + half * 256;
#pragma unroll 4
    for (int kk = 0; kk < 256; kk++) acc += pp[kk] * Wp[(size_t)kk * DIM];
    red[t] = acc;
    __syncthreads();
    if (t < 128) part[((size_t)b * 8 + s) * DIM + t] = red[t] + red[t + 128];
}

__global__ __launch_bounds__(128) void ft_reduce(
    const float* __restrict__ part, const float* __restrict__ al3,
    const float* __restrict__ ar3, float* __restrict__ ft,
    float* __restrict__ sl, float* __restrict__ sr) {
    __shared__ float r1[128], r2[128];
    int b = blockIdx.x, d = threadIdx.x;
    float acc = 0.f;
#pragma unroll
    for (int s = 0; s < 8; s++) acc += part[((size_t)b * 8 + s) * DIM + d];
    ft[b * DIM + d] = acc;
    r1[d] = acc * al3[d];
    r2[d] = acc * ar3[d];
    __syncthreads();
    for (int s = 64; s > 0; s >>= 1) {
        if (d < s) { r1[d] += r1[d + s]; r2[d] += r2[d + s]; }
        __syncthreads();
    }
    if (d == 0) { sl[b] = r1[0]; sr[b] = r2[0]; }
}

// ---------------- final-graph GAT ----------------
__global__ __launch_bounds__(128) void fg_kernel(
    const int* __restrict__ fg_src, const int* __restrict__ fg_dst,
    const float* __restrict__ sl, const float* __restrict__ sr,
    const float* __restrict__ ft, const float* __restrict__ b3,
    float* __restrict__ g) {
    __shared__ int list[EFE];
    __shared__ float wgt[EFE];
    __shared__ float red[128];
    __shared__ int cnt;
    int b = blockIdx.x, t = threadIdx.x;
    if (t == 0) cnt = 0;
    __syncthreads();
    for (int e = t; e < EFE; e += 128)
        if (fg_dst[e] == b) { int p = atomicAdd(&cnt, 1); list[p] = e; }
    __syncthreads();
    int deg = cnt;
    float srb = sr[b];
    float m = -1e30f;
    for (int j = t; j < deg; j += 128) {
        float s = sl[fg_src[list[j]]] + srb;
        s = s > 0.f ? s : 0.2f * s;
        m = fmaxf(m, s);
    }
    red[t] = m;
    __syncthreads();
    for (int s = 64; s > 0; s >>= 1) { if (t < s) red[t] = fmaxf(red[t], red[t + s]); __syncthreads(); }
    m = red[0];
    __syncthreads();
    float se = 0.f;
    for (int j = t; j < deg; j += 128) {
        float s = sl[fg_src[list[j]]] + srb;
        s = s > 0.f ? s : 0.2f * s;
        se += __expf(s - m);
    }
    red[t] = se;
    __syncthreads();
    for (int s = 64; s > 0; s >>= 1) { if (t < s) red[t] += red[t + s]; __syncthreads(); }
    float inv = (deg > 0) ? 1.f / red[0] : 0.f;
    __syncthreads();
    for (int j = t; j < deg; j += 128) {
        float s = sl[fg_src[list[j]]] + srb;
        s = s > 0.f ? s : 0.2f * s;
        wgt[j] = __expf(s - m) * inv;
    }
    __syncthreads();
    float acc = 0.f;
    for (int j = 0; j < deg; j++) acc += wgt[j] * ft[(size_t)fg_src[list[j]] * DIM + t];
    g[b * DIM + t] = fmaxf(acc + b3[t], 0.f);
}

// ---------------- g2 = relu(g @ Wl + bl) ----------------
__global__ __launch_bounds__(128) void gl_kernel(const float* __restrict__ g,
                                                 const float* __restrict__ Wl,
                                                 const float* __restrict__ bl,
                                                 float* __restrict__ g2) {
    __shared__ float gs[128];
    int b = blockIdx.x, d = threadIdx.x;
    gs[d] = g[b * DIM + d];
    __syncthreads();
    float acc = 0.f;
    for (int k = 0; k < 128; k++) acc += gs[k] * Wl[k * DIM + d];
    g2[b * DIM + d] = fmaxf(acc + bl[d], 0.f);
}

// ---------------- out = g2 @ Wc + bc ----------------
__global__ __launch_bounds__(256) void out_kernel(const float* __restrict__ g2,
                                                  const float* __restrict__ Wc,
                                                  const float* __restrict__ bc,
                                                  float* __restrict__ out) {
    int i = threadIdx.x;
    int b = i >> 1, j = i & 1;
    float acc = bc[j];
    for (int k = 0; k < 128; k++) acc += g2[b * DIM + k] * Wc[k * 2 + j];
    out[b * 2 + j] = acc;
}

extern "C" void kernel_launch(void* const* d_in, const int* in_sizes, int n_in,
                              void* d_out, int out_size, void* d_ws, size_t ws_size,
                              hipStream_t stream) {
    const int* tokens_h = (const int*)d_in[0];
    const int* tokens_e = (const int*)d_in[1];
    const int* src = (const int*)d_in[2];
    const int* dst = (const int*)d_in[3];
    const int* fg_src = (const int*)d_in[4];
    const int* fg_dst = (const int*)d_in[5];
    const float* token_emb = (const float*)d_in[6];
    const float* e_token_emb = (const float*)d_in[7];
    const float* W_ni = (const float*)d_in[8];
    const float* W_nj = (const float*)d_in[9];
    const float* W_fij = (const float*)d_in[10];
    const float* W_node = (const float*)d_in[11];
    const float* attn_e = (const float*)d_in[12];
    const float* bias_e = (const float*)d_in[13];
    const float* Wf = (const float*)d_in[14];
    const float* bf_ = (const float*)d_in[15];
    const float* W3 = (const float*)d_in[16];
    const float* al3 = (const float*)d_in[17];
    const float* ar3 = (const float*)d_in[18];
    const float* b3 = (const float*)d_in[19];
    const float* Wl = (const float*)d_in[20];
    const float* bl = (const float*)d_in[21];
    const float* Wc = (const float*)d_in[22];
    const float* bc = (const float*)d_in[23];
    float* out = (float*)d_out;

    char* w = (char*)d_ws;
    auto alloc = [&](size_t b) -> char* {
        char* p = w;
        w += (b + 255) & ~(size_t)255;
        return p;
    };
    ushort_t* h = (ushort_t*)alloc((size_t)N_NODES * DIM * 2);
    ushort_t* fni = (ushort_t*)alloc((size_t)N_NODES * DIM * 2);
    ushort_t* fnj = (ushort_t*)alloc((size_t)N_NODES * DIM * 2);
    ushort_t* hs = (ushort_t*)alloc((size_t)N_NODES * DIM * 2);
    uchar_t* e = (uchar_t*)alloc((size_t)N_EDGES * DIM);     // fp8 now
    float* score = (float*)alloc((size_t)N_EDGES * 4);
    int* deg = (int*)alloc((size_t)N_NODES * 4);
    int* off = (int*)alloc((size_t)(N_NODES + 1) * 4);
    int* cursor = (int*)alloc((size_t)N_NODES * 4);
    int* bsum = (int*)alloc(64 * 4);
    int* psrc = (int*)alloc((size_t)N_EDGES * 4);
    int* pdst = (int*)alloc((size_t)N_EDGES * 4);
    int* ptok = (int*)alloc((size_t)N_EDGES * 4);
    float* eftab = (float*)alloc(100 * DIM * 4);
    float* maxval = (float*)alloc((size_t)N_NODES * 4);
    float* pooled = (float*)alloc((size_t)BGR * KPOOL * DIM * 4);
    float* ft = (float*)alloc(BGR * DIM * 4);
    float* part = (float*)alloc((size_t)BGR * 8 * DIM * 4);
    float* sl = (float*)alloc(BGR * 4);
    float* sr = (float*)alloc(BGR * 4);
    float* g = (float*)alloc(BGR * DIM * 4);
    float* g2 = (float*)alloc(BGR * DIM * 4);
    uchar_t* Wf7 = (uchar_t*)alloc((size_t)NLAYERS * DIM * DIM);   // fp8
    ushort_t* Wn = (ushort_t*)alloc((size_t)3 * NLAYERS * DIM * DIM * 2);
    // h2/hsort (fp32, 13.1 MB each) live in the e region (52 MB) after the layer loop
    float* h2 = (float*)e;
    float* hsort = (float*)((char*)e + (size_t)16 * 1024 * 1024);

    // weight prep
    wfprep8<<<(NLAYERS * DIM * DIM) / 256, 256, 0, stream>>>(W_fij, Wf7);
    wnprep<<<(3 * NLAYERS * DIM * DIM) / 256, 256, 0, stream>>>(W_ni, W_nj, W_node, Wn);

    // CSR build + edge permutation (dst-sorted order), hierarchical scan
    zero_deg<<<(N_NODES + 255) / 256, 256, 0, stream>>>(deg, N_NODES);
    count_deg<<<N_EDGES / 256, 256, 0, stream>>>(dst, deg, N_EDGES);
    scan_local<<<(N_NODES + 1023) / 1024, 1024, 0, stream>>>(deg, off, bsum, N_NODES);
    scan_bsum<<<1, 32, 0, stream>>>(bsum, (N_NODES + 1023) / 1024);
    scan_add<<<(N_NODES + 255) / 256, 256, 0, stream>>>(off, bsum, cursor, N_NODES, N_EDGES);
    scatter_perm<<<N_EDGES / 256, 256, 0, stream>>>(src, dst, tokens_e, cursor,
                                                    psrc, pdst, ptok, N_EDGES);

    init_h<<<(N_NODES * DIM) / 256, 256, 0, stream>>>(tokens_h, token_emb, h);
    eftab_kernel<<<100, 128, 0, stream>>>(e_token_emb, W_fij, eftab);

    for (int l = 0; l < NLAYERS; l++) {
        node_gemm_mfma<<<dim3(N_NODES / 64, 3), 256, 0, stream>>>(
            h, Wn + l * 16384, fni, fnj, hs);
        if (l == 0) {
            edge0<<<(N_EDGES * 32) / 256, 256, 0, stream>>>(
                ptok, eftab, fni, fnj, psrc, pdst, attn_e, bias_e, e, score);
        } else {
            edge_gemm_fp8<<<N_EDGES / 64, 256, 0, stream>>>(
                e, fni, fnj, psrc, pdst, Wf7 + (size_t)l * DIM * DIM,
                attn_e + l * DIM, bias_e + l * DIM, score);
        }
        agg_wave<<<N_NODES / 4, 256, 0, stream>>>(off, psrc, score, hs, h);
    }

    node_gemm1<<<N_NODES / 64, 256, 0, stream>>>(h, Wf, bf_, h2);
    sort_wave<<<N_NODES / 4, 256, 0, stream>>>(h2, hsort, maxval);
    topk_pool<<<BGR, 256, 0, stream>>>(maxval, hsort, pooled);
    ft_partial<<<dim3(BGR, 8), 256, 0, stream>>>(pooled, W3, part);
    ft_reduce<<<BGR, 128, 0, stream>>>(part, al3, ar3, ft, sl, sr);
    fg_kernel<<<BGR, 128, 0, stream>>>(fg_src, fg_dst, sl, sr, ft, b3, g);
    gl_kernel<<<BGR, 128, 0, stream>>>(g, Wl, bl, g2);
    out_kernel<<<1, 256, 0, stream>>>(g2, Wc, bc, out);
}

// Round 15
// 1121.364 us; speedup vs baseline: 1.5337x; 1.0309x over previous
//
#include <hip/hip_runtime.h>

#define N_NODES 25600
#define N_EDGES 409600
#define BGR 128
#define EFE 1024
#define DIM 128
#define NLAYERS 8
#define KPOOL 32
#define NPG 200

typedef unsigned short ushort_t;
typedef unsigned char uchar_t;
typedef __attribute__((ext_vector_type(8))) short bf16x8;
typedef __attribute__((ext_vector_type(4))) float f32x4;

#define STG_S 136   // per-wave C-staging stride; 272B = 17x16B, 272 mod 128B banks -> 2-way (free)
#define ESCALE 16.0f
#define WSCALE 4.0f
#define UNSCALE 0.015625f  // 1/64
#define HSCALE 16.0f
#define HUNSCALE 0.0625f   // 1/16

__device__ __forceinline__ float b2f(ushort_t v) {
    return __uint_as_float(((unsigned int)v) << 16);
}
__device__ __forceinline__ float blo(unsigned int u) {
    return __uint_as_float(u << 16);
}
__device__ __forceinline__ float bhi(unsigned int u) {
    return __uint_as_float(u & 0xffff0000u);
}
__device__ __forceinline__ ushort_t f2b(float f) {
    unsigned int u = __float_as_uint(f);
    unsigned int r = (u + 0x7fffu + ((u >> 16) & 1u)) >> 16;
    return (ushort_t)r;
}
__device__ __forceinline__ uint2 pack4(float4 v) {
    uint2 p;
    p.x = (unsigned int)f2b(v.x) | ((unsigned int)f2b(v.y) << 16);
    p.y = (unsigned int)f2b(v.z) | ((unsigned int)f2b(v.w) << 16);
    return p;
}
__device__ __forceinline__ unsigned int pk8(float v0, float v1, float v2, float v3) {
    int d = __builtin_amdgcn_cvt_pk_fp8_f32(v0, v1, 0, false);
    d = __builtin_amdgcn_cvt_pk_fp8_f32(v2, v3, d, true);
    return (unsigned int)d;
}

// ---------------- W_fij -> fragment-linear fp8 (x4 scale) ----------------
__global__ void wfprep8(const float* __restrict__ W, uchar_t* __restrict__ Wf) {
    int idx = blockIdx.x * 256 + threadIdx.x;  // 8 * 16384
    int l = idx >> 14, rem = idx & 16383;
    int j = rem & 7, lane = (rem >> 3) & 63, nt = (rem >> 9) & 7, kc = rem >> 12;
    int q = lane >> 4, r = lane & 15;
    int k = kc * 32 + q * 8 + j, n = nt * 16 + r;
    float w = W[l * 16384 + k * 128 + n] * WSCALE;
    int d = __builtin_amdgcn_cvt_pk_fp8_f32(w, w, 0, false);
    Wf[idx] = (uchar_t)(d & 0xff);
}

// W_ni / W_nj / W_node -> fragment-linear bf16, layout [m][l][16384]
__global__ void wnprep(const float* __restrict__ Wni, const float* __restrict__ Wnj,
                       const float* __restrict__ Wnode, ushort_t* __restrict__ Wn) {
    int idx = blockIdx.x * 256 + threadIdx.x;  // 3 * 8 * 16384
    int m = idx >> 17;
    int l = (idx >> 14) & 7;
    int rem = idx & 16383;
    int j = rem & 7, lane = (rem >> 3) & 63, nt = (rem >> 9) & 7, kc = rem >> 12;
    int q = lane >> 4, r = lane & 15;
    int k = kc * 32 + q * 8 + j, n = nt * 16 + r;
    const float* W = (m == 0) ? Wni : (m == 1) ? Wnj : Wnode;
    Wn[idx] = f2b(W[l * 16384 + k * 128 + n]);
}

// ---------------- zero deg ----------------
__global__ void zero_deg(int* __restrict__ deg, int n) {
    int i = blockIdx.x * 256 + threadIdx.x;
    if (i < n) deg[i] = 0;
}

// ---------------- CSR build ----------------
__global__ void count_deg(const int* __restrict__ dst, int* __restrict__ deg, int n) {
    int i = blockIdx.x * 256 + threadIdx.x;
    if (i < n) atomicAdd(&deg[dst[i]], 1);
}

__global__ __launch_bounds__(1024) void scan_local(const int* __restrict__ deg,
                                                   int* __restrict__ off,
                                                   int* __restrict__ bsum, int n) {
    __shared__ int buf[1024];
    int b = blockIdx.x, t = threadIdx.x;
    int gi = b * 1024 + t;
    int v = (gi < n) ? deg[gi] : 0;
    buf[t] = v;
    __syncthreads();
    for (int s = 1; s < 1024; s <<= 1) {
        int x = (t >= s) ? buf[t - s] : 0;
        __syncthreads();
        buf[t] += x;
        __syncthreads();
    }
    if (gi < n) off[gi] = buf[t] - v;
    if (t == 1023) bsum[b] = buf[1023];
}

__global__ void scan_bsum(int* __restrict__ bsum, int nb) {
    if (threadIdx.x == 0) {
        int acc = 0;
        for (int i = 0; i < nb; i++) { int v = bsum[i]; bsum[i] = acc; acc += v; }
    }
}

__global__ void scan_add(int* __restrict__ off, const int* __restrict__ bsum,
                         int* __restrict__ cursor, int n, int total) {
    int i = blockIdx.x * 256 + threadIdx.x;
    if (i < n) {
        int v = off[i] + bsum[i >> 10];
        off[i] = v;
        cursor[i] = v;
    }
    if (i == 0) off[n] = total;
}

__global__ void scatter_perm(const int* __restrict__ src, const int* __restrict__ dst,
                             const int* __restrict__ tokens_e, int* __restrict__ cursor,
                             int* __restrict__ psrc, int* __restrict__ pdst,
                             int* __restrict__ ptok, int n) {
    int i = blockIdx.x * 256 + threadIdx.x;
    if (i < n) {
        int p = atomicAdd(&cursor[dst[i]], 1);
        psrc[p] = src[i];
        pdst[p] = dst[i];
        ptok[p] = tokens_e[i];
    }
}

// ---------------- init (h bf16) ----------------
__global__ void init_h(const int* __restrict__ tok, const float* __restrict__ emb,
                       ushort_t* __restrict__ h) {
    int i = blockIdx.x * 256 + threadIdx.x;
    int r = i >> 7, d = i & 127;
    float v = emb[tok[r] * DIM + d];
    h[i] = f2b(fmaxf(v, 0.f));
}

__global__ __launch_bounds__(128) void eftab_kernel(const float* __restrict__ etab,
                                                    const float* __restrict__ W,
                                                    float* __restrict__ out) {
    int r = blockIdx.x, d = threadIdx.x;
    float acc = 0.f;
    for (int k = 0; k < DIM; k++)
        acc += etab[r * DIM + k] * W[k * DIM + d];
    out[r * DIM + d] = acc;
}

// ---------------- MFMA node GEMM: grid (400, 3); m=2 (hs) stores fp8 x16 ----------------
__global__ __launch_bounds__(256, 4) void node_gemm_mfma(
    const ushort_t* __restrict__ h,
    const ushort_t* __restrict__ Wn,
    ushort_t* __restrict__ C0, ushort_t* __restrict__ C1, uchar_t* __restrict__ C2) {
    __shared__ __align__(16) ushort_t wF[16384];
    int tid = threadIdx.x, wv = tid >> 6, lane = tid & 63;
    int r = lane & 15, q = lane >> 4;
    int el = lane >> 2, qq = lane & 3;
    int m = blockIdx.y;
    size_t row = (size_t)blockIdx.x * 64 + 16 * wv;

    const ushort_t* aRow = h + (row + r) * DIM + q * 8;
    bf16x8 a0 = *(const bf16x8*)(aRow);
    bf16x8 a1 = *(const bf16x8*)(aRow + 32);
    bf16x8 a2 = *(const bf16x8*)(aRow + 64);
    bf16x8 a3 = *(const bf16x8*)(aRow + 96);

    {
        const uint4* wg = (const uint4*)(Wn + (size_t)m * NLAYERS * 16384);
        uint4* ws = (uint4*)wF;
        for (int i = tid; i < 2048; i += 256) ws[i] = wg[i];
    }
    __syncthreads();

    f32x4 acc[8] = {};
    const bf16x8* wfrag = (const bf16x8*)wF;
#pragma unroll
    for (int nt = 0; nt < 8; nt++)
        acc[nt] = __builtin_amdgcn_mfma_f32_16x16x32_bf16(a0, wfrag[(0 * 8 + nt) * 64 + lane], acc[nt], 0, 0, 0);
#pragma unroll
    for (int nt = 0; nt < 8; nt++)
        acc[nt] = __builtin_amdgcn_mfma_f32_16x16x32_bf16(a1, wfrag[(1 * 8 + nt) * 64 + lane], acc[nt], 0, 0, 0);
#pragma unroll
    for (int nt = 0; nt < 8; nt++)
        acc[nt] = __builtin_amdgcn_mfma_f32_16x16x32_bf16(a2, wfrag[(2 * 8 + nt) * 64 + lane], acc[nt], 0, 0, 0);
#pragma unroll
    for (int nt = 0; nt < 8; nt++)
        acc[nt] = __builtin_amdgcn_mfma_f32_16x16x32_bf16(a3, wfrag[(3 * 8 + nt) * 64 + lane], acc[nt], 0, 0, 0);
    __syncthreads();

    ushort_t* ss = wF + wv * 16 * STG_S;
#pragma unroll
    for (int nt = 0; nt < 8; nt++)
#pragma unroll
        for (int rg = 0; rg < 4; rg++)
            ss[(q * 4 + rg) * STG_S + nt * 16 + r] = f2b(acc[nt][rg]);

    const uint4* sp = (const uint4*)(ss + el * STG_S + qq * 32);
    if (m < 2) {
        ushort_t* Cp = (m == 0) ? C0 : C1;
        uint4* cp = (uint4*)(Cp + (row + el) * DIM + qq * 32);
#pragma unroll
        for (int cc = 0; cc < 4; cc++) cp[cc] = sp[cc];
    } else {
        // hs: pack 32 bf16 -> 32 fp8 bytes (x16 scale), 4 lanes cover the 128 B row
        unsigned int ob[8];
#pragma unroll
        for (int cc = 0; cc < 4; cc++) {
            uint4 v = sp[cc];
            float f0 = blo(v.x) * HSCALE, f1 = bhi(v.x) * HSCALE;
            float f2 = blo(v.y) * HSCALE, f3 = bhi(v.y) * HSCALE;
            float f4 = blo(v.z) * HSCALE, f5 = bhi(v.z) * HSCALE;
            float f6 = blo(v.w) * HSCALE, f7 = bhi(v.w) * HSCALE;
            ob[cc * 2] = pk8(f0, f1, f2, f3);
            ob[cc * 2 + 1] = pk8(f4, f5, f6, f7);
        }
        uint4* cp = (uint4*)(C2 + (row + el) * DIM + qq * 32);
        cp[0] = make_uint4(ob[0], ob[1], ob[2], ob[3]);
        cp[1] = make_uint4(ob[4], ob[5], ob[6], ob[7]);
    }
}

// single-W with bias + relu (final Wf): h bf16 in, fp32 out
__global__ __launch_bounds__(256) void node_gemm1(
    const ushort_t* __restrict__ A, const float* __restrict__ W,
    const float* __restrict__ bias, float* __restrict__ C) {
    __shared__ float As[64 * 128];
    __shared__ uint2 Ws4[128 * 32];
    int tid = threadIdx.x;
    size_t row0 = (size_t)blockIdx.x * 64;
    const uint2* Ag = (const uint2*)(A + row0 * DIM);
    for (int f = tid; f < 64 * 32; f += 256) {
        uint2 v = Ag[f];
        ((float4*)As)[f] = make_float4(blo(v.x), bhi(v.x), blo(v.y), bhi(v.y));
    }
    const float4* Wg = (const float4*)W;
    for (int i = tid; i < 128 * 32; i += 256) Ws4[i] = pack4(Wg[i]);
    __syncthreads();
    int cq = tid & 31, r0 = (tid >> 5) * 8, c0 = cq * 4;
    float acc[8][4] = {};
    for (int k = 0; k < 128; k++) {
        uint2 wp = Ws4[k * 32 + cq];
        float w0 = blo(wp.x), w1 = bhi(wp.x), w2 = blo(wp.y), w3 = bhi(wp.y);
#pragma unroll
        for (int i = 0; i < 8; i++) {
            float a = As[(r0 + i) * 128 + k];
            acc[i][0] += a * w0; acc[i][1] += a * w1;
            acc[i][2] += a * w2; acc[i][3] += a * w3;
        }
    }
    float b0 = bias[c0], b1 = bias[c0 + 1], b2v = bias[c0 + 2], b3v = bias[c0 + 3];
#pragma unroll
    for (int i = 0; i < 8; i++) {
        *(float4*)&C[(row0 + r0 + i) * DIM + c0] =
            make_float4(fmaxf(acc[i][0] + b0, 0.f), fmaxf(acc[i][1] + b1, 0.f),
                        fmaxf(acc[i][2] + b2v, 0.f), fmaxf(acc[i][3] + b3v, 0.f));
    }
}

// ---------------- fp8 MFMA edge GEMM (layers 1..7) ----------------
__global__ __launch_bounds__(256, 4) void edge_gemm_fp8(
    uchar_t* __restrict__ e,
    const ushort_t* __restrict__ fni, const ushort_t* __restrict__ fnj,
    const int* __restrict__ psrc, const int* __restrict__ pdst,
    const uchar_t* __restrict__ Wf,
    const float* __restrict__ attn, const float* __restrict__ bias,
    float* __restrict__ score) {
    __shared__ __align__(16) char smem[4 * 16 * STG_S * 2];  // 17408 B; W uses first 16384

    int tid = threadIdx.x;
    int wv = tid >> 6, lane = tid & 63;
    int r = lane & 15, q = lane >> 4;
    int el = lane >> 2, qq = lane & 3;
    size_t row = (size_t)blockIdx.x * 64 + 16 * wv;
    size_t eid = row + el;

    int sv = psrc[eid], dv = pdst[eid];

    const uchar_t* aRow = e + (row + r) * DIM + q * 8;
    long long a0 = *(const long long*)(aRow);
    long long a1 = *(const long long*)(aRow + 32);
    long long a2 = *(const long long*)(aRow + 64);
    long long a3 = *(const long long*)(aRow + 96);

    {
        const uint4* wg = (const uint4*)Wf;
        uint4* ws = (uint4*)smem;
        for (int i = tid; i < 1024; i += 256) ws[i] = wg[i];
    }
    __syncthreads();

    f32x4 acc[8] = {};
    const long long* wfrag = (const long long*)smem;
#pragma unroll
    for (int nt = 0; nt < 8; nt++)
        acc[nt] = __builtin_amdgcn_mfma_f32_16x16x32_fp8_fp8(a0, wfrag[(0 * 8 + nt) * 64 + lane], acc[nt], 0, 0, 0);
#pragma unroll
    for (int nt = 0; nt < 8; nt++)
        acc[nt] = __builtin_amdgcn_mfma_f32_16x16x32_fp8_fp8(a1, wfrag[(1 * 8 + nt) * 64 + lane], acc[nt], 0, 0, 0);
#pragma unroll
    for (int nt = 0; nt < 8; nt++)
        acc[nt] = __builtin_amdgcn_mfma_f32_16x16x32_fp8_fp8(a2, wfrag[(2 * 8 + nt) * 64 + lane], acc[nt], 0, 0, 0);
#pragma unroll
    for (int nt = 0; nt < 8; nt++)
        acc[nt] = __builtin_amdgcn_mfma_f32_16x16x32_fp8_fp8(a3, wfrag[(3 * 8 + nt) * 64 + lane], acc[nt], 0, 0, 0);
    __syncthreads();  // W reads done -> staging overlay

    ushort_t* ss = (ushort_t*)smem + wv * 16 * STG_S;
#pragma unroll
    for (int nt = 0; nt < 8; nt++)
#pragma unroll
        for (int rg = 0; rg < 4; rg++)
            ss[(q * 4 + rg) * STG_S + nt * 16 + r] = f2b(acc[nt][rg] * UNSCALE);

    const uint4* nip = (const uint4*)(fni + (size_t)sv * DIM + qq * 32);
    const uint4* njp = (const uint4*)(fnj + (size_t)dv * DIM + qq * 32);
    const uint4* sp = (const uint4*)(ss + el * STG_S + qq * 32);
    unsigned int outb[8];
    float p = 0.f;
#pragma unroll
    for (int cc = 0; cc < 4; cc++) {
        uint4 avq = sp[cc];
        uint4 niq = nip[cc];
        uint4 njq = njp[cc];
        float vv[8];
#pragma unroll
        for (int u = 0; u < 4; u++) {
            unsigned int aw = ((const unsigned int*)&avq)[u];
            unsigned int nw = ((const unsigned int*)&niq)[u];
            unsigned int jw = ((const unsigned int*)&njq)[u];
            int c = qq * 32 + cc * 8 + u * 2;
            float v0 = blo(aw) + blo(nw) + blo(jw) + bias[c];
            float v1 = bhi(aw) + bhi(nw) + bhi(jw) + bias[c + 1];
            v0 = v0 > 0.f ? v0 : 0.01f * v0;
            v1 = v1 > 0.f ? v1 : 0.01f * v1;
            vv[u * 2] = v0; vv[u * 2 + 1] = v1;
            p += v0 * attn[c] + v1 * attn[c + 1];
        }
        outb[cc * 2] = pk8(vv[0] * ESCALE, vv[1] * ESCALE, vv[2] * ESCALE, vv[3] * ESCALE);
        outb[cc * 2 + 1] = pk8(vv[4] * ESCALE, vv[5] * ESCALE, vv[6] * ESCALE, vv[7] * ESCALE);
    }
    uint4* ep = (uint4*)(e + eid * DIM + qq * 32);
    ep[0] = make_uint4(outb[0], outb[1], outb[2], outb[3]);
    ep[1] = make_uint4(outb[4], outb[5], outb[6], outb[7]);
    p += __shfl_xor(p, 1);
    p += __shfl_xor(p, 2);
    if (qq == 0) score[eid] = p;
}

// ---------------- layer-0 edge kernel (fp8 e out) ----------------
__global__ __launch_bounds__(256) void edge0(
    const int* __restrict__ ptok, const float* __restrict__ eftab,
    const ushort_t* __restrict__ fni, const ushort_t* __restrict__ fnj,
    const int* __restrict__ psrc, const int* __restrict__ pdst,
    const float* __restrict__ attn, const float* __restrict__ bias,
    uchar_t* __restrict__ e, float* __restrict__ score) {
    unsigned int gid = blockIdx.x * 256 + threadIdx.x;
    unsigned int eid = gid >> 5;
    int cq = gid & 31, c0 = cq * 4;
    int tok = ptok[eid];
    int sv = psrc[eid], dv = pdst[eid];
    float4 t = *(const float4*)&eftab[tok * DIM + c0];
    uint2 niw = *(const uint2*)(fni + (size_t)sv * DIM + c0);
    uint2 njw = *(const uint2*)(fnj + (size_t)dv * DIM + c0);
    float v0 = t.x + blo(niw.x) + blo(njw.x) + bias[c0];
    float v1 = t.y + bhi(niw.x) + bhi(njw.x) + bias[c0 + 1];
    float v2 = t.z + blo(niw.y) + blo(njw.y) + bias[c0 + 2];
    float v3 = t.w + bhi(niw.y) + bhi(njw.y) + bias[c0 + 3];
    v0 = v0 > 0.f ? v0 : 0.01f * v0;
    v1 = v1 > 0.f ? v1 : 0.01f * v1;
    v2 = v2 > 0.f ? v2 : 0.01f * v2;
    v3 = v3 > 0.f ? v3 : 0.01f * v3;
    *(unsigned int*)(e + (size_t)eid * DIM + c0) =
        pk8(v0 * ESCALE, v1 * ESCALE, v2 * ESCALE, v3 * ESCALE);
    float p = v0 * attn[c0] + v1 * attn[c0 + 1] + v2 * attn[c0 + 2] + v3 * attn[c0 + 3];
#pragma unroll
    for (int o = 1; o < 32; o <<= 1) p += __shfl_xor(p, o);
    if (cq == 0) score[eid] = p;
}

// ---------------- wave-per-node softmax + aggregation (fp8 hs) ----------------
__global__ __launch_bounds__(256) void agg_wave(
    const int* __restrict__ off, const int* __restrict__ psrc,
    const float* __restrict__ score, const uchar_t* __restrict__ hs,
    ushort_t* __restrict__ h) {
    int node = blockIdx.x * 4 + (threadIdx.x >> 6);
    int lane = threadIdx.x & 63;
    int b0 = off[node];
    int deg = off[node + 1] - b0;

    float m = -1e30f;
    for (int j = lane; j < deg; j += 64) m = fmaxf(m, score[b0 + j]);
#pragma unroll
    for (int o = 32; o > 0; o >>= 1) m = fmaxf(m, __shfl_xor(m, o));
    float se = 0.f;
    for (int j = lane; j < deg; j += 64) se += __expf(score[b0 + j] - m);
#pragma unroll
    for (int o = 32; o > 0; o >>= 1) se += __shfl_xor(se, o);
    float inv = (deg > 0) ? 1.f / se : 0.f;

    float acc0 = 0.f, acc1 = 0.f;
    for (int base = 0; base < deg; base += 64) {
        int cnt = min(64, deg - base);
        float wgt = 0.f;
        int sidx = 0;
        if (lane < cnt) {
            wgt = __expf(score[b0 + base + lane] - m) * inv;
            sidx = psrc[b0 + base + lane];
        }
        int i = 0;
        for (; i + 4 <= cnt; i += 4) {
            float w0 = __shfl(wgt, i), w1 = __shfl(wgt, i + 1);
            float w2 = __shfl(wgt, i + 2), w3 = __shfl(wgt, i + 3);
            int s0 = __shfl(sidx, i), s1 = __shfl(sidx, i + 1);
            int s2 = __shfl(sidx, i + 2), s3 = __shfl(sidx, i + 3);
            int h0 = *(const ushort_t*)(hs + (size_t)s0 * DIM + lane * 2);
            int h1 = *(const ushort_t*)(hs + (size_t)s1 * DIM + lane * 2);
            int h2 = *(const ushort_t*)(hs + (size_t)s2 * DIM + lane * 2);
            int h3 = *(const ushort_t*)(hs + (size_t)s3 * DIM + lane * 2);
            acc0 += w0 * __builtin_amdgcn_cvt_f32_fp8(h0, 0);
            acc1 += w0 * __builtin_amdgcn_cvt_f32_fp8(h0, 1);
            acc0 += w1 * __builtin_amdgcn_cvt_f32_fp8(h1, 0);
            acc1 += w1 * __builtin_amdgcn_cvt_f32_fp8(h1, 1);
            acc0 += w2 * __builtin_amdgcn_cvt_f32_fp8(h2, 0);
            acc1 += w2 * __builtin_amdgcn_cvt_f32_fp8(h2, 1);
            acc0 += w3 * __builtin_amdgcn_cvt_f32_fp8(h3, 0);
            acc1 += w3 * __builtin_amdgcn_cvt_f32_fp8(h3, 1);
        }
        for (; i < cnt; i++) {
            float wi = __shfl(wgt, i);
            int si = __shfl(sidx, i);
            int hv = *(const ushort_t*)(hs + (size_t)si * DIM + lane * 2);
            acc0 += wi * __builtin_amdgcn_cvt_f32_fp8(hv, 0);
            acc1 += wi * __builtin_amdgcn_cvt_f32_fp8(hv, 1);
        }
    }
    unsigned int outp = (unsigned int)f2b(fmaxf(acc0 * HUNSCALE, 0.f)) |
                        ((unsigned int)f2b(fmaxf(acc1 * HUNSCALE, 0.f)) << 16);
    *(unsigned int*)(h + (size_t)node * DIM + lane * 2) = outp;
}

// ---------------- wave bitonic sort of 128 features (no barriers) ----------------
__global__ __launch_bounds__(256) void sort_wave(const float* __restrict__ h2,
                                                 float* __restrict__ hsort,
                                                 float* __restrict__ maxval) {
    int node = blockIdx.x * 4 + (threadIdx.x >> 6);
    int lane = threadIdx.x & 63;
    float x0 = h2[(size_t)node * DIM + lane];
    float x1 = h2[(size_t)node * DIM + 64 + lane];
    for (int k = 2; k <= 128; k <<= 1) {
        for (int s = k >> 1; s >= 1; s >>= 1) {
            bool d0 = ((lane & k) == 0);
            bool d1 = (((lane + 64) & k) == 0);
            if (s == 64) {
                float mn = fminf(x0, x1), mx = fmaxf(x0, x1);
                x0 = d0 ? mn : mx;
                x1 = d0 ? mx : mn;
            } else {
                bool low = ((lane & s) == 0);
                float y0 = __shfl_xor(x0, s);
                float y1 = __shfl_xor(x1, s);
                float mn0 = fminf(x0, y0), mx0 = fmaxf(x0, y0);
                float mn1 = fminf(x1, y1), mx1 = fmaxf(x1, y1);
                x0 = (low == d0) ? mn0 : mx0;
                x1 = (low == d1) ? mn1 : mx1;
            }
        }
    }
    hsort[(size_t)node * DIM + lane] = x0;
    hsort[(size_t)node * DIM + 64 + lane] = x1;
    if (lane == 63) maxval[node] = x1;
}

// ---------------- per-graph top-k + gather pooled rows ----------------
__global__ __launch_bounds__(256) void topk_pool(const float* __restrict__ maxval,
                                                 const float* __restrict__ hsort,
                                                 float* __restrict__ pooled) {
    __shared__ float v[256];
    __shared__ int id[256];
    int b = blockIdx.x, t = threadIdx.x;
    v[t] = (t < NPG) ? maxval[b * NPG + t] : -1e30f;
    id[t] = t;
    __syncthreads();
    for (int k = 2; k <= 256; k <<= 1) {
        for (int j = k >> 1; j > 0; j >>= 1) {
            int ixj = t ^ j;
            float va = v[t], vb = v[ixj];
            int ia = id[t], ib = id[ixj];
            __syncthreads();
            bool dirDesc = ((t & k) == 0);
            bool cmp = (va > vb) || (va == vb && ia < ib);
            bool takeMine = ((t < ixj) == (dirDesc == cmp));
            v[t] = takeMine ? va : vb;
            id[t] = takeMine ? ia : ib;
            __syncthreads();
        }
    }
    for (int i = t; i < KPOOL * DIM; i += 256) {
        int kk = i >> 7, d = i & 127;
        pooled[((size_t)b * KPOOL + kk) * DIM + d] = hsort[((size_t)b * NPG + id[kk]) * DIM + d];
    }
}

// ---------------- ft split-K ----------------
__global__ __launch_bounds__(256) void ft_partial(
    const float* __restrict__ pooled, const float* __restrict__ W3,
    float* __restrict__ part) {
    __shared__ float ps[512];
    __shared__ float red[256];
    int b = blockIdx.x, s = blockIdx.y;
    int t = threadIdx.x;
    int d = t & 127, half = t >> 7;
    for (int i = t; i < 512; i += 256) ps[i] = pooled[(size_t)b * 4096 + s * 512 + i];
    __syncthreads();
    float acc = 0.f;
    const float* Wp = W3 + (size_t)(s * 512 + half * 256) * DIM + d;
    const float* pp = ps + half * 256;
#pragma unroll 4
    for (int kk = 0; kk < 256; kk++) acc += pp[kk] * Wp[(size_t)kk * DIM];
    red[t] = acc;
    __syncthreads();
    if (t < 128) part[((size_t)b * 8 + s) * DIM + t] = red[t] + red[t + 128];
}

__global__ __launch_bounds__(128) void ft_reduce(
    const float* __restrict__ part, const float* __restrict__ al3,
    const float* __restrict__ ar3, float* __restrict__ ft,
    float* __restrict__ sl, float* __restrict__ sr) {
    __shared__ float r1[128], r2[128];
    int b = blockIdx.x, d = threadIdx.x;
    float acc = 0.f;
#pragma unroll
    for (int s = 0; s < 8; s++) acc += part[((size_t)b * 8 + s) * DIM + d];
    ft[b * DIM + d] = acc;
    r1[d] = acc * al3[d];
    r2[d] = acc * ar3[d];
    __syncthreads();
    for (int s = 64; s > 0; s >>= 1) {
        if (d < s) { r1[d] += r1[d + s]; r2[d] += r2[d + s]; }
        __syncthreads();
    }
    if (d == 0) { sl[b] = r1[0]; sr[b] = r2[0]; }
}

// ---------------- final-graph GAT ----------------
__global__ __launch_bounds__(128) void fg_kernel(
    const int* __restrict__ fg_src, const int* __restrict__ fg_dst,
    const float* __restrict__ sl, const float* __restrict__ sr,
    const float* __restrict__ ft, const float* __restrict__ b3,
    float* __restrict__ g) {
    __shared__ int list[EFE];
    __shared__ float wgt[EFE];
    __shared__ float red[128];
    __shared__ int cnt;
    int b = blockIdx.x, t = threadIdx.x;
    if (t == 0) cnt = 0;
    __syncthreads();
    for (int e = t; e < EFE; e += 128)
        if (fg_dst[e] == b) { int p = atomicAdd(&cnt, 1); list[p] = e; }
    __syncthreads();
    int deg = cnt;
    float srb = sr[b];
    float m = -1e30f;
    for (int j = t; j < deg; j += 128) {
        float s = sl[fg_src[list[j]]] + srb;
        s = s > 0.f ? s : 0.2f * s;
        m = fmaxf(m, s);
    }
    red[t] = m;
    __syncthreads();
    for (int s = 64; s > 0; s >>= 1) { if (t < s) red[t] = fmaxf(red[t], red[t + s]); __syncthreads(); }
    m = red[0];
    __syncthreads();
    float se = 0.f;
    for (int j = t; j < deg; j += 128) {
        float s = sl[fg_src[list[j]]] + srb;
        s = s > 0.f ? s : 0.2f * s;
        se += __expf(s - m);
    }
    red[t] = se;
    __syncthreads();
    for (int s = 64; s > 0; s >>= 1) { if (t < s) red[t] += red[t + s]; __syncthreads(); }
    float inv = (deg > 0) ? 1.f / red[0] : 0.f;
    __syncthreads();
    for (int j = t; j < deg; j += 128) {
        float s = sl[fg_src[list[j]]] + srb;
        s = s > 0.f ? s : 0.2f * s;
        wgt[j] = __expf(s - m) * inv;
    }
    __syncthreads();
    float acc = 0.f;
    for (int j = 0; j < deg; j++) acc += wgt[j] * ft[(size_t)fg_src[list[j]] * DIM + t];
    g[b * DIM + t] = fmaxf(acc + b3[t], 0.f);
}

// ---------------- g2 = relu(g @ Wl + bl) ----------------
__global__ __launch_bounds__(128) void gl_kernel(const float* __restrict__ g,
                                                 const float* __restrict__ Wl,
                                                 const float* __restrict__ bl,
                                                 float* __restrict__ g2) {
    __shared__ float gs[128];
    int b = blockIdx.x, d = threadIdx.x;
    gs[d] = g[b * DIM + d];
    __syncthreads();
    float acc = 0.f;
    for (int k = 0; k < 128; k++) acc += gs[k] * Wl[k * DIM + d];
    g2[b * DIM + d] = fmaxf(acc + bl[d], 0.f);
}

// ---------------- out = g2 @ Wc + bc ----------------
__global__ __launch_bounds__(256) void out_kernel(const float* __restrict__ g2,
                                                  const float* __restrict__ Wc,
                                                  const float* __restrict__ bc,
                                                  float* __restrict__ out) {
    int i = threadIdx.x;
    int b = i >> 1, j = i & 1;
    float acc = bc[j];
    for (int k = 0; k < 128; k++) acc += g2[b * DIM + k] * Wc[k * 2 + j];
    out[b * 2 + j] = acc;
}

extern "C" void kernel_launch(void* const* d_in, const int* in_sizes, int n_in,
                              void* d_out, int out_size, void* d_ws, size_t ws_size,
                              hipStream_t stream) {
    const int* tokens_h = (const int*)d_in[0];
    const int* tokens_e = (const int*)d_in[1];
    const int* src = (const int*)d_in[2];
    const int* dst = (const int*)d_in[3];
    const int* fg_src = (const int*)d_in[4];
    const int* fg_dst = (const int*)d_in[5];
    const float* token_emb = (const float*)d_in[6];
    const float* e_token_emb = (const float*)d_in[7];
    const float* W_ni = (const float*)d_in[8];
    const float* W_nj = (const float*)d_in[9];
    const float* W_fij = (const float*)d_in[10];
    const float* W_node = (const float*)d_in[11];
    const float* attn_e = (const float*)d_in[12];
    const float* bias_e = (const float*)d_in[13];
    const float* Wf = (const float*)d_in[14];
    const float* bf_ = (const float*)d_in[15];
    const float* W3 = (const float*)d_in[16];
    const float* al3 = (const float*)d_in[17];
    const float* ar3 = (const float*)d_in[18];
    const float* b3 = (const float*)d_in[19];
    const float* Wl = (const float*)d_in[20];
    const float* bl = (const float*)d_in[21];
    const float* Wc = (const float*)d_in[22];
    const float* bc = (const float*)d_in[23];
    float* out = (float*)d_out;

    char* w = (char*)d_ws;
    auto alloc = [&](size_t b) -> char* {
        char* p = w;
        w += (b + 255) & ~(size_t)255;
        return p;
    };
    ushort_t* h = (ushort_t*)alloc((size_t)N_NODES * DIM * 2);
    ushort_t* fni = (ushort_t*)alloc((size_t)N_NODES * DIM * 2);
    ushort_t* fnj = (ushort_t*)alloc((size_t)N_NODES * DIM * 2);
    uchar_t* hs = (uchar_t*)alloc((size_t)N_NODES * DIM);      // fp8 now
    uchar_t* e = (uchar_t*)alloc((size_t)N_EDGES * DIM);       // fp8
    float* score = (float*)alloc((size_t)N_EDGES * 4);
    int* deg = (int*)alloc((size_t)N_NODES * 4);
    int* off = (int*)alloc((size_t)(N_NODES + 1) * 4);
    int* cursor = (int*)alloc((size_t)N_NODES * 4);
    int* bsum = (int*)alloc(64 * 4);
    int* psrc = (int*)alloc((size_t)N_EDGES * 4);
    int* pdst = (int*)alloc((size_t)N_EDGES * 4);
    int* ptok = (int*)alloc((size_t)N_EDGES * 4);
    float* eftab = (float*)alloc(100 * DIM * 4);
    float* maxval = (float*)alloc((size_t)N_NODES * 4);
    float* pooled = (float*)alloc((size_t)BGR * KPOOL * DIM * 4);
    float* ft = (float*)alloc(BGR * DIM * 4);
    float* part = (float*)alloc((size_t)BGR * 8 * DIM * 4);
    float* sl = (float*)alloc(BGR * 4);
    float* sr = (float*)alloc(BGR * 4);
    float* g = (float*)alloc(BGR * DIM * 4);
    float* g2 = (float*)alloc(BGR * DIM * 4);
    uchar_t* Wf7 = (uchar_t*)alloc((size_t)NLAYERS * DIM * DIM);
    ushort_t* Wn = (ushort_t*)alloc((size_t)3 * NLAYERS * DIM * DIM * 2);
    // h2/hsort (fp32, 13.1 MB each) live in the e region (52 MB) after the layer loop
    float* h2 = (float*)e;
    float* hsort = (float*)((char*)e + (size_t)16 * 1024 * 1024);

    // weight prep
    wfprep8<<<(NLAYERS * DIM * DIM) / 256, 256, 0, stream>>>(W_fij, Wf7);
    wnprep<<<(3 * NLAYERS * DIM * DIM) / 256, 256, 0, stream>>>(W_ni, W_nj, W_node, Wn);

    // CSR build + edge permutation (dst-sorted order), hierarchical scan
    zero_deg<<<(N_NODES + 255) / 256, 256, 0, stream>>>(deg, N_NODES);
    count_deg<<<N_EDGES / 256, 256, 0, stream>>>(dst, deg, N_EDGES);
    scan_local<<<(N_NODES + 1023) / 1024, 1024, 0, stream>>>(deg, off, bsum, N_NODES);
    scan_bsum<<<1, 32, 0, stream>>>(bsum, (N_NODES + 1023) / 1024);
    scan_add<<<(N_NODES + 255) / 256, 256, 0, stream>>>(off, bsum, cursor, N_NODES, N_EDGES);
    scatter_perm<<<N_EDGES / 256, 256, 0, stream>>>(src, dst, tokens_e, cursor,
                                                    psrc, pdst, ptok, N_EDGES);

    init_h<<<(N_NODES * DIM) / 256, 256, 0, stream>>>(tokens_h, token_emb, h);
    eftab_kernel<<<100, 128, 0, stream>>>(e_token_emb, W_fij, eftab);

    for (int l = 0; l < NLAYERS; l++) {
        node_gemm_mfma<<<dim3(N_NODES / 64, 3), 256, 0, stream>>>(
            h, Wn + l * 16384, fni, fnj, hs);
        if (l == 0) {
            edge0<<<(N_EDGES * 32) / 256, 256, 0, stream>>>(
                ptok, eftab, fni, fnj, psrc, pdst, attn_e, bias_e, e, score);
        } else {
            edge_gemm_fp8<<<N_EDGES / 64, 256, 0, stream>>>(
                e, fni, fnj, psrc, pdst, Wf7 + (size_t)l * DIM * DIM,
                attn_e + l * DIM, bias_e + l * DIM, score);
        }
        agg_wave<<<N_NODES / 4, 256, 0, stream>>>(off, psrc, score, hs, h);
    }

    node_gemm1<<<N_NODES / 64, 256, 0, stream>>>(h, Wf, bf_, h2);
    sort_wave<<<N_NODES / 4, 256, 0, stream>>>(h2, hsort, maxval);
    topk_pool<<<BGR, 256, 0, stream>>>(maxval, hsort, pooled);
    ft_partial<<<dim3(BGR, 8), 256, 0, stream>>>(pooled, W3, part);
    ft_reduce<<<BGR, 128, 0, stream>>>(part, al3, ar3, ft, sl, sr);
    fg_kernel<<<BGR, 128, 0, stream>>>(fg_src, fg_dst, sl, sr, ft, b3, g);
    gl_kernel<<<BGR, 128, 0, stream>>>(g, Wl, bl, g2);
    out_kernel<<<1, 256, 0, stream>>>(g2, Wc, bc, out);
}

// Round 17
// 1034.569 us; speedup vs baseline: 1.6624x; 1.0839x over previous
//
#include <hip/hip_runtime.h>

#define N_NODES 25600
#define N_EDGES 409600
#define BGR 128
#define EFE 1024
#define DIM 128
#define NLAYERS 8
#define KPOOL 32
#define NPG 200

typedef unsigned short ushort_t;
typedef unsigned char uchar_t;
typedef __attribute__((ext_vector_type(8))) short bf16x8;
typedef __attribute__((ext_vector_type(4))) float f32x4;

#define STG_S 136   // per-wave C-staging stride; 2-way LDS aliasing = free (R15 verified)
#define ESCALE 16.0f
#define WSCALE 4.0f
#define UNSCALE 0.015625f  // 1/64
#define HSCALE 16.0f
#define HUNSCALE 0.0625f   // 1/16

__device__ __forceinline__ float b2f(ushort_t v) {
    return __uint_as_float(((unsigned int)v) << 16);
}
__device__ __forceinline__ float blo(unsigned int u) {
    return __uint_as_float(u << 16);
}
__device__ __forceinline__ float bhi(unsigned int u) {
    return __uint_as_float(u & 0xffff0000u);
}
__device__ __forceinline__ ushort_t f2b(float f) {
    unsigned int u = __float_as_uint(f);
    unsigned int r = (u + 0x7fffu + ((u >> 16) & 1u)) >> 16;
    return (ushort_t)r;
}
__device__ __forceinline__ uint2 pack4(float4 v) {
    uint2 p;
    p.x = (unsigned int)f2b(v.x) | ((unsigned int)f2b(v.y) << 16);
    p.y = (unsigned int)f2b(v.z) | ((unsigned int)f2b(v.w) << 16);
    return p;
}
__device__ __forceinline__ unsigned int pk8(float v0, float v1, float v2, float v3) {
    int d = __builtin_amdgcn_cvt_pk_fp8_f32(v0, v1, 0, false);
    d = __builtin_amdgcn_cvt_pk_fp8_f32(v2, v3, d, true);
    return (unsigned int)d;
}
// constant-selector fp8 decode (builtin requires ICE selector)
template <int SEL>
__device__ __forceinline__ float cvt8(int w) {
    return __builtin_amdgcn_cvt_f32_fp8(w, SEL);
}

// ---------------- W_fij -> fragment-linear fp8 (x4 scale) ----------------
__global__ void wfprep8(const float* __restrict__ W, uchar_t* __restrict__ Wf) {
    int idx = blockIdx.x * 256 + threadIdx.x;  // 8 * 16384
    int l = idx >> 14, rem = idx & 16383;
    int j = rem & 7, lane = (rem >> 3) & 63, nt = (rem >> 9) & 7, kc = rem >> 12;
    int q = lane >> 4, r = lane & 15;
    int k = kc * 32 + q * 8 + j, n = nt * 16 + r;
    float w = W[l * 16384 + k * 128 + n] * WSCALE;
    int d = __builtin_amdgcn_cvt_pk_fp8_f32(w, w, 0, false);
    Wf[idx] = (uchar_t)(d & 0xff);
}

// W_ni / W_nj / W_node -> fragment-linear bf16, layout [m][l][16384]
__global__ void wnprep(const float* __restrict__ Wni, const float* __restrict__ Wnj,
                       const float* __restrict__ Wnode, ushort_t* __restrict__ Wn) {
    int idx = blockIdx.x * 256 + threadIdx.x;  // 3 * 8 * 16384
    int m = idx >> 17;
    int l = (idx >> 14) & 7;
    int rem = idx & 16383;
    int j = rem & 7, lane = (rem >> 3) & 63, nt = (rem >> 9) & 7, kc = rem >> 12;
    int q = lane >> 4, r = lane & 15;
    int k = kc * 32 + q * 8 + j, n = nt * 16 + r;
    const float* W = (m == 0) ? Wni : (m == 1) ? Wnj : Wnode;
    Wn[idx] = f2b(W[l * 16384 + k * 128 + n]);
}

// ---------------- zero deg ----------------
__global__ void zero_deg(int* __restrict__ deg, int n) {
    int i = blockIdx.x * 256 + threadIdx.x;
    if (i < n) deg[i] = 0;
}

// ---------------- CSR build ----------------
__global__ void count_deg(const int* __restrict__ dst, int* __restrict__ deg, int n) {
    int i = blockIdx.x * 256 + threadIdx.x;
    if (i < n) atomicAdd(&deg[dst[i]], 1);
}

__global__ __launch_bounds__(1024) void scan_local(const int* __restrict__ deg,
                                                   int* __restrict__ off,
                                                   int* __restrict__ bsum, int n) {
    __shared__ int buf[1024];
    int b = blockIdx.x, t = threadIdx.x;
    int gi = b * 1024 + t;
    int v = (gi < n) ? deg[gi] : 0;
    buf[t] = v;
    __syncthreads();
    for (int s = 1; s < 1024; s <<= 1) {
        int x = (t >= s) ? buf[t - s] : 0;
        __syncthreads();
        buf[t] += x;
        __syncthreads();
    }
    if (gi < n) off[gi] = buf[t] - v;
    if (t == 1023) bsum[b] = buf[1023];
}

__global__ void scan_bsum(int* __restrict__ bsum, int nb) {
    if (threadIdx.x == 0) {
        int acc = 0;
        for (int i = 0; i < nb; i++) { int v = bsum[i]; bsum[i] = acc; acc += v; }
    }
}

__global__ void scan_add(int* __restrict__ off, const int* __restrict__ bsum,
                         int* __restrict__ cursor, int n, int total) {
    int i = blockIdx.x * 256 + threadIdx.x;
    if (i < n) {
        int v = off[i] + bsum[i >> 10];
        off[i] = v;
        cursor[i] = v;
    }
    if (i == 0) off[n] = total;
}

__global__ void scatter_perm(const int* __restrict__ src, const int* __restrict__ dst,
                             const int* __restrict__ tokens_e, int* __restrict__ cursor,
                             int* __restrict__ psrc, int* __restrict__ pdst,
                             int* __restrict__ ptok, int n) {
    int i = blockIdx.x * 256 + threadIdx.x;
    if (i < n) {
        int p = atomicAdd(&cursor[dst[i]], 1);
        psrc[p] = src[i];
        pdst[p] = dst[i];
        ptok[p] = tokens_e[i];
    }
}

// ---------------- init (h bf16) ----------------
__global__ void init_h(const int* __restrict__ tok, const float* __restrict__ emb,
                       ushort_t* __restrict__ h) {
    int i = blockIdx.x * 256 + threadIdx.x;
    int r = i >> 7, d = i & 127;
    float v = emb[tok[r] * DIM + d];
    h[i] = f2b(fmaxf(v, 0.f));
}

__global__ __launch_bounds__(128) void eftab_kernel(const float* __restrict__ etab,
                                                    const float* __restrict__ W,
                                                    float* __restrict__ out) {
    int r = blockIdx.x, d = threadIdx.x;
    float acc = 0.f;
    for (int k = 0; k < DIM; k++)
        acc += etab[r * DIM + k] * W[k * DIM + d];
    out[r * DIM + d] = acc;
}

// ---------------- MFMA node GEMM: grid (400, 3); ALL outputs fp8 x16 ----------------
__global__ __launch_bounds__(256, 4) void node_gemm_mfma(
    const ushort_t* __restrict__ h,
    const ushort_t* __restrict__ Wn,
    uchar_t* __restrict__ C0, uchar_t* __restrict__ C1, uchar_t* __restrict__ C2) {
    __shared__ __align__(16) ushort_t wF[16384];
    int tid = threadIdx.x, wv = tid >> 6, lane = tid & 63;
    int r = lane & 15, q = lane >> 4;
    int el = lane >> 2, qq = lane & 3;
    int m = blockIdx.y;
    size_t row = (size_t)blockIdx.x * 64 + 16 * wv;

    const ushort_t* aRow = h + (row + r) * DIM + q * 8;
    bf16x8 a0 = *(const bf16x8*)(aRow);
    bf16x8 a1 = *(const bf16x8*)(aRow + 32);
    bf16x8 a2 = *(const bf16x8*)(aRow + 64);
    bf16x8 a3 = *(const bf16x8*)(aRow + 96);

    {
        const uint4* wg = (const uint4*)(Wn + (size_t)m * NLAYERS * 16384);
        uint4* ws = (uint4*)wF;
        for (int i = tid; i < 2048; i += 256) ws[i] = wg[i];
    }
    __syncthreads();

    f32x4 acc[8] = {};
    const bf16x8* wfrag = (const bf16x8*)wF;
#pragma unroll
    for (int nt = 0; nt < 8; nt++)
        acc[nt] = __builtin_amdgcn_mfma_f32_16x16x32_bf16(a0, wfrag[(0 * 8 + nt) * 64 + lane], acc[nt], 0, 0, 0);
#pragma unroll
    for (int nt = 0; nt < 8; nt++)
        acc[nt] = __builtin_amdgcn_mfma_f32_16x16x32_bf16(a1, wfrag[(1 * 8 + nt) * 64 + lane], acc[nt], 0, 0, 0);
#pragma unroll
    for (int nt = 0; nt < 8; nt++)
        acc[nt] = __builtin_amdgcn_mfma_f32_16x16x32_bf16(a2, wfrag[(2 * 8 + nt) * 64 + lane], acc[nt], 0, 0, 0);
#pragma unroll
    for (int nt = 0; nt < 8; nt++)
        acc[nt] = __builtin_amdgcn_mfma_f32_16x16x32_bf16(a3, wfrag[(3 * 8 + nt) * 64 + lane], acc[nt], 0, 0, 0);
    __syncthreads();

    ushort_t* ss = wF + wv * 16 * STG_S;
#pragma unroll
    for (int nt = 0; nt < 8; nt++)
#pragma unroll
        for (int rg = 0; rg < 4; rg++)
            ss[(q * 4 + rg) * STG_S + nt * 16 + r] = f2b(acc[nt][rg]);

    const uint4* sp = (const uint4*)(ss + el * STG_S + qq * 32);
    uchar_t* Cp = (m == 0) ? C0 : (m == 1) ? C1 : C2;
    unsigned int ob[8];
#pragma unroll
    for (int cc = 0; cc < 4; cc++) {
        uint4 v = sp[cc];
        ob[cc * 2] = pk8(blo(v.x) * HSCALE, bhi(v.x) * HSCALE,
                         blo(v.y) * HSCALE, bhi(v.y) * HSCALE);
        ob[cc * 2 + 1] = pk8(blo(v.z) * HSCALE, bhi(v.z) * HSCALE,
                             blo(v.w) * HSCALE, bhi(v.w) * HSCALE);
    }
    uint4* cp = (uint4*)(Cp + (row + el) * DIM + qq * 32);
    cp[0] = make_uint4(ob[0], ob[1], ob[2], ob[3]);
    cp[1] = make_uint4(ob[4], ob[5], ob[6], ob[7]);
}

// single-W with bias + relu (final Wf): h bf16 in, fp32 out
__global__ __launch_bounds__(256) void node_gemm1(
    const ushort_t* __restrict__ A, const float* __restrict__ W,
    const float* __restrict__ bias, float* __restrict__ C) {
    __shared__ float As[64 * 128];
    __shared__ uint2 Ws4[128 * 32];
    int tid = threadIdx.x;
    size_t row0 = (size_t)blockIdx.x * 64;
    const uint2* Ag = (const uint2*)(A + row0 * DIM);
    for (int f = tid; f < 64 * 32; f += 256) {
        uint2 v = Ag[f];
        ((float4*)As)[f] = make_float4(blo(v.x), bhi(v.x), blo(v.y), bhi(v.y));
    }
    const float4* Wg = (const float4*)W;
    for (int i = tid; i < 128 * 32; i += 256) Ws4[i] = pack4(Wg[i]);
    __syncthreads();
    int cq = tid & 31, r0 = (tid >> 5) * 8, c0 = cq * 4;
    float acc[8][4] = {};
    for (int k = 0; k < 128; k++) {
        uint2 wp = Ws4[k * 32 + cq];
        float w0 = blo(wp.x), w1 = bhi(wp.x), w2 = blo(wp.y), w3 = bhi(wp.y);
#pragma unroll
        for (int i = 0; i < 8; i++) {
            float a = As[(r0 + i) * 128 + k];
            acc[i][0] += a * w0; acc[i][1] += a * w1;
            acc[i][2] += a * w2; acc[i][3] += a * w3;
        }
    }
    float b0 = bias[c0], b1 = bias[c0 + 1], b2v = bias[c0 + 2], b3v = bias[c0 + 3];
#pragma unroll
    for (int i = 0; i < 8; i++) {
        *(float4*)&C[(row0 + r0 + i) * DIM + c0] =
            make_float4(fmaxf(acc[i][0] + b0, 0.f), fmaxf(acc[i][1] + b1, 0.f),
                        fmaxf(acc[i][2] + b2v, 0.f), fmaxf(acc[i][3] + b3v, 0.f));
    }
}

// ---------------- fp8 MFMA edge GEMM (layers 1..7); fni/fnj fp8 ----------------
__global__ __launch_bounds__(256, 4) void edge_gemm_fp8(
    uchar_t* __restrict__ e,
    const uchar_t* __restrict__ fni, const uchar_t* __restrict__ fnj,
    const int* __restrict__ psrc, const int* __restrict__ pdst,
    const uchar_t* __restrict__ Wf,
    const float* __restrict__ attn, const float* __restrict__ bias,
    float* __restrict__ score) {
    __shared__ __align__(16) char smem[4 * 16 * STG_S * 2];  // 17408 B; W uses first 16384

    int tid = threadIdx.x;
    int wv = tid >> 6, lane = tid & 63;
    int r = lane & 15, q = lane >> 4;
    int el = lane >> 2, qq = lane & 3;
    size_t row = (size_t)blockIdx.x * 64 + 16 * wv;
    size_t eid = row + el;

    int sv = psrc[eid], dv = pdst[eid];

    const uchar_t* aRow = e + (row + r) * DIM + q * 8;
    long long a0 = *(const long long*)(aRow);
    long long a1 = *(const long long*)(aRow + 32);
    long long a2 = *(const long long*)(aRow + 64);
    long long a3 = *(const long long*)(aRow + 96);

    {
        const uint4* wg = (const uint4*)Wf;
        uint4* ws = (uint4*)smem;
        for (int i = tid; i < 1024; i += 256) ws[i] = wg[i];
    }
    __syncthreads();

    f32x4 acc[8] = {};
    const long long* wfrag = (const long long*)smem;
#pragma unroll
    for (int nt = 0; nt < 8; nt++)
        acc[nt] = __builtin_amdgcn_mfma_f32_16x16x32_fp8_fp8(a0, wfrag[(0 * 8 + nt) * 64 + lane], acc[nt], 0, 0, 0);
#pragma unroll
    for (int nt = 0; nt < 8; nt++)
        acc[nt] = __builtin_amdgcn_mfma_f32_16x16x32_fp8_fp8(a1, wfrag[(1 * 8 + nt) * 64 + lane], acc[nt], 0, 0, 0);
#pragma unroll
    for (int nt = 0; nt < 8; nt++)
        acc[nt] = __builtin_amdgcn_mfma_f32_16x16x32_fp8_fp8(a2, wfrag[(2 * 8 + nt) * 64 + lane], acc[nt], 0, 0, 0);
#pragma unroll
    for (int nt = 0; nt < 8; nt++)
        acc[nt] = __builtin_amdgcn_mfma_f32_16x16x32_fp8_fp8(a3, wfrag[(3 * 8 + nt) * 64 + lane], acc[nt], 0, 0, 0);
    __syncthreads();  // W reads done -> staging overlay

    ushort_t* ss = (ushort_t*)smem + wv * 16 * STG_S;
#pragma unroll
    for (int nt = 0; nt < 8; nt++)
#pragma unroll
        for (int rg = 0; rg < 4; rg++)
            ss[(q * 4 + rg) * STG_S + nt * 16 + r] = f2b(acc[nt][rg] * UNSCALE);

    // fp8 gathers: 32 bytes each for my 32 cols
    unsigned int niw[8], njw[8];
    {
        const uint4* nip = (const uint4*)(fni + (size_t)sv * DIM + qq * 32);
        const uint4* njp = (const uint4*)(fnj + (size_t)dv * DIM + qq * 32);
        *(uint4*)&niw[0] = nip[0]; *(uint4*)&niw[4] = nip[1];
        *(uint4*)&njw[0] = njp[0]; *(uint4*)&njw[4] = njp[1];
    }
    const uint4* sp = (const uint4*)(ss + el * STG_S + qq * 32);
    unsigned int outb[8];
    float p = 0.f;
#pragma unroll
    for (int cc = 0; cc < 4; cc++) {
        uint4 avq = sp[cc];
        int wlo_i = (int)niw[cc * 2], whi_i = (int)niw[cc * 2 + 1];
        int wlo_j = (int)njw[cc * 2], whi_j = (int)njw[cc * 2 + 1];
        float niv[8], njv[8];
        niv[0] = cvt8<0>(wlo_i); niv[1] = cvt8<1>(wlo_i);
        niv[2] = cvt8<2>(wlo_i); niv[3] = cvt8<3>(wlo_i);
        niv[4] = cvt8<0>(whi_i); niv[5] = cvt8<1>(whi_i);
        niv[6] = cvt8<2>(whi_i); niv[7] = cvt8<3>(whi_i);
        njv[0] = cvt8<0>(wlo_j); njv[1] = cvt8<1>(wlo_j);
        njv[2] = cvt8<2>(wlo_j); njv[3] = cvt8<3>(wlo_j);
        njv[4] = cvt8<0>(whi_j); njv[5] = cvt8<1>(whi_j);
        njv[6] = cvt8<2>(whi_j); njv[7] = cvt8<3>(whi_j);
        float vv[8];
#pragma unroll
        for (int u = 0; u < 4; u++) {
            unsigned int aw = ((const unsigned int*)&avq)[u];
            int c = qq * 32 + cc * 8 + u * 2;
            float v0 = blo(aw) + (niv[u * 2] + njv[u * 2]) * HUNSCALE + bias[c];
            float v1 = bhi(aw) + (niv[u * 2 + 1] + njv[u * 2 + 1]) * HUNSCALE + bias[c + 1];
            v0 = v0 > 0.f ? v0 : 0.01f * v0;
            v1 = v1 > 0.f ? v1 : 0.01f * v1;
            vv[u * 2] = v0; vv[u * 2 + 1] = v1;
            p += v0 * attn[c] + v1 * attn[c + 1];
        }
        outb[cc * 2] = pk8(vv[0] * ESCALE, vv[1] * ESCALE, vv[2] * ESCALE, vv[3] * ESCALE);
        outb[cc * 2 + 1] = pk8(vv[4] * ESCALE, vv[5] * ESCALE, vv[6] * ESCALE, vv[7] * ESCALE);
    }
    uint4* ep = (uint4*)(e + eid * DIM + qq * 32);
    ep[0] = make_uint4(outb[0], outb[1], outb[2], outb[3]);
    ep[1] = make_uint4(outb[4], outb[5], outb[6], outb[7]);
    p += __shfl_xor(p, 1);
    p += __shfl_xor(p, 2);
    if (qq == 0) score[eid] = p;
}

// ---------------- layer-0 edge kernel (fp8 fni/fnj, fp8 e out) ----------------
__global__ __launch_bounds__(256) void edge0(
    const int* __restrict__ ptok, const float* __restrict__ eftab,
    const uchar_t* __restrict__ fni, const uchar_t* __restrict__ fnj,
    const int* __restrict__ psrc, const int* __restrict__ pdst,
    const float* __restrict__ attn, const float* __restrict__ bias,
    uchar_t* __restrict__ e, float* __restrict__ score) {
    unsigned int gid = blockIdx.x * 256 + threadIdx.x;
    unsigned int eid = gid >> 5;
    int cq = gid & 31, c0 = cq * 4;
    int tok = ptok[eid];
    int sv = psrc[eid], dv = pdst[eid];
    float4 t = *(const float4*)&eftab[tok * DIM + c0];
    int niw = *(const int*)(fni + (size_t)sv * DIM + c0);
    int njw = *(const int*)(fnj + (size_t)dv * DIM + c0);
    float v0 = t.x + (cvt8<0>(niw) + cvt8<0>(njw)) * HUNSCALE + bias[c0];
    float v1 = t.y + (cvt8<1>(niw) + cvt8<1>(njw)) * HUNSCALE + bias[c0 + 1];
    float v2 = t.z + (cvt8<2>(niw) + cvt8<2>(njw)) * HUNSCALE + bias[c0 + 2];
    float v3 = t.w + (cvt8<3>(niw) + cvt8<3>(njw)) * HUNSCALE + bias[c0 + 3];
    v0 = v0 > 0.f ? v0 : 0.01f * v0;
    v1 = v1 > 0.f ? v1 : 0.01f * v1;
    v2 = v2 > 0.f ? v2 : 0.01f * v2;
    v3 = v3 > 0.f ? v3 : 0.01f * v3;
    *(unsigned int*)(e + (size_t)eid * DIM + c0) =
        pk8(v0 * ESCALE, v1 * ESCALE, v2 * ESCALE, v3 * ESCALE);
    float p = v0 * attn[c0] + v1 * attn[c0 + 1] + v2 * attn[c0 + 2] + v3 * attn[c0 + 3];
#pragma unroll
    for (int o = 1; o < 32; o <<= 1) p += __shfl_xor(p, o);
    if (cq == 0) score[eid] = p;
}

// ---------------- wave-per-node softmax + aggregation (fp8 hs) ----------------
__global__ __launch_bounds__(256) void agg_wave(
    const int* __restrict__ off, const int* __restrict__ psrc,
    const float* __restrict__ score, const uchar_t* __restrict__ hs,
    ushort_t* __restrict__ h) {
    int node = blockIdx.x * 4 + (threadIdx.x >> 6);
    int lane = threadIdx.x & 63;
    int b0 = off[node];
    int deg = off[node + 1] - b0;

    float m = -1e30f;
    for (int j = lane; j < deg; j += 64) m = fmaxf(m, score[b0 + j]);
#pragma unroll
    for (int o = 32; o > 0; o >>= 1) m = fmaxf(m, __shfl_xor(m, o));
    float se = 0.f;
    for (int j = lane; j < deg; j += 64) se += __expf(score[b0 + j] - m);
#pragma unroll
    for (int o = 32; o > 0; o >>= 1) se += __shfl_xor(se, o);
    float inv = (deg > 0) ? 1.f / se : 0.f;

    float acc0 = 0.f, acc1 = 0.f;
    for (int base = 0; base < deg; base += 64) {
        int cnt = min(64, deg - base);
        float wgt = 0.f;
        int sidx = 0;
        if (lane < cnt) {
            wgt = __expf(score[b0 + base + lane] - m) * inv;
            sidx = psrc[b0 + base + lane];
        }
        int i = 0;
        for (; i + 4 <= cnt; i += 4) {
            float w0 = __shfl(wgt, i), w1 = __shfl(wgt, i + 1);
            float w2 = __shfl(wgt, i + 2), w3 = __shfl(wgt, i + 3);
            int s0 = __shfl(sidx, i), s1 = __shfl(sidx, i + 1);
            int s2 = __shfl(sidx, i + 2), s3 = __shfl(sidx, i + 3);
            int h0 = *(const ushort_t*)(hs + (size_t)s0 * DIM + lane * 2);
            int h1 = *(const ushort_t*)(hs + (size_t)s1 * DIM + lane * 2);
            int h2 = *(const ushort_t*)(hs + (size_t)s2 * DIM + lane * 2);
            int h3 = *(const ushort_t*)(hs + (size_t)s3 * DIM + lane * 2);
            acc0 += w0 * cvt8<0>(h0);
            acc1 += w0 * cvt8<1>(h0);
            acc0 += w1 * cvt8<0>(h1);
            acc1 += w1 * cvt8<1>(h1);
            acc0 += w2 * cvt8<0>(h2);
            acc1 += w2 * cvt8<1>(h2);
            acc0 += w3 * cvt8<0>(h3);
            acc1 += w3 * cvt8<1>(h3);
        }
        for (; i < cnt; i++) {
            float wi = __shfl(wgt, i);
            int si = __shfl(sidx, i);
            int hv = *(const ushort_t*)(hs + (size_t)si * DIM + lane * 2);
            acc0 += wi * cvt8<0>(hv);
            acc1 += wi * cvt8<1>(hv);
        }
    }
    unsigned int outp = (unsigned int)f2b(fmaxf(acc0 * HUNSCALE, 0.f)) |
                        ((unsigned int)f2b(fmaxf(acc1 * HUNSCALE, 0.f)) << 16);
    *(unsigned int*)(h + (size_t)node * DIM + lane * 2) = outp;
}

// ---------------- wave bitonic sort of 128 features (no barriers) ----------------
__global__ __launch_bounds__(256) void sort_wave(const float* __restrict__ h2,
                                                 float* __restrict__ hsort,
                                                 float* __restrict__ maxval) {
    int node = blockIdx.x * 4 + (threadIdx.x >> 6);
    int lane = threadIdx.x & 63;
    float x0 = h2[(size_t)node * DIM + lane];
    float x1 = h2[(size_t)node * DIM + 64 + lane];
    for (int k = 2; k <= 128; k <<= 1) {
        for (int s = k >> 1; s >= 1; s >>= 1) {
            bool d0 = ((lane & k) == 0);
            bool d1 = (((lane + 64) & k) == 0);
            if (s == 64) {
                float mn = fminf(x0, x1), mx = fmaxf(x0, x1);
                x0 = d0 ? mn : mx;
                x1 = d0 ? mx : mn;
            } else {
                bool low = ((lane & s) == 0);
                float y0 = __shfl_xor(x0, s);
                float y1 = __shfl_xor(x1, s);
                float mn0 = fminf(x0, y0), mx0 = fmaxf(x0, y0);
                float mn1 = fminf(x1, y1), mx1 = fmaxf(x1, y1);
                x0 = (low == d0) ? mn0 : mx0;
                x1 = (low == d1) ? mn1 : mx1;
            }
        }
    }
    hsort[(size_t)node * DIM + lane] = x0;
    hsort[(size_t)node * DIM + 64 + lane] = x1;
    if (lane == 63) maxval[node] = x1;
}

// ---------------- per-graph top-k + gather pooled rows ----------------
__global__ __launch_bounds__(256) void topk_pool(const float* __restrict__ maxval,
                                                 const float* __restrict__ hsort,
                                                 float* __restrict__ pooled) {
    __shared__ float v[256];
    __shared__ int id[256];
    int b = blockIdx.x, t = threadIdx.x;
    v[t] = (t < NPG) ? maxval[b * NPG + t] : -1e30f;
    id[t] = t;
    __syncthreads();
    for (int k = 2; k <= 256; k <<= 1) {
        for (int j = k >> 1; j > 0; j >>= 1) {
            int ixj = t ^ j;
            float va = v[t], vb = v[ixj];
            int ia = id[t], ib = id[ixj];
            __syncthreads();
            bool dirDesc = ((t & k) == 0);
            bool cmp = (va > vb) || (va == vb && ia < ib);
            bool takeMine = ((t < ixj) == (dirDesc == cmp));
            v[t] = takeMine ? va : vb;
            id[t] = takeMine ? ia : ib;
            __syncthreads();
        }
    }
    for (int i = t; i < KPOOL * DIM; i += 256) {
        int kk = i >> 7, d = i & 127;
        pooled[((size_t)b * KPOOL + kk) * DIM + d] = hsort[((size_t)b * NPG + id[kk]) * DIM + d];
    }
}

// ---------------- ft split-K ----------------
__global__ __launch_bounds__(256) void ft_partial(
    const float* __restrict__ pooled, const float* __restrict__ W3,
    float* __restrict__ part) {
    __shared__ float ps[512];
    __shared__ float red[256];
    int b = blockIdx.x, s = blockIdx.y;
    int t = threadIdx.x;
    int d = t & 127, half = t >> 7;
    for (int i = t; i < 512; i += 256) ps[i] = pooled[(size_t)b * 4096 + s * 512 + i];
    __syncthreads();
    float acc = 0.f;
    const float* Wp = W3 + (size_t)(s * 512 + half * 256) * DIM + d;
    const float* pp = ps + half * 256;
#pragma unroll 4
    for (int kk = 0; kk < 256; kk++) acc += pp[kk] * Wp[(size_t)kk * DIM];
    red[t] = acc;
    __syncthreads();
    if (t < 128) part[((size_t)b * 8 + s) * DIM + t] = red[t] + red[t + 128];
}

__global__ __launch_bounds__(128) void ft_reduce(
    const float* __restrict__ part, const float* __restrict__ al3,
    const float* __restrict__ ar3, float* __restrict__ ft,
    float* __restrict__ sl, float* __restrict__ sr) {
    __shared__ float r1[128], r2[128];
    int b = blockIdx.x, d = threadIdx.x;
    float acc = 0.f;
#pragma unroll
    for (int s = 0; s < 8; s++) acc += part[((size_t)b * 8 + s) * DIM + d];
    ft[b * DIM + d] = acc;
    r1[d] = acc * al3[d];
    r2[d] = acc * ar3[d];
    __syncthreads();
    for (int s = 64; s > 0; s >>= 1) {
        if (d < s) { r1[d] += r1[d + s]; r2[d] += r2[d + s]; }
        __syncthreads();
    }
    if (d == 0) { sl[b] = r1[0]; sr[b] = r2[0]; }
}

// ---------------- final-graph GAT ----------------
__global__ __launch_bounds__(128) void fg_kernel(
    const int* __restrict__ fg_src, const int* __restrict__ fg_dst,
    const float* __restrict__ sl, const float* __restrict__ sr,
    const float* __restrict__ ft, const float* __restrict__ b3,
    float* __restrict__ g) {
    __shared__ int list[EFE];
    __shared__ float wgt[EFE];
    __shared__ float red[128];
    __shared__ int cnt;
    int b = blockIdx.x, t = threadIdx.x;
    if (t == 0) cnt = 0;
    __syncthreads();
    for (int e = t; e < EFE; e += 128)
        if (fg_dst[e] == b) { int p = atomicAdd(&cnt, 1); list[p] = e; }
    __syncthreads();
    int deg = cnt;
    float srb = sr[b];
    float m = -1e30f;
    for (int j = t; j < deg; j += 128) {
        float s = sl[fg_src[list[j]]] + srb;
        s = s > 0.f ? s : 0.2f * s;
        m = fmaxf(m, s);
    }
    red[t] = m;
    __syncthreads();
    for (int s = 64; s > 0; s >>= 1) { if (t < s) red[t] = fmaxf(red[t], red[t + s]); __syncthreads(); }
    m = red[0];
    __syncthreads();
    float se = 0.f;
    for (int j = t; j < deg; j += 128) {
        float s = sl[fg_src[list[j]]] + srb;
        s = s > 0.f ? s : 0.2f * s;
        se += __expf(s - m);
    }
    red[t] = se;
    __syncthreads();
    for (int s = 64; s > 0; s >>= 1) { if (t < s) red[t] += red[t + s]; __syncthreads(); }
    float inv = (deg > 0) ? 1.f / red[0] : 0.f;
    __syncthreads();
    for (int j = t; j < deg; j += 128) {
        float s = sl[fg_src[list[j]]] + srb;
        s = s > 0.f ? s : 0.2f * s;
        wgt[j] = __expf(s - m) * inv;
    }
    __syncthreads();
    float acc = 0.f;
    for (int j = 0; j < deg; j++) acc += wgt[j] * ft[(size_t)fg_src[list[j]] * DIM + t];
    g[b * DIM + t] = fmaxf(acc + b3[t], 0.f);
}

// ---------------- g2 = relu(g @ Wl + bl) ----------------
__global__ __launch_bounds__(128) void gl_kernel(const float* __restrict__ g,
                                                 const float* __restrict__ Wl,
                                                 const float* __restrict__ bl,
                                                 float* __restrict__ g2) {
    __shared__ float gs[128];
    int b = blockIdx.x, d = threadIdx.x;
    gs[d] = g[b * DIM + d];
    __syncthreads();
    float acc = 0.f;
    for (int k = 0; k < 128; k++) acc += gs[k] * Wl[k * DIM + d];
    g2[b * DIM + d] = fmaxf(acc + bl[d], 0.f);
}

// ---------------- out = g2 @ Wc + bc ----------------
__global__ __launch_bounds__(256) void out_kernel(const float* __restrict__ g2,
                                                  const float* __restrict__ Wc,
                                                  const float* __restrict__ bc,
                                                  float* __restrict__ out) {
    int i = threadIdx.x;
    int b = i >> 1, j = i & 1;
    float acc = bc[j];
    for (int k = 0; k < 128; k++) acc += g2[b * DIM + k] * Wc[k * 2 + j];
    out[b * 2 + j] = acc;
}

extern "C" void kernel_launch(void* const* d_in, const int* in_sizes, int n_in,
                              void* d_out, int out_size, void* d_ws, size_t ws_size,
                              hipStream_t stream) {
    const int* tokens_h = (const int*)d_in[0];
    const int* tokens_e = (const int*)d_in[1];
    const int* src = (const int*)d_in[2];
    const int* dst = (const int*)d_in[3];
    const int* fg_src = (const int*)d_in[4];
    const int* fg_dst = (const int*)d_in[5];
    const float* token_emb = (const float*)d_in[6];
    const float* e_token_emb = (const float*)d_in[7];
    const float* W_ni = (const float*)d_in[8];
    const float* W_nj = (const float*)d_in[9];
    const float* W_fij = (const float*)d_in[10];
    const float* W_node = (const float*)d_in[11];
    const float* attn_e = (const float*)d_in[12];
    const float* bias_e = (const float*)d_in[13];
    const float* Wf = (const float*)d_in[14];
    const float* bf_ = (const float*)d_in[15];
    const float* W3 = (const float*)d_in[16];
    const float* al3 = (const float*)d_in[17];
    const float* ar3 = (const float*)d_in[18];
    const float* b3 = (const float*)d_in[19];
    const float* Wl = (const float*)d_in[20];
    const float* bl = (const float*)d_in[21];
    const float* Wc = (const float*)d_in[22];
    const float* bc = (const float*)d_in[23];
    float* out = (float*)d_out;

    char* w = (char*)d_ws;
    auto alloc = [&](size_t b) -> char* {
        char* p = w;
        w += (b + 255) & ~(size_t)255;
        return p;
    };
    ushort_t* h = (ushort_t*)alloc((size_t)N_NODES * DIM * 2);
    uchar_t* fni = (uchar_t*)alloc((size_t)N_NODES * DIM);     // fp8
    uchar_t* fnj = (uchar_t*)alloc((size_t)N_NODES * DIM);     // fp8
    uchar_t* hs = (uchar_t*)alloc((size_t)N_NODES * DIM);      // fp8
    uchar_t* e = (uchar_t*)alloc((size_t)N_EDGES * DIM);       // fp8
    float* score = (float*)alloc((size_t)N_EDGES * 4);
    int* deg = (int*)alloc((size_t)N_NODES * 4);
    int* off = (int*)alloc((size_t)(N_NODES + 1) * 4);
    int* cursor = (int*)alloc((size_t)N_NODES * 4);
    int* bsum = (int*)alloc(64 * 4);
    int* psrc = (int*)alloc((size_t)N_EDGES * 4);
    int* pdst = (int*)alloc((size_t)N_EDGES * 4);
    int* ptok = (int*)alloc((size_t)N_EDGES * 4);
    float* eftab = (float*)alloc(100 * DIM * 4);
    float* maxval = (float*)alloc((size_t)N_NODES * 4);
    float* pooled = (float*)alloc((size_t)BGR * KPOOL * DIM * 4);
    float* ft = (float*)alloc(BGR * DIM * 4);
    float* part = (float*)alloc((size_t)BGR * 8 * DIM * 4);
    float* sl = (float*)alloc(BGR * 4);
    float* sr = (float*)alloc(BGR * 4);
    float* g = (float*)alloc(BGR * DIM * 4);
    float* g2 = (float*)alloc(BGR * DIM * 4);
    uchar_t* Wf7 = (uchar_t*)alloc((size_t)NLAYERS * DIM * DIM);
    ushort_t* Wn = (ushort_t*)alloc((size_t)3 * NLAYERS * DIM * DIM * 2);
    // h2/hsort (fp32, 13.1 MB each) live in the e region (52 MB) after the layer loop
    float* h2 = (float*)e;
    float* hsort = (float*)((char*)e + (size_t)16 * 1024 * 1024);

    // weight prep
    wfprep8<<<(NLAYERS * DIM * DIM) / 256, 256, 0, stream>>>(W_fij, Wf7);
    wnprep<<<(3 * NLAYERS * DIM * DIM) / 256, 256, 0, stream>>>(W_ni, W_nj, W_node, Wn);

    // CSR build + edge permutation (dst-sorted order), hierarchical scan
    zero_deg<<<(N_NODES + 255) / 256, 256, 0, stream>>>(deg, N_NODES);
    count_deg<<<N_EDGES / 256, 256, 0, stream>>>(dst, deg, N_EDGES);
    scan_local<<<(N_NODES + 1023) / 1024, 1024, 0, stream>>>(deg, off, bsum, N_NODES);
    scan_bsum<<<1, 32, 0, stream>>>(bsum, (N_NODES + 1023) / 1024);
    scan_add<<<(N_NODES + 255) / 256, 256, 0, stream>>>(off, bsum, cursor, N_NODES, N_EDGES);
    scatter_perm<<<N_EDGES / 256, 256, 0, stream>>>(src, dst, tokens_e, cursor,
                                                    psrc, pdst, ptok, N_EDGES);

    init_h<<<(N_NODES * DIM) / 256, 256, 0, stream>>>(tokens_h, token_emb, h);
    eftab_kernel<<<100, 128, 0, stream>>>(e_token_emb, W_fij, eftab);

    for (int l = 0; l < NLAYERS; l++) {
        node_gemm_mfma<<<dim3(N_NODES / 64, 3), 256, 0, stream>>>(
            h, Wn + l * 16384, fni, fnj, hs);
        if (l == 0) {
            edge0<<<(N_EDGES * 32) / 256, 256, 0, stream>>>(
                ptok, eftab, fni, fnj, psrc, pdst, attn_e, bias_e, e, score);
        } else {
            edge_gemm_fp8<<<N_EDGES / 64, 256, 0, stream>>>(
                e, fni, fnj, psrc, pdst, Wf7 + (size_t)l * DIM * DIM,
                attn_e + l * DIM, bias_e + l * DIM, score);
        }
        agg_wave<<<N_NODES / 4, 256, 0, stream>>>(off, psrc, score, hs, h);
    }

    node_gemm1<<<N_NODES / 64, 256, 0, stream>>>(h, Wf, bf_, h2);
    sort_wave<<<N_NODES / 4, 256, 0, stream>>>(h2, hsort, maxval);
    topk_pool<<<BGR, 256, 0, stream>>>(maxval, hsort, pooled);
    ft_partial<<<dim3(BGR, 8), 256, 0, stream>>>(pooled, W3, part);
    ft_reduce<<<BGR, 128, 0, stream>>>(part, al3, ar3, ft, sl, sr);
    fg_kernel<<<BGR, 128, 0, stream>>>(fg_src, fg_dst, sl, sr, ft, b3, g);
    gl_kernel<<<BGR, 128, 0, stream>>>(g, Wl, bl, g2);
    out_kernel<<<1, 256, 0, stream>>>(g2, Wc, bc, out);
}

// Round 18
// 999.426 us; speedup vs baseline: 1.7209x; 1.0352x over previous
//
#include <hip/hip_runtime.h>

#define N_NODES 25600
#define N_EDGES 409600
#define BGR 128
#define EFE 1024
#define DIM 128
#define NLAYERS 8
#define KPOOL 32
#define NPG 200

typedef unsigned short ushort_t;
typedef unsigned char uchar_t;
typedef __attribute__((ext_vector_type(8))) short bf16x8;
typedef __attribute__((ext_vector_type(4))) float f32x4;

#define STG_S 136   // per-wave C-staging stride; 2-way LDS aliasing = free (R15 verified)
#define ESCALE 16.0f
#define WSCALE 4.0f
#define UNSCALE 0.015625f  // 1/64
#define HSCALE 16.0f
#define HUNSCALE 0.0625f   // 1/16

__device__ __forceinline__ float b2f(ushort_t v) {
    return __uint_as_float(((unsigned int)v) << 16);
}
__device__ __forceinline__ float blo(unsigned int u) {
    return __uint_as_float(u << 16);
}
__device__ __forceinline__ float bhi(unsigned int u) {
    return __uint_as_float(u & 0xffff0000u);
}
__device__ __forceinline__ ushort_t f2b(float f) {
    unsigned int u = __float_as_uint(f);
    unsigned int r = (u + 0x7fffu + ((u >> 16) & 1u)) >> 16;
    return (ushort_t)r;
}
__device__ __forceinline__ uint2 pack4(float4 v) {
    uint2 p;
    p.x = (unsigned int)f2b(v.x) | ((unsigned int)f2b(v.y) << 16);
    p.y = (unsigned int)f2b(v.z) | ((unsigned int)f2b(v.w) << 16);
    return p;
}
__device__ __forceinline__ unsigned int pk8(float v0, float v1, float v2, float v3) {
    int d = __builtin_amdgcn_cvt_pk_fp8_f32(v0, v1, 0, false);
    d = __builtin_amdgcn_cvt_pk_fp8_f32(v2, v3, d, true);
    return (unsigned int)d;
}
template <int SEL>
__device__ __forceinline__ float cvt8(int w) {
    return __builtin_amdgcn_cvt_f32_fp8(w, SEL);
}

// ---------------- W_fij -> fragment-linear fp8 (x4 scale) ----------------
__global__ void wfprep8(const float* __restrict__ W, uchar_t* __restrict__ Wf) {
    int idx = blockIdx.x * 256 + threadIdx.x;  // 8 * 16384
    int l = idx >> 14, rem = idx & 16383;
    int j = rem & 7, lane = (rem >> 3) & 63, nt = (rem >> 9) & 7, kc = rem >> 12;
    int q = lane >> 4, r = lane & 15;
    int k = kc * 32 + q * 8 + j, n = nt * 16 + r;
    float w = W[l * 16384 + k * 128 + n] * WSCALE;
    int d = __builtin_amdgcn_cvt_pk_fp8_f32(w, w, 0, false);
    Wf[idx] = (uchar_t)(d & 0xff);
}

// W_ni / W_nj / W_node -> fragment-linear fp8 (x4), layout [m][l][16384]
__global__ void wnprep8(const float* __restrict__ Wni, const float* __restrict__ Wnj,
                        const float* __restrict__ Wnode, uchar_t* __restrict__ Wn) {
    int idx = blockIdx.x * 256 + threadIdx.x;  // 3 * 8 * 16384
    int m = idx >> 17;
    int l = (idx >> 14) & 7;
    int rem = idx & 16383;
    int j = rem & 7, lane = (rem >> 3) & 63, nt = (rem >> 9) & 7, kc = rem >> 12;
    int q = lane >> 4, r = lane & 15;
    int k = kc * 32 + q * 8 + j, n = nt * 16 + r;
    const float* W = (m == 0) ? Wni : (m == 1) ? Wnj : Wnode;
    float w = W[l * 16384 + k * 128 + n] * WSCALE;
    int d = __builtin_amdgcn_cvt_pk_fp8_f32(w, w, 0, false);
    Wn[idx] = (uchar_t)(d & 0xff);
}

// ---------------- zero deg ----------------
__global__ void zero_deg(int* __restrict__ deg, int n) {
    int i = blockIdx.x * 256 + threadIdx.x;
    if (i < n) deg[i] = 0;
}

// ---------------- CSR build ----------------
__global__ void count_deg(const int* __restrict__ dst, int* __restrict__ deg, int n) {
    int i = blockIdx.x * 256 + threadIdx.x;
    if (i < n) atomicAdd(&deg[dst[i]], 1);
}

__global__ __launch_bounds__(1024) void scan_local(const int* __restrict__ deg,
                                                   int* __restrict__ off,
                                                   int* __restrict__ bsum, int n) {
    __shared__ int buf[1024];
    int b = blockIdx.x, t = threadIdx.x;
    int gi = b * 1024 + t;
    int v = (gi < n) ? deg[gi] : 0;
    buf[t] = v;
    __syncthreads();
    for (int s = 1; s < 1024; s <<= 1) {
        int x = (t >= s) ? buf[t - s] : 0;
        __syncthreads();
        buf[t] += x;
        __syncthreads();
    }
    if (gi < n) off[gi] = buf[t] - v;
    if (t == 1023) bsum[b] = buf[1023];
}

// scan_bsum merged: each thread sums its prefix of block sums (<=25)
__global__ void scan_add(int* __restrict__ off, const int* __restrict__ bsum,
                         int* __restrict__ cursor, int n, int total) {
    int i = blockIdx.x * 256 + threadIdx.x;
    if (i < n) {
        int nb = i >> 10;
        int base = 0;
        for (int b = 0; b < nb; b++) base += bsum[b];
        int v = off[i] + base;
        off[i] = v;
        cursor[i] = v;
    }
    if (i == 0) off[n] = total;
}

__global__ void scatter_perm(const int* __restrict__ src, const int* __restrict__ dst,
                             const int* __restrict__ tokens_e, int* __restrict__ cursor,
                             int* __restrict__ psrc, int* __restrict__ pdst,
                             int* __restrict__ ptok, int n) {
    int i = blockIdx.x * 256 + threadIdx.x;
    if (i < n) {
        int p = atomicAdd(&cursor[dst[i]], 1);
        psrc[p] = src[i];
        pdst[p] = dst[i];
        ptok[p] = tokens_e[i];
    }
}

// ---------------- init (h fp8 x16) ----------------
__global__ void init_h(const int* __restrict__ tok, const float* __restrict__ emb,
                       uchar_t* __restrict__ h) {
    int i = blockIdx.x * 256 + threadIdx.x;  // N*D/4 threads
    int r = i >> 5, c0 = (i & 31) * 4;
    const float4 v = *(const float4*)&emb[tok[r] * DIM + c0];
    *(unsigned int*)(h + (size_t)r * DIM + c0) =
        pk8(fmaxf(v.x, 0.f) * HSCALE, fmaxf(v.y, 0.f) * HSCALE,
            fmaxf(v.z, 0.f) * HSCALE, fmaxf(v.w, 0.f) * HSCALE);
}

__global__ __launch_bounds__(128) void eftab_kernel(const float* __restrict__ etab,
                                                    const float* __restrict__ W,
                                                    float* __restrict__ out) {
    int r = blockIdx.x, d = threadIdx.x;
    float acc = 0.f;
    for (int k = 0; k < DIM; k++)
        acc += etab[r * DIM + k] * W[k * DIM + d];
    out[r * DIM + d] = acc;
}

// ---------------- fp8 MFMA node GEMM: grid (400, 3); outputs fp8 x16 ----------------
__global__ __launch_bounds__(256, 4) void node_gemm_mfma(
    const uchar_t* __restrict__ h,
    const uchar_t* __restrict__ Wn,
    uchar_t* __restrict__ C0, uchar_t* __restrict__ C1, uchar_t* __restrict__ C2) {
    __shared__ __align__(16) char smem[4 * 16 * STG_S * 2];  // 17408 B; W uses first 16384
    int tid = threadIdx.x, wv = tid >> 6, lane = tid & 63;
    int r = lane & 15, q = lane >> 4;
    int el = lane >> 2, qq = lane & 3;
    int m = blockIdx.y;
    size_t row = (size_t)blockIdx.x * 64 + 16 * wv;

    const uchar_t* aRow = h + (row + r) * DIM + q * 8;
    long long a0 = *(const long long*)(aRow);
    long long a1 = *(const long long*)(aRow + 32);
    long long a2 = *(const long long*)(aRow + 64);
    long long a3 = *(const long long*)(aRow + 96);

    {
        const uint4* wg = (const uint4*)(Wn + (size_t)m * NLAYERS * 16384);
        uint4* ws = (uint4*)smem;
        for (int i = tid; i < 1024; i += 256) ws[i] = wg[i];
    }
    __syncthreads();

    f32x4 acc[8] = {};
    const long long* wfrag = (const long long*)smem;
#pragma unroll
    for (int nt = 0; nt < 8; nt++)
        acc[nt] = __builtin_amdgcn_mfma_f32_16x16x32_fp8_fp8(a0, wfrag[(0 * 8 + nt) * 64 + lane], acc[nt], 0, 0, 0);
#pragma unroll
    for (int nt = 0; nt < 8; nt++)
        acc[nt] = __builtin_amdgcn_mfma_f32_16x16x32_fp8_fp8(a1, wfrag[(1 * 8 + nt) * 64 + lane], acc[nt], 0, 0, 0);
#pragma unroll
    for (int nt = 0; nt < 8; nt++)
        acc[nt] = __builtin_amdgcn_mfma_f32_16x16x32_fp8_fp8(a2, wfrag[(2 * 8 + nt) * 64 + lane], acc[nt], 0, 0, 0);
#pragma unroll
    for (int nt = 0; nt < 8; nt++)
        acc[nt] = __builtin_amdgcn_mfma_f32_16x16x32_fp8_fp8(a3, wfrag[(3 * 8 + nt) * 64 + lane], acc[nt], 0, 0, 0);
    __syncthreads();

    // acc is x64 (h x16, W x4): stage bf16 at true scale
    ushort_t* ss = (ushort_t*)smem + wv * 16 * STG_S;
#pragma unroll
    for (int nt = 0; nt < 8; nt++)
#pragma unroll
        for (int rg = 0; rg < 4; rg++)
            ss[(q * 4 + rg) * STG_S + nt * 16 + r] = f2b(acc[nt][rg] * UNSCALE);

    const uint4* sp = (const uint4*)(ss + el * STG_S + qq * 32);
    uchar_t* Cp = (m == 0) ? C0 : (m == 1) ? C1 : C2;
    unsigned int ob[8];
#pragma unroll
    for (int cc = 0; cc < 4; cc++) {
        uint4 v = sp[cc];
        ob[cc * 2] = pk8(blo(v.x) * HSCALE, bhi(v.x) * HSCALE,
                         blo(v.y) * HSCALE, bhi(v.y) * HSCALE);
        ob[cc * 2 + 1] = pk8(blo(v.z) * HSCALE, bhi(v.z) * HSCALE,
                             blo(v.w) * HSCALE, bhi(v.w) * HSCALE);
    }
    uint4* cp = (uint4*)(Cp + (row + el) * DIM + qq * 32);
    cp[0] = make_uint4(ob[0], ob[1], ob[2], ob[3]);
    cp[1] = make_uint4(ob[4], ob[5], ob[6], ob[7]);
}

// single-W with bias + relu (final Wf): h fp8 in, fp32 out
__global__ __launch_bounds__(256) void node_gemm1(
    const uchar_t* __restrict__ A, const float* __restrict__ W,
    const float* __restrict__ bias, float* __restrict__ C) {
    __shared__ float As[64 * 128];
    __shared__ uint2 Ws4[128 * 32];
    int tid = threadIdx.x;
    size_t row0 = (size_t)blockIdx.x * 64;
    const unsigned int* Ag = (const unsigned int*)(A + row0 * DIM);
    for (int f = tid; f < 64 * 32; f += 256) {
        int v = (int)Ag[f];
        ((float4*)As)[f] = make_float4(cvt8<0>(v) * HUNSCALE, cvt8<1>(v) * HUNSCALE,
                                       cvt8<2>(v) * HUNSCALE, cvt8<3>(v) * HUNSCALE);
    }
    const float4* Wg = (const float4*)W;
    for (int i = tid; i < 128 * 32; i += 256) Ws4[i] = pack4(Wg[i]);
    __syncthreads();
    int cq = tid & 31, r0 = (tid >> 5) * 8, c0 = cq * 4;
    float acc[8][4] = {};
    for (int k = 0; k < 128; k++) {
        uint2 wp = Ws4[k * 32 + cq];
        float w0 = blo(wp.x), w1 = bhi(wp.x), w2 = blo(wp.y), w3 = bhi(wp.y);
#pragma unroll
        for (int i = 0; i < 8; i++) {
            float a = As[(r0 + i) * 128 + k];
            acc[i][0] += a * w0; acc[i][1] += a * w1;
            acc[i][2] += a * w2; acc[i][3] += a * w3;
        }
    }
    float b0 = bias[c0], b1 = bias[c0 + 1], b2v = bias[c0 + 2], b3v = bias[c0 + 3];
#pragma unroll
    for (int i = 0; i < 8; i++) {
        *(float4*)&C[(row0 + r0 + i) * DIM + c0] =
            make_float4(fmaxf(acc[i][0] + b0, 0.f), fmaxf(acc[i][1] + b1, 0.f),
                        fmaxf(acc[i][2] + b2v, 0.f), fmaxf(acc[i][3] + b3v, 0.f));
    }
}

// ---------------- fp8 MFMA edge GEMM (layers 1..7); stores exp(score) ----------------
__global__ __launch_bounds__(256, 4) void edge_gemm_fp8(
    uchar_t* __restrict__ e,
    const uchar_t* __restrict__ fni, const uchar_t* __restrict__ fnj,
    const int* __restrict__ psrc, const int* __restrict__ pdst,
    const uchar_t* __restrict__ Wf,
    const float* __restrict__ attn, const float* __restrict__ bias,
    float* __restrict__ escore) {
    __shared__ __align__(16) char smem[4 * 16 * STG_S * 2];  // 17408 B; W uses first 16384

    int tid = threadIdx.x;
    int wv = tid >> 6, lane = tid & 63;
    int r = lane & 15, q = lane >> 4;
    int el = lane >> 2, qq = lane & 3;
    size_t row = (size_t)blockIdx.x * 64 + 16 * wv;
    size_t eid = row + el;

    int sv = psrc[eid], dv = pdst[eid];

    const uchar_t* aRow = e + (row + r) * DIM + q * 8;
    long long a0 = *(const long long*)(aRow);
    long long a1 = *(const long long*)(aRow + 32);
    long long a2 = *(const long long*)(aRow + 64);
    long long a3 = *(const long long*)(aRow + 96);

    {
        const uint4* wg = (const uint4*)Wf;
        uint4* ws = (uint4*)smem;
        for (int i = tid; i < 1024; i += 256) ws[i] = wg[i];
    }
    __syncthreads();

    f32x4 acc[8] = {};
    const long long* wfrag = (const long long*)smem;
#pragma unroll
    for (int nt = 0; nt < 8; nt++)
        acc[nt] = __builtin_amdgcn_mfma_f32_16x16x32_fp8_fp8(a0, wfrag[(0 * 8 + nt) * 64 + lane], acc[nt], 0, 0, 0);
#pragma unroll
    for (int nt = 0; nt < 8; nt++)
        acc[nt] = __builtin_amdgcn_mfma_f32_16x16x32_fp8_fp8(a1, wfrag[(1 * 8 + nt) * 64 + lane], acc[nt], 0, 0, 0);
#pragma unroll
    for (int nt = 0; nt < 8; nt++)
        acc[nt] = __builtin_amdgcn_mfma_f32_16x16x32_fp8_fp8(a2, wfrag[(2 * 8 + nt) * 64 + lane], acc[nt], 0, 0, 0);
#pragma unroll
    for (int nt = 0; nt < 8; nt++)
        acc[nt] = __builtin_amdgcn_mfma_f32_16x16x32_fp8_fp8(a3, wfrag[(3 * 8 + nt) * 64 + lane], acc[nt], 0, 0, 0);
    __syncthreads();  // W reads done -> staging overlay

    ushort_t* ss = (ushort_t*)smem + wv * 16 * STG_S;
#pragma unroll
    for (int nt = 0; nt < 8; nt++)
#pragma unroll
        for (int rg = 0; rg < 4; rg++)
            ss[(q * 4 + rg) * STG_S + nt * 16 + r] = f2b(acc[nt][rg] * UNSCALE);

    unsigned int niw[8], njw[8];
    {
        const uint4* nip = (const uint4*)(fni + (size_t)sv * DIM + qq * 32);
        const uint4* njp = (const uint4*)(fnj + (size_t)dv * DIM + qq * 32);
        *(uint4*)&niw[0] = nip[0]; *(uint4*)&niw[4] = nip[1];
        *(uint4*)&njw[0] = njp[0]; *(uint4*)&njw[4] = njp[1];
    }
    const uint4* sp = (const uint4*)(ss + el * STG_S + qq * 32);
    unsigned int outb[8];
    float p = 0.f;
#pragma unroll
    for (int cc = 0; cc < 4; cc++) {
        uint4 avq = sp[cc];
        int wlo_i = (int)niw[cc * 2], whi_i = (int)niw[cc * 2 + 1];
        int wlo_j = (int)njw[cc * 2], whi_j = (int)njw[cc * 2 + 1];
        float niv[8], njv[8];
        niv[0] = cvt8<0>(wlo_i); niv[1] = cvt8<1>(wlo_i);
        niv[2] = cvt8<2>(wlo_i); niv[3] = cvt8<3>(wlo_i);
        niv[4] = cvt8<0>(whi_i); niv[5] = cvt8<1>(whi_i);
        niv[6] = cvt8<2>(whi_i); niv[7] = cvt8<3>(whi_i);
        njv[0] = cvt8<0>(wlo_j); njv[1] = cvt8<1>(wlo_j);
        njv[2] = cvt8<2>(wlo_j); njv[3] = cvt8<3>(wlo_j);
        njv[4] = cvt8<0>(whi_j); njv[5] = cvt8<1>(whi_j);
        njv[6] = cvt8<2>(whi_j); njv[7] = cvt8<3>(whi_j);
        float vv[8];
#pragma unroll
        for (int u = 0; u < 4; u++) {
            unsigned int aw = ((const unsigned int*)&avq)[u];
            int c = qq * 32 + cc * 8 + u * 2;
            float v0 = blo(aw) + (niv[u * 2] + njv[u * 2]) * HUNSCALE + bias[c];
            float v1 = bhi(aw) + (niv[u * 2 + 1] + njv[u * 2 + 1]) * HUNSCALE + bias[c + 1];
            v0 = v0 > 0.f ? v0 : 0.01f * v0;
            v1 = v1 > 0.f ? v1 : 0.01f * v1;
            vv[u * 2] = v0; vv[u * 2 + 1] = v1;
            p += v0 * attn[c] + v1 * attn[c + 1];
        }
        outb[cc * 2] = pk8(vv[0] * ESCALE, vv[1] * ESCALE, vv[2] * ESCALE, vv[3] * ESCALE);
        outb[cc * 2 + 1] = pk8(vv[4] * ESCALE, vv[5] * ESCALE, vv[6] * ESCALE, vv[7] * ESCALE);
    }
    uint4* ep = (uint4*)(e + eid * DIM + qq * 32);
    ep[0] = make_uint4(outb[0], outb[1], outb[2], outb[3]);
    ep[1] = make_uint4(outb[4], outb[5], outb[6], outb[7]);
    p += __shfl_xor(p, 1);
    p += __shfl_xor(p, 2);
    if (qq == 0) escore[eid] = __expf(p);
}

// ---------------- layer-0 edge kernel (stores exp(score)) ----------------
__global__ __launch_bounds__(256) void edge0(
    const int* __restrict__ ptok, const float* __restrict__ eftab,
    const uchar_t* __restrict__ fni, const uchar_t* __restrict__ fnj,
    const int* __restrict__ psrc, const int* __restrict__ pdst,
    const float* __restrict__ attn, const float* __restrict__ bias,
    uchar_t* __restrict__ e, float* __restrict__ escore) {
    unsigned int gid = blockIdx.x * 256 + threadIdx.x;
    unsigned int eid = gid >> 5;
    int cq = gid & 31, c0 = cq * 4;
    int tok = ptok[eid];
    int sv = psrc[eid], dv = pdst[eid];
    float4 t = *(const float4*)&eftab[tok * DIM + c0];
    int niw = *(const int*)(fni + (size_t)sv * DIM + c0);
    int njw = *(const int*)(fnj + (size_t)dv * DIM + c0);
    float v0 = t.x + (cvt8<0>(niw) + cvt8<0>(njw)) * HUNSCALE + bias[c0];
    float v1 = t.y + (cvt8<1>(niw) + cvt8<1>(njw)) * HUNSCALE + bias[c0 + 1];
    float v2 = t.z + (cvt8<2>(niw) + cvt8<2>(njw)) * HUNSCALE + bias[c0 + 2];
    float v3 = t.w + (cvt8<3>(niw) + cvt8<3>(njw)) * HUNSCALE + bias[c0 + 3];
    v0 = v0 > 0.f ? v0 : 0.01f * v0;
    v1 = v1 > 0.f ? v1 : 0.01f * v1;
    v2 = v2 > 0.f ? v2 : 0.01f * v2;
    v3 = v3 > 0.f ? v3 : 0.01f * v3;
    *(unsigned int*)(e + (size_t)eid * DIM + c0) =
        pk8(v0 * ESCALE, v1 * ESCALE, v2 * ESCALE, v3 * ESCALE);
    float p = v0 * attn[c0] + v1 * attn[c0 + 1] + v2 * attn[c0 + 2] + v3 * attn[c0 + 3];
#pragma unroll
    for (int o = 1; o < 32; o <<= 1) p += __shfl_xor(p, o);
    if (cq == 0) escore[eid] = __expf(p);
}

// ---------------- wave-per-node aggregation (escore pre-exponentiated, fp8 hs/h) ----------------
__global__ __launch_bounds__(256) void agg_wave(
    const int* __restrict__ off, const int* __restrict__ psrc,
    const float* __restrict__ escore, const uchar_t* __restrict__ hs,
    uchar_t* __restrict__ h) {
    int node = blockIdx.x * 4 + (threadIdx.x >> 6);
    int lane = threadIdx.x & 63;
    int b0 = off[node];
    int deg = off[node + 1] - b0;

    float se = 0.f;
    for (int j = lane; j < deg; j += 64) se += escore[b0 + j];
#pragma unroll
    for (int o = 32; o > 0; o >>= 1) se += __shfl_xor(se, o);
    float inv = (deg > 0) ? 1.f / se : 0.f;

    float acc0 = 0.f, acc1 = 0.f;
    for (int base = 0; base < deg; base += 64) {
        int cnt = min(64, deg - base);
        float wgt = 0.f;
        int sidx = 0;
        if (lane < cnt) {
            wgt = escore[b0 + base + lane] * inv;
            sidx = psrc[b0 + base + lane];
        }
        int i = 0;
        for (; i + 4 <= cnt; i += 4) {
            float w0 = __shfl(wgt, i), w1 = __shfl(wgt, i + 1);
            float w2 = __shfl(wgt, i + 2), w3 = __shfl(wgt, i + 3);
            int s0 = __shfl(sidx, i), s1 = __shfl(sidx, i + 1);
            int s2 = __shfl(sidx, i + 2), s3 = __shfl(sidx, i + 3);
            int h0 = *(const ushort_t*)(hs + (size_t)s0 * DIM + lane * 2);
            int h1 = *(const ushort_t*)(hs + (size_t)s1 * DIM + lane * 2);
            int h2 = *(const ushort_t*)(hs + (size_t)s2 * DIM + lane * 2);
            int h3 = *(const ushort_t*)(hs + (size_t)s3 * DIM + lane * 2);
            acc0 += w0 * cvt8<0>(h0);
            acc1 += w0 * cvt8<1>(h0);
            acc0 += w1 * cvt8<0>(h1);
            acc1 += w1 * cvt8<1>(h1);
            acc0 += w2 * cvt8<0>(h2);
            acc1 += w2 * cvt8<1>(h2);
            acc0 += w3 * cvt8<0>(h3);
            acc1 += w3 * cvt8<1>(h3);
        }
        for (; i < cnt; i++) {
            float wi = __shfl(wgt, i);
            int si = __shfl(sidx, i);
            int hv = *(const ushort_t*)(hs + (size_t)si * DIM + lane * 2);
            acc0 += wi * cvt8<0>(hv);
            acc1 += wi * cvt8<1>(hv);
        }
    }
    // acc is in hs-scale (x16): relu then re-store as fp8 x16 directly
    int op = __builtin_amdgcn_cvt_pk_fp8_f32(fmaxf(acc0, 0.f), fmaxf(acc1, 0.f), 0, false);
    *(ushort_t*)(h + (size_t)node * DIM + lane * 2) = (ushort_t)(op & 0xffff);
}

// ---------------- wave bitonic sort of 128 features (no barriers) ----------------
__global__ __launch_bounds__(256) void sort_wave(const float* __restrict__ h2,
                                                 float* __restrict__ hsort,
                                                 float* __restrict__ maxval) {
    int node = blockIdx.x * 4 + (threadIdx.x >> 6);
    int lane = threadIdx.x & 63;
    float x0 = h2[(size_t)node * DIM + lane];
    float x1 = h2[(size_t)node * DIM + 64 + lane];
    for (int k = 2; k <= 128; k <<= 1) {
        for (int s = k >> 1; s >= 1; s >>= 1) {
            bool d0 = ((lane & k) == 0);
            bool d1 = (((lane + 64) & k) == 0);
            if (s == 64) {
                float mn = fminf(x0, x1), mx = fmaxf(x0, x1);
                x0 = d0 ? mn : mx;
                x1 = d0 ? mx : mn;
            } else {
                bool low = ((lane & s) == 0);
                float y0 = __shfl_xor(x0, s);
                float y1 = __shfl_xor(x1, s);
                float mn0 = fminf(x0, y0), mx0 = fmaxf(x0, y0);
                float mn1 = fminf(x1, y1), mx1 = fmaxf(x1, y1);
                x0 = (low == d0) ? mn0 : mx0;
                x1 = (low == d1) ? mn1 : mx1;
            }
        }
    }
    hsort[(size_t)node * DIM + lane] = x0;
    hsort[(size_t)node * DIM + 64 + lane] = x1;
    if (lane == 63) maxval[node] = x1;
}

// ---------------- per-graph top-k + gather pooled rows ----------------
__global__ __launch_bounds__(256) void topk_pool(const float* __restrict__ maxval,
                                                 const float* __restrict__ hsort,
                                                 float* __restrict__ pooled) {
    __shared__ float v[256];
    __shared__ int id[256];
    int b = blockIdx.x, t = threadIdx.x;
    v[t] = (t < NPG) ? maxval[b * NPG + t] : -1e30f;
    id[t] = t;
    __syncthreads();
    for (int k = 2; k <= 256; k <<= 1) {
        for (int j = k >> 1; j > 0; j >>= 1) {
            int ixj = t ^ j;
            float va = v[t], vb = v[ixj];
            int ia = id[t], ib = id[ixj];
            __syncthreads();
            bool dirDesc = ((t & k) == 0);
            bool cmp = (va > vb) || (va == vb && ia < ib);
            bool takeMine = ((t < ixj) == (dirDesc == cmp));
            v[t] = takeMine ? va : vb;
            id[t] = takeMine ? ia : ib;
            __syncthreads();
        }
    }
    for (int i = t; i < KPOOL * DIM; i += 256) {
        int kk = i >> 7, d = i & 127;
        pooled[((size_t)b * KPOOL + kk) * DIM + d] = hsort[((size_t)b * NPG + id[kk]) * DIM + d];
    }
}

// ---------------- ft split-K ----------------
__global__ __launch_bounds__(256) void ft_partial(
    const float* __restrict__ pooled, const float* __restrict__ W3,
    float* __restrict__ part) {
    __shared__ float ps[512];
    __shared__ float red[256];
    int b = blockIdx.x, s = blockIdx.y;
    int t = threadIdx.x;
    int d = t & 127, half = t >> 7;
    for (int i = t; i < 512; i += 256) ps[i] = pooled[(size_t)b * 4096 + s * 512 + i];
    __syncthreads();
    float acc = 0.f;
    const float* Wp = W3 + (size_t)(s * 512 + half * 256) * DIM + d;
    const float* pp = ps + half * 256;
#pragma unroll 4
    for (int kk = 0; kk < 256; kk++) acc += pp[kk] * Wp[(size_t)kk * DIM];
    red[t] = acc;
    __syncthreads();
    if (t < 128) part[((size_t)b * 8 + s) * DIM + t] = red[t] + red[t + 128];
}

__global__ __launch_bounds__(128) void ft_reduce(
    const float* __restrict__ part, const float* __restrict__ al3,
    const float* __restrict__ ar3, float* __restrict__ ft,
    float* __restrict__ sl, float* __restrict__ sr) {
    __shared__ float r1[128], r2[128];
    int b = blockIdx.x, d = threadIdx.x;
    float acc = 0.f;
#pragma unroll
    for (int s = 0; s < 8; s++) acc += part[((size_t)b * 8 + s) * DIM + d];
    ft[b * DIM + d] = acc;
    r1[d] = acc * al3[d];
    r2[d] = acc * ar3[d];
    __syncthreads();
    for (int s = 64; s > 0; s >>= 1) {
        if (d < s) { r1[d] += r1[d + s]; r2[d] += r2[d + s]; }
        __syncthreads();
    }
    if (d == 0) { sl[b] = r1[0]; sr[b] = r2[0]; }
}

// ---------------- final-graph GAT ----------------
__global__ __launch_bounds__(128) void fg_kernel(
    const int* __restrict__ fg_src, const int* __restrict__ fg_dst,
    const float* __restrict__ sl, const float* __restrict__ sr,
    const float* __restrict__ ft, const float* __restrict__ b3,
    float* __restrict__ g) {
    __shared__ int list[EFE];
    __shared__ float wgt[EFE];
    __shared__ float red[128];
    __shared__ int cnt;
    int b = blockIdx.x, t = threadIdx.x;
    if (t == 0) cnt = 0;
    __syncthreads();
    for (int e = t; e < EFE; e += 128)
        if (fg_dst[e] == b) { int p = atomicAdd(&cnt, 1); list[p] = e; }
    __syncthreads();
    int deg = cnt;
    float srb = sr[b];
    float m = -1e30f;
    for (int j = t; j < deg; j += 128) {
        float s = sl[fg_src[list[j]]] + srb;
        s = s > 0.f ? s : 0.2f * s;
        m = fmaxf(m, s);
    }
    red[t] = m;
    __syncthreads();
    for (int s = 64; s > 0; s >>= 1) { if (t < s) red[t] = fmaxf(red[t], red[t + s]); __syncthreads(); }
    m = red[0];
    __syncthreads();
    float se = 0.f;
    for (int j = t; j < deg; j += 128) {
        float s = sl[fg_src[list[j]]] + srb;
        s = s > 0.f ? s : 0.2f * s;
        se += __expf(s - m);
    }
    red[t] = se;
    __syncthreads();
    for (int s = 64; s > 0; s >>= 1) { if (t < s) red[t] += red[t + s]; __syncthreads(); }
    float inv = (deg > 0) ? 1.f / red[0] : 0.f;
    __syncthreads();
    for (int j = t; j < deg; j += 128) {
        float s = sl[fg_src[list[j]]] + srb;
        s = s > 0.f ? s : 0.2f * s;
        wgt[j] = __expf(s - m) * inv;
    }
    __syncthreads();
    float acc = 0.f;
    for (int j = 0; j < deg; j++) acc += wgt[j] * ft[(size_t)fg_src[list[j]] * DIM + t];
    g[b * DIM + t] = fmaxf(acc + b3[t], 0.f);
}

// ---------------- g2 = relu(g @ Wl + bl) ----------------
__global__ __launch_bounds__(128) void gl_kernel(const float* __restrict__ g,
                                                 const float* __restrict__ Wl,
                                                 const float* __restrict__ bl,
                                                 float* __restrict__ g2) {
    __shared__ float gs[128];
    int b = blockIdx.x, d = threadIdx.x;
    gs[d] = g[b * DIM + d];
    __syncthreads();
    float acc = 0.f;
    for (int k = 0; k < 128; k++) acc += gs[k] * Wl[k * DIM + d];
    g2[b * DIM + d] = fmaxf(acc + bl[d], 0.f);
}

// ---------------- out = g2 @ Wc + bc ----------------
__global__ __launch_bounds__(256) void out_kernel(const float* __restrict__ g2,
                                                  const float* __restrict__ Wc,
                                                  const float* __restrict__ bc,
                                                  float* __restrict__ out) {
    int i = threadIdx.x;
    int b = i >> 1, j = i & 1;
    float acc = bc[j];
    for (int k = 0; k < 128; k++) acc += g2[b * DIM + k] * Wc[k * 2 + j];
    out[b * 2 + j] = acc;
}

extern "C" void kernel_launch(void* const* d_in, const int* in_sizes, int n_in,
                              void* d_out, int out_size, void* d_ws, size_t ws_size,
                              hipStream_t stream) {
    const int* tokens_h = (const int*)d_in[0];
    const int* tokens_e = (const int*)d_in[1];
    const int* src = (const int*)d_in[2];
    const int* dst = (const int*)d_in[3];
    const int* fg_src = (const int*)d_in[4];
    const int* fg_dst = (const int*)d_in[5];
    const float* token_emb = (const float*)d_in[6];
    const float* e_token_emb = (const float*)d_in[7];
    const float* W_ni = (const float*)d_in[8];
    const float* W_nj = (const float*)d_in[9];
    const float* W_fij = (const float*)d_in[10];
    const float* W_node = (const float*)d_in[11];
    const float* attn_e = (const float*)d_in[12];
    const float* bias_e = (const float*)d_in[13];
    const float* Wf = (const float*)d_in[14];
    const float* bf_ = (const float*)d_in[15];
    const float* W3 = (const float*)d_in[16];
    const float* al3 = (const float*)d_in[17];
    const float* ar3 = (const float*)d_in[18];
    const float* b3 = (const float*)d_in[19];
    const float* Wl = (const float*)d_in[20];
    const float* bl = (const float*)d_in[21];
    const float* Wc = (const float*)d_in[22];
    const float* bc = (const float*)d_in[23];
    float* out = (float*)d_out;

    char* w = (char*)d_ws;
    auto alloc = [&](size_t b) -> char* {
        char* p = w;
        w += (b + 255) & ~(size_t)255;
        return p;
    };
    uchar_t* h = (uchar_t*)alloc((size_t)N_NODES * DIM);       // fp8 x16
    uchar_t* fni = (uchar_t*)alloc((size_t)N_NODES * DIM);     // fp8
    uchar_t* fnj = (uchar_t*)alloc((size_t)N_NODES * DIM);     // fp8
    uchar_t* hs = (uchar_t*)alloc((size_t)N_NODES * DIM);      // fp8
    uchar_t* e = (uchar_t*)alloc((size_t)N_EDGES * DIM);       // fp8
    float* escore = (float*)alloc((size_t)N_EDGES * 4);
    int* deg = (int*)alloc((size_t)N_NODES * 4);
    int* off = (int*)alloc((size_t)(N_NODES + 1) * 4);
    int* cursor = (int*)alloc((size_t)N_NODES * 4);
    int* bsum = (int*)alloc(64 * 4);
    int* psrc = (int*)alloc((size_t)N_EDGES * 4);
    int* pdst = (int*)alloc((size_t)N_EDGES * 4);
    int* ptok = (int*)alloc((size_t)N_EDGES * 4);
    float* eftab = (float*)alloc(100 * DIM * 4);
    float* maxval = (float*)alloc((size_t)N_NODES * 4);
    float* pooled = (float*)alloc((size_t)BGR * KPOOL * DIM * 4);
    float* ft = (float*)alloc(BGR * DIM * 4);
    float* part = (float*)alloc((size_t)BGR * 8 * DIM * 4);
    float* sl = (float*)alloc(BGR * 4);
    float* sr = (float*)alloc(BGR * 4);
    float* g = (float*)alloc(BGR * DIM * 4);
    float* g2 = (float*)alloc(BGR * DIM * 4);
    uchar_t* Wf7 = (uchar_t*)alloc((size_t)NLAYERS * DIM * DIM);
    uchar_t* Wn = (uchar_t*)alloc((size_t)3 * NLAYERS * DIM * DIM);
    // h2/hsort (fp32, 13.1 MB each) live in the e region (52 MB) after the layer loop
    float* h2 = (float*)e;
    float* hsort = (float*)((char*)e + (size_t)16 * 1024 * 1024);

    // weight prep
    wfprep8<<<(NLAYERS * DIM * DIM) / 256, 256, 0, stream>>>(W_fij, Wf7);
    wnprep8<<<(3 * NLAYERS * DIM * DIM) / 256, 256, 0, stream>>>(W_ni, W_nj, W_node, Wn);

    // CSR build + edge permutation (dst-sorted order), hierarchical scan
    zero_deg<<<(N_NODES + 255) / 256, 256, 0, stream>>>(deg, N_NODES);
    count_deg<<<N_EDGES / 256, 256, 0, stream>>>(dst, deg, N_EDGES);
    scan_local<<<(N_NODES + 1023) / 1024, 1024, 0, stream>>>(deg, off, bsum, N_NODES);
    scan_add<<<(N_NODES + 255) / 256, 256, 0, stream>>>(off, bsum, cursor, N_NODES, N_EDGES);
    scatter_perm<<<N_EDGES / 256, 256, 0, stream>>>(src, dst, tokens_e, cursor,
                                                    psrc, pdst, ptok, N_EDGES);

    init_h<<<(N_NODES * DIM / 4) / 256, 256, 0, stream>>>(tokens_h, token_emb, h);
    eftab_kernel<<<100, 128, 0, stream>>>(e_token_emb, W_fij, eftab);

    for (int l = 0; l < NLAYERS; l++) {
        node_gemm_mfma<<<dim3(N_NODES / 64, 3), 256, 0, stream>>>(
            h, Wn + l * 16384, fni, fnj, hs);
        if (l == 0) {
            edge0<<<(N_EDGES * 32) / 256, 256, 0, stream>>>(
                ptok, eftab, fni, fnj, psrc, pdst, attn_e, bias_e, e, escore);
        } else {
            edge_gemm_fp8<<<N_EDGES / 64, 256, 0, stream>>>(
                e, fni, fnj, psrc, pdst, Wf7 + (size_t)l * DIM * DIM,
                attn_e + l * DIM, bias_e + l * DIM, escore);
        }
        agg_wave<<<N_NODES / 4, 256, 0, stream>>>(off, psrc, escore, hs, h);
    }

    node_gemm1<<<N_NODES / 64, 256, 0, stream>>>(h, Wf, bf_, h2);
    sort_wave<<<N_NODES / 4, 256, 0, stream>>>(h2, hsort, maxval);
    topk_pool<<<BGR, 256, 0, stream>>>(maxval, hsort, pooled);
    ft_partial<<<dim3(BGR, 8), 256, 0, stream>>>(pooled, W3, part);
    ft_reduce<<<BGR, 128, 0, stream>>>(part, al3, ar3, ft, sl, sr);
    fg_kernel<<<BGR, 128, 0, stream>>>(fg_src, fg_dst, sl, sr, ft, b3, g);
    gl_kernel<<<BGR, 128, 0, stream>>>(g, Wl, bl, g2);
    out_kernel<<<1, 256, 0, stream>>>(g2, Wc, bc, out);
}

// Round 19
// 990.751 us; speedup vs baseline: 1.7359x; 1.0088x over previous
//
#include <hip/hip_runtime.h>

#define N_NODES 25600
#define N_EDGES 409600
#define BGR 128
#define EFE 1024
#define DIM 128
#define NLAYERS 8
#define KPOOL 32
#define NPG 200

typedef unsigned short ushort_t;
typedef unsigned char uchar_t;
typedef __attribute__((ext_vector_type(8))) short bf16x8;
typedef __attribute__((ext_vector_type(4))) float f32x4;

#define STG_S 136   // per-wave C-staging stride; 2-way LDS aliasing = free (R15 verified)
#define ESCALE 16.0f
#define WSCALE 4.0f
#define UNSCALE 0.015625f  // 1/64
#define HSCALE 16.0f
#define HUNSCALE 0.0625f   // 1/16

__device__ __forceinline__ float b2f(ushort_t v) {
    return __uint_as_float(((unsigned int)v) << 16);
}
__device__ __forceinline__ float blo(unsigned int u) {
    return __uint_as_float(u << 16);
}
__device__ __forceinline__ float bhi(unsigned int u) {
    return __uint_as_float(u & 0xffff0000u);
}
__device__ __forceinline__ ushort_t f2b(float f) {
    unsigned int u = __float_as_uint(f);
    unsigned int r = (u + 0x7fffu + ((u >> 16) & 1u)) >> 16;
    return (ushort_t)r;
}
__device__ __forceinline__ uint2 pack4(float4 v) {
    uint2 p;
    p.x = (unsigned int)f2b(v.x) | ((unsigned int)f2b(v.y) << 16);
    p.y = (unsigned int)f2b(v.z) | ((unsigned int)f2b(v.w) << 16);
    return p;
}
__device__ __forceinline__ unsigned int pk8(float v0, float v1, float v2, float v3) {
    int d = __builtin_amdgcn_cvt_pk_fp8_f32(v0, v1, 0, false);
    d = __builtin_amdgcn_cvt_pk_fp8_f32(v2, v3, d, true);
    return (unsigned int)d;
}
template <int SEL>
__device__ __forceinline__ float cvt8(int w) {
    return __builtin_amdgcn_cvt_f32_fp8(w, SEL);
}

// ---------------- W_fij -> fragment-linear fp8 (x4 scale) ----------------
__global__ void wfprep8(const float* __restrict__ W, uchar_t* __restrict__ Wf) {
    int idx = blockIdx.x * 256 + threadIdx.x;  // 8 * 16384
    int l = idx >> 14, rem = idx & 16383;
    int j = rem & 7, lane = (rem >> 3) & 63, nt = (rem >> 9) & 7, kc = rem >> 12;
    int q = lane >> 4, r = lane & 15;
    int k = kc * 32 + q * 8 + j, n = nt * 16 + r;
    float w = W[l * 16384 + k * 128 + n] * WSCALE;
    int d = __builtin_amdgcn_cvt_pk_fp8_f32(w, w, 0, false);
    Wf[idx] = (uchar_t)(d & 0xff);
}

// W_ni / W_nj / W_node -> fragment-linear fp8 (x4), layout [m][l][16384]
__global__ void wnprep8(const float* __restrict__ Wni, const float* __restrict__ Wnj,
                        const float* __restrict__ Wnode, uchar_t* __restrict__ Wn) {
    int idx = blockIdx.x * 256 + threadIdx.x;  // 3 * 8 * 16384
    int m = idx >> 17;
    int l = (idx >> 14) & 7;
    int rem = idx & 16383;
    int j = rem & 7, lane = (rem >> 3) & 63, nt = (rem >> 9) & 7, kc = rem >> 12;
    int q = lane >> 4, r = lane & 15;
    int k = kc * 32 + q * 8 + j, n = nt * 16 + r;
    const float* W = (m == 0) ? Wni : (m == 1) ? Wnj : Wnode;
    float w = W[l * 16384 + k * 128 + n] * WSCALE;
    int d = __builtin_amdgcn_cvt_pk_fp8_f32(w, w, 0, false);
    Wn[idx] = (uchar_t)(d & 0xff);
}

// ---------------- zero deg ----------------
__global__ void zero_deg(int* __restrict__ deg, int n) {
    int i = blockIdx.x * 256 + threadIdx.x;
    if (i < n) deg[i] = 0;
}

// ---------------- CSR build ----------------
__global__ void count_deg(const int* __restrict__ dst, int* __restrict__ deg, int n) {
    int i = blockIdx.x * 256 + threadIdx.x;
    if (i < n) atomicAdd(&deg[dst[i]], 1);
}

__global__ __launch_bounds__(1024) void scan_local(const int* __restrict__ deg,
                                                   int* __restrict__ off,
                                                   int* __restrict__ bsum, int n) {
    __shared__ int buf[1024];
    int b = blockIdx.x, t = threadIdx.x;
    int gi = b * 1024 + t;
    int v = (gi < n) ? deg[gi] : 0;
    buf[t] = v;
    __syncthreads();
    for (int s = 1; s < 1024; s <<= 1) {
        int x = (t >= s) ? buf[t - s] : 0;
        __syncthreads();
        buf[t] += x;
        __syncthreads();
    }
    if (gi < n) off[gi] = buf[t] - v;
    if (t == 1023) bsum[b] = buf[1023];
}

__global__ void scan_add(int* __restrict__ off, const int* __restrict__ bsum,
                         int* __restrict__ cursor, int n, int total) {
    int i = blockIdx.x * 256 + threadIdx.x;
    if (i < n) {
        int nb = i >> 10;
        int base = 0;
        for (int b = 0; b < nb; b++) base += bsum[b];
        int v = off[i] + base;
        off[i] = v;
        cursor[i] = v;
    }
    if (i == 0) off[n] = total;
}

__global__ void scatter_perm(const int* __restrict__ src, const int* __restrict__ dst,
                             const int* __restrict__ tokens_e, int* __restrict__ cursor,
                             int* __restrict__ psrc, int* __restrict__ pdst,
                             int* __restrict__ ptok, int n) {
    int i = blockIdx.x * 256 + threadIdx.x;
    if (i < n) {
        int p = atomicAdd(&cursor[dst[i]], 1);
        psrc[p] = src[i];
        pdst[p] = dst[i];
        ptok[p] = tokens_e[i];
    }
}

// ---------------- init (h fp8 x16) ----------------
__global__ void init_h(const int* __restrict__ tok, const float* __restrict__ emb,
                       uchar_t* __restrict__ h) {
    int i = blockIdx.x * 256 + threadIdx.x;  // N*D/4 threads
    int r = i >> 5, c0 = (i & 31) * 4;
    const float4 v = *(const float4*)&emb[tok[r] * DIM + c0];
    *(unsigned int*)(h + (size_t)r * DIM + c0) =
        pk8(fmaxf(v.x, 0.f) * HSCALE, fmaxf(v.y, 0.f) * HSCALE,
            fmaxf(v.z, 0.f) * HSCALE, fmaxf(v.w, 0.f) * HSCALE);
}

__global__ __launch_bounds__(128) void eftab_kernel(const float* __restrict__ etab,
                                                    const float* __restrict__ W,
                                                    float* __restrict__ out) {
    int r = blockIdx.x, d = threadIdx.x;
    float acc = 0.f;
    for (int k = 0; k < DIM; k++)
        acc += etab[r * DIM + k] * W[k * DIM + d];
    out[r * DIM + d] = acc;
}

// ---------------- fp8 MFMA node GEMM: grid (400, 3); outputs fp8 x16 ----------------
__global__ __launch_bounds__(256, 4) void node_gemm_mfma(
    const uchar_t* __restrict__ h,
    const uchar_t* __restrict__ Wn,
    uchar_t* __restrict__ C0, uchar_t* __restrict__ C1, uchar_t* __restrict__ C2) {
    __shared__ __align__(16) char smem[4 * 16 * STG_S * 2];  // 17408 B; W uses first 16384
    int tid = threadIdx.x, wv = tid >> 6, lane = tid & 63;
    int r = lane & 15, q = lane >> 4;
    int el = lane >> 2, qq = lane & 3;
    int m = blockIdx.y;
    size_t row = (size_t)blockIdx.x * 64 + 16 * wv;

    const uchar_t* aRow = h + (row + r) * DIM + q * 8;
    long long a0 = *(const long long*)(aRow);
    long long a1 = *(const long long*)(aRow + 32);
    long long a2 = *(const long long*)(aRow + 64);
    long long a3 = *(const long long*)(aRow + 96);

    {
        const uint4* wg = (const uint4*)(Wn + (size_t)m * NLAYERS * 16384);
        uint4* ws = (uint4*)smem;
        for (int i = tid; i < 1024; i += 256) ws[i] = wg[i];
    }
    __syncthreads();

    f32x4 acc[8] = {};
    const long long* wfrag = (const long long*)smem;
#pragma unroll
    for (int nt = 0; nt < 8; nt++)
        acc[nt] = __builtin_amdgcn_mfma_f32_16x16x32_fp8_fp8(a0, wfrag[(0 * 8 + nt) * 64 + lane], acc[nt], 0, 0, 0);
#pragma unroll
    for (int nt = 0; nt < 8; nt++)
        acc[nt] = __builtin_amdgcn_mfma_f32_16x16x32_fp8_fp8(a1, wfrag[(1 * 8 + nt) * 64 + lane], acc[nt], 0, 0, 0);
#pragma unroll
    for (int nt = 0; nt < 8; nt++)
        acc[nt] = __builtin_amdgcn_mfma_f32_16x16x32_fp8_fp8(a2, wfrag[(2 * 8 + nt) * 64 + lane], acc[nt], 0, 0, 0);
#pragma unroll
    for (int nt = 0; nt < 8; nt++)
        acc[nt] = __builtin_amdgcn_mfma_f32_16x16x32_fp8_fp8(a3, wfrag[(3 * 8 + nt) * 64 + lane], acc[nt], 0, 0, 0);
    __syncthreads();

    ushort_t* ss = (ushort_t*)smem + wv * 16 * STG_S;
#pragma unroll
    for (int nt = 0; nt < 8; nt++)
#pragma unroll
        for (int rg = 0; rg < 4; rg++)
            ss[(q * 4 + rg) * STG_S + nt * 16 + r] = f2b(acc[nt][rg] * UNSCALE);

    const uint4* sp = (const uint4*)(ss + el * STG_S + qq * 32);
    uchar_t* Cp = (m == 0) ? C0 : (m == 1) ? C1 : C2;
    unsigned int ob[8];
#pragma unroll
    for (int cc = 0; cc < 4; cc++) {
        uint4 v = sp[cc];
        ob[cc * 2] = pk8(blo(v.x) * HSCALE, bhi(v.x) * HSCALE,
                         blo(v.y) * HSCALE, bhi(v.y) * HSCALE);
        ob[cc * 2 + 1] = pk8(blo(v.z) * HSCALE, bhi(v.z) * HSCALE,
                             blo(v.w) * HSCALE, bhi(v.w) * HSCALE);
    }
    uint4* cp = (uint4*)(Cp + (row + el) * DIM + qq * 32);
    cp[0] = make_uint4(ob[0], ob[1], ob[2], ob[3]);
    cp[1] = make_uint4(ob[4], ob[5], ob[6], ob[7]);
}

// single-W with bias + relu (final Wf): h fp8 in, fp32 out
__global__ __launch_bounds__(256) void node_gemm1(
    const uchar_t* __restrict__ A, const float* __restrict__ W,
    const float* __restrict__ bias, float* __restrict__ C) {
    __shared__ float As[64 * 128];
    __shared__ uint2 Ws4[128 * 32];
    int tid = threadIdx.x;
    size_t row0 = (size_t)blockIdx.x * 64;
    const unsigned int* Ag = (const unsigned int*)(A + row0 * DIM);
    for (int f = tid; f < 64 * 32; f += 256) {
        int v = (int)Ag[f];
        ((float4*)As)[f] = make_float4(cvt8<0>(v) * HUNSCALE, cvt8<1>(v) * HUNSCALE,
                                       cvt8<2>(v) * HUNSCALE, cvt8<3>(v) * HUNSCALE);
    }
    const float4* Wg = (const float4*)W;
    for (int i = tid; i < 128 * 32; i += 256) Ws4[i] = pack4(Wg[i]);
    __syncthreads();
    int cq = tid & 31, r0 = (tid >> 5) * 8, c0 = cq * 4;
    float acc[8][4] = {};
    for (int k = 0; k < 128; k++) {
        uint2 wp = Ws4[k * 32 + cq];
        float w0 = blo(wp.x), w1 = bhi(wp.x), w2 = blo(wp.y), w3 = bhi(wp.y);
#pragma unroll
        for (int i = 0; i < 8; i++) {
            float a = As[(r0 + i) * 128 + k];
            acc[i][0] += a * w0; acc[i][1] += a * w1;
            acc[i][2] += a * w2; acc[i][3] += a * w3;
        }
    }
    float b0 = bias[c0], b1 = bias[c0 + 1], b2v = bias[c0 + 2], b3v = bias[c0 + 3];
#pragma unroll
    for (int i = 0; i < 8; i++) {
        *(float4*)&C[(row0 + r0 + i) * DIM + c0] =
            make_float4(fmaxf(acc[i][0] + b0, 0.f), fmaxf(acc[i][1] + b1, 0.f),
                        fmaxf(acc[i][2] + b2v, 0.f), fmaxf(acc[i][3] + b3v, 0.f));
    }
}

// ---------------- fp8 MFMA edge GEMM (layers 1..7); stores exp(score) ----------------
__global__ __launch_bounds__(256, 4) void edge_gemm_fp8(
    uchar_t* __restrict__ e,
    const uchar_t* __restrict__ fni, const uchar_t* __restrict__ fnj,
    const int* __restrict__ psrc, const int* __restrict__ pdst,
    const uchar_t* __restrict__ Wf,
    const float* __restrict__ attn, const float* __restrict__ bias,
    float* __restrict__ escore) {
    __shared__ __align__(16) char smem[4 * 16 * STG_S * 2];  // 17408 B; W uses first 16384

    int tid = threadIdx.x;
    int wv = tid >> 6, lane = tid & 63;
    int r = lane & 15, q = lane >> 4;
    int el = lane >> 2, qq = lane & 3;
    size_t row = (size_t)blockIdx.x * 64 + 16 * wv;
    size_t eid = row + el;

    int sv = psrc[eid], dv = pdst[eid];

    const uchar_t* aRow = e + (row + r) * DIM + q * 8;
    long long a0 = *(const long long*)(aRow);
    long long a1 = *(const long long*)(aRow + 32);
    long long a2 = *(const long long*)(aRow + 64);
    long long a3 = *(const long long*)(aRow + 96);

    {
        const uint4* wg = (const uint4*)Wf;
        uint4* ws = (uint4*)smem;
        for (int i = tid; i < 1024; i += 256) ws[i] = wg[i];
    }
    __syncthreads();

    f32x4 acc[8] = {};
    const long long* wfrag = (const long long*)smem;
#pragma unroll
    for (int nt = 0; nt < 8; nt++)
        acc[nt] = __builtin_amdgcn_mfma_f32_16x16x32_fp8_fp8(a0, wfrag[(0 * 8 + nt) * 64 + lane], acc[nt], 0, 0, 0);
#pragma unroll
    for (int nt = 0; nt < 8; nt++)
        acc[nt] = __builtin_amdgcn_mfma_f32_16x16x32_fp8_fp8(a1, wfrag[(1 * 8 + nt) * 64 + lane], acc[nt], 0, 0, 0);
#pragma unroll
    for (int nt = 0; nt < 8; nt++)
        acc[nt] = __builtin_amdgcn_mfma_f32_16x16x32_fp8_fp8(a2, wfrag[(2 * 8 + nt) * 64 + lane], acc[nt], 0, 0, 0);
#pragma unroll
    for (int nt = 0; nt < 8; nt++)
        acc[nt] = __builtin_amdgcn_mfma_f32_16x16x32_fp8_fp8(a3, wfrag[(3 * 8 + nt) * 64 + lane], acc[nt], 0, 0, 0);
    __syncthreads();  // W reads done -> staging overlay

    ushort_t* ss = (ushort_t*)smem + wv * 16 * STG_S;
#pragma unroll
    for (int nt = 0; nt < 8; nt++)
#pragma unroll
        for (int rg = 0; rg < 4; rg++)
            ss[(q * 4 + rg) * STG_S + nt * 16 + r] = f2b(acc[nt][rg] * UNSCALE);

    unsigned int niw[8], njw[8];
    {
        const uint4* nip = (const uint4*)(fni + (size_t)sv * DIM + qq * 32);
        const uint4* njp = (const uint4*)(fnj + (size_t)dv * DIM + qq * 32);
        *(uint4*)&niw[0] = nip[0]; *(uint4*)&niw[4] = nip[1];
        *(uint4*)&njw[0] = njp[0]; *(uint4*)&njw[4] = njp[1];
    }
    const uint4* sp = (const uint4*)(ss + el * STG_S + qq * 32);
    unsigned int outb[8];
    float p = 0.f;
#pragma unroll
    for (int cc = 0; cc < 4; cc++) {
        uint4 avq = sp[cc];
        int wlo_i = (int)niw[cc * 2], whi_i = (int)niw[cc * 2 + 1];
        int wlo_j = (int)njw[cc * 2], whi_j = (int)njw[cc * 2 + 1];
        float niv[8], njv[8];
        niv[0] = cvt8<0>(wlo_i); niv[1] = cvt8<1>(wlo_i);
        niv[2] = cvt8<2>(wlo_i); niv[3] = cvt8<3>(wlo_i);
        niv[4] = cvt8<0>(whi_i); niv[5] = cvt8<1>(whi_i);
        niv[6] = cvt8<2>(whi_i); niv[7] = cvt8<3>(whi_i);
        njv[0] = cvt8<0>(wlo_j); njv[1] = cvt8<1>(wlo_j);
        njv[2] = cvt8<2>(wlo_j); njv[3] = cvt8<3>(wlo_j);
        njv[4] = cvt8<0>(whi_j); njv[5] = cvt8<1>(whi_j);
        njv[6] = cvt8<2>(whi_j); njv[7] = cvt8<3>(whi_j);
        float vv[8];
#pragma unroll
        for (int u = 0; u < 4; u++) {
            unsigned int aw = ((const unsigned int*)&avq)[u];
            int c = qq * 32 + cc * 8 + u * 2;
            float v0 = blo(aw) + (niv[u * 2] + njv[u * 2]) * HUNSCALE + bias[c];
            float v1 = bhi(aw) + (niv[u * 2 + 1] + njv[u * 2 + 1]) * HUNSCALE + bias[c + 1];
            v0 = v0 > 0.f ? v0 : 0.01f * v0;
            v1 = v1 > 0.f ? v1 : 0.01f * v1;
            vv[u * 2] = v0; vv[u * 2 + 1] = v1;
            p += v0 * attn[c] + v1 * attn[c + 1];
        }
        outb[cc * 2] = pk8(vv[0] * ESCALE, vv[1] * ESCALE, vv[2] * ESCALE, vv[3] * ESCALE);
        outb[cc * 2 + 1] = pk8(vv[4] * ESCALE, vv[5] * ESCALE, vv[6] * ESCALE, vv[7] * ESCALE);
    }
    uint4* ep = (uint4*)(e + eid * DIM + qq * 32);
    ep[0] = make_uint4(outb[0], outb[1], outb[2], outb[3]);
    ep[1] = make_uint4(outb[4], outb[5], outb[6], outb[7]);
    p += __shfl_xor(p, 1);
    p += __shfl_xor(p, 2);
    if (qq == 0) escore[eid] = __expf(p);
}

// ---------------- layer-0 edge kernel: E*16 threads, 8 cols each ----------------
__global__ __launch_bounds__(256) void edge0(
    const int* __restrict__ ptok, const float* __restrict__ eftab,
    const uchar_t* __restrict__ fni, const uchar_t* __restrict__ fnj,
    const int* __restrict__ psrc, const int* __restrict__ pdst,
    const float* __restrict__ attn, const float* __restrict__ bias,
    uchar_t* __restrict__ e, float* __restrict__ escore) {
    unsigned int gid = blockIdx.x * 256 + threadIdx.x;  // E*16 threads
    unsigned int eid = gid >> 4;
    int cq = gid & 15, c0 = cq * 8;
    int tok = ptok[eid];
    int sv = psrc[eid], dv = pdst[eid];
    float4 t0 = *(const float4*)&eftab[tok * DIM + c0];
    float4 t1 = *(const float4*)&eftab[tok * DIM + c0 + 4];
    uint2 niw = *(const uint2*)(fni + (size_t)sv * DIM + c0);
    uint2 njw = *(const uint2*)(fnj + (size_t)dv * DIM + c0);
    float v0 = t0.x + (cvt8<0>((int)niw.x) + cvt8<0>((int)njw.x)) * HUNSCALE + bias[c0];
    float v1 = t0.y + (cvt8<1>((int)niw.x) + cvt8<1>((int)njw.x)) * HUNSCALE + bias[c0 + 1];
    float v2 = t0.z + (cvt8<2>((int)niw.x) + cvt8<2>((int)njw.x)) * HUNSCALE + bias[c0 + 2];
    float v3 = t0.w + (cvt8<3>((int)niw.x) + cvt8<3>((int)njw.x)) * HUNSCALE + bias[c0 + 3];
    float v4 = t1.x + (cvt8<0>((int)niw.y) + cvt8<0>((int)njw.y)) * HUNSCALE + bias[c0 + 4];
    float v5 = t1.y + (cvt8<1>((int)niw.y) + cvt8<1>((int)njw.y)) * HUNSCALE + bias[c0 + 5];
    float v6 = t1.z + (cvt8<2>((int)niw.y) + cvt8<2>((int)njw.y)) * HUNSCALE + bias[c0 + 6];
    float v7 = t1.w + (cvt8<3>((int)niw.y) + cvt8<3>((int)njw.y)) * HUNSCALE + bias[c0 + 7];
    v0 = v0 > 0.f ? v0 : 0.01f * v0;
    v1 = v1 > 0.f ? v1 : 0.01f * v1;
    v2 = v2 > 0.f ? v2 : 0.01f * v2;
    v3 = v3 > 0.f ? v3 : 0.01f * v3;
    v4 = v4 > 0.f ? v4 : 0.01f * v4;
    v5 = v5 > 0.f ? v5 : 0.01f * v5;
    v6 = v6 > 0.f ? v6 : 0.01f * v6;
    v7 = v7 > 0.f ? v7 : 0.01f * v7;
    uint2 ow;
    ow.x = pk8(v0 * ESCALE, v1 * ESCALE, v2 * ESCALE, v3 * ESCALE);
    ow.y = pk8(v4 * ESCALE, v5 * ESCALE, v6 * ESCALE, v7 * ESCALE);
    *(uint2*)(e + (size_t)eid * DIM + c0) = ow;
    float p = v0 * attn[c0] + v1 * attn[c0 + 1] + v2 * attn[c0 + 2] + v3 * attn[c0 + 3] +
              v4 * attn[c0 + 4] + v5 * attn[c0 + 5] + v6 * attn[c0 + 6] + v7 * attn[c0 + 7];
#pragma unroll
    for (int o = 1; o < 16; o <<= 1) p += __shfl_xor(p, o);
    if (cq == 0) escore[eid] = __expf(p);
}

// ---------------- wave-per-node aggregation: single escore load for deg<=64 ----------------
__global__ __launch_bounds__(256) void agg_wave(
    const int* __restrict__ off, const int* __restrict__ psrc,
    const float* __restrict__ escore, const uchar_t* __restrict__ hs,
    uchar_t* __restrict__ h) {
    int node = blockIdx.x * 4 + (threadIdx.x >> 6);
    int lane = threadIdx.x & 63;
    int b0 = off[node];
    int deg = off[node + 1] - b0;

    // first-chunk escore value retained (deg<=64 common case: no re-read)
    float esc0 = (lane < deg) ? escore[b0 + lane] : 0.f;
    float se = esc0;
    for (int j = lane + 64; j < deg; j += 64) se += escore[b0 + j];
#pragma unroll
    for (int o = 32; o > 0; o >>= 1) se += __shfl_xor(se, o);
    float inv = (deg > 0) ? 1.f / se : 0.f;

    float acc0 = 0.f, acc1 = 0.f;
    for (int base = 0; base < deg; base += 64) {
        int cnt = min(64, deg - base);
        float wgt = 0.f;
        int sidx = 0;
        if (lane < cnt) {
            float ev = (base == 0) ? esc0 : escore[b0 + base + lane];
            wgt = ev * inv;
            sidx = psrc[b0 + base + lane];
        }
        int i = 0;
        for (; i + 4 <= cnt; i += 4) {
            float w0 = __shfl(wgt, i), w1 = __shfl(wgt, i + 1);
            float w2 = __shfl(wgt, i + 2), w3 = __shfl(wgt, i + 3);
            int s0 = __shfl(sidx, i), s1 = __shfl(sidx, i + 1);
            int s2 = __shfl(sidx, i + 2), s3 = __shfl(sidx, i + 3);
            int h0 = *(const ushort_t*)(hs + (size_t)s0 * DIM + lane * 2);
            int h1 = *(const ushort_t*)(hs + (size_t)s1 * DIM + lane * 2);
            int h2 = *(const ushort_t*)(hs + (size_t)s2 * DIM + lane * 2);
            int h3 = *(const ushort_t*)(hs + (size_t)s3 * DIM + lane * 2);
            acc0 += w0 * cvt8<0>(h0);
            acc1 += w0 * cvt8<1>(h0);
            acc0 += w1 * cvt8<0>(h1);
            acc1 += w1 * cvt8<1>(h1);
            acc0 += w2 * cvt8<0>(h2);
            acc1 += w2 * cvt8<1>(h2);
            acc0 += w3 * cvt8<0>(h3);
            acc1 += w3 * cvt8<1>(h3);
        }
        for (; i < cnt; i++) {
            float wi = __shfl(wgt, i);
            int si = __shfl(sidx, i);
            int hv = *(const ushort_t*)(hs + (size_t)si * DIM + lane * 2);
            acc0 += wi * cvt8<0>(hv);
            acc1 += wi * cvt8<1>(hv);
        }
    }
    int op = __builtin_amdgcn_cvt_pk_fp8_f32(fmaxf(acc0, 0.f), fmaxf(acc1, 0.f), 0, false);
    *(ushort_t*)(h + (size_t)node * DIM + lane * 2) = (ushort_t)(op & 0xffff);
}

// ---------------- wave bitonic sort of 128 features (no barriers) ----------------
__global__ __launch_bounds__(256) void sort_wave(const float* __restrict__ h2,
                                                 float* __restrict__ hsort,
                                                 float* __restrict__ maxval) {
    int node = blockIdx.x * 4 + (threadIdx.x >> 6);
    int lane = threadIdx.x & 63;
    float x0 = h2[(size_t)node * DIM + lane];
    float x1 = h2[(size_t)node * DIM + 64 + lane];
    for (int k = 2; k <= 128; k <<= 1) {
        for (int s = k >> 1; s >= 1; s >>= 1) {
            bool d0 = ((lane & k) == 0);
            bool d1 = (((lane + 64) & k) == 0);
            if (s == 64) {
                float mn = fminf(x0, x1), mx = fmaxf(x0, x1);
                x0 = d0 ? mn : mx;
                x1 = d0 ? mx : mn;
            } else {
                bool low = ((lane & s) == 0);
                float y0 = __shfl_xor(x0, s);
                float y1 = __shfl_xor(x1, s);
                float mn0 = fminf(x0, y0), mx0 = fmaxf(x0, y0);
                float mn1 = fminf(x1, y1), mx1 = fmaxf(x1, y1);
                x0 = (low == d0) ? mn0 : mx0;
                x1 = (low == d1) ? mn1 : mx1;
            }
        }
    }
    hsort[(size_t)node * DIM + lane] = x0;
    hsort[(size_t)node * DIM + 64 + lane] = x1;
    if (lane == 63) maxval[node] = x1;
}

// ---------------- per-graph top-k + gather pooled rows ----------------
__global__ __launch_bounds__(256) void topk_pool(const float* __restrict__ maxval,
                                                 const float* __restrict__ hsort,
                                                 float* __restrict__ pooled) {
    __shared__ float v[256];
    __shared__ int id[256];
    int b = blockIdx.x, t = threadIdx.x;
    v[t] = (t < NPG) ? maxval[b * NPG + t] : -1e30f;
    id[t] = t;
    __syncthreads();
    for (int k = 2; k <= 256; k <<= 1) {
        for (int j = k >> 1; j > 0; j >>= 1) {
            int ixj = t ^ j;
            float va = v[t], vb = v[ixj];
            int ia = id[t], ib = id[ixj];
            __syncthreads();
            bool dirDesc = ((t & k) == 0);
            bool cmp = (va > vb) || (va == vb && ia < ib);
            bool takeMine = ((t < ixj) == (dirDesc == cmp));
            v[t] = takeMine ? va : vb;
            id[t] = takeMine ? ia : ib;
            __syncthreads();
        }
    }
    for (int i = t; i < KPOOL * DIM; i += 256) {
        int kk = i >> 7, d = i & 127;
        pooled[((size_t)b * KPOOL + kk) * DIM + d] = hsort[((size_t)b * NPG + id[kk]) * DIM + d];
    }
}

// ---------------- ft split-K ----------------
__global__ __launch_bounds__(256) void ft_partial(
    const float* __restrict__ pooled, const float* __restrict__ W3,
    float* __restrict__ part) {
    __shared__ float ps[512];
    __shared__ float red[256];
    int b = blockIdx.x, s = blockIdx.y;
    int t = threadIdx.x;
    int d = t & 127, half = t >> 7;
    for (int i = t; i < 512; i += 256) ps[i] = pooled[(size_t)b * 4096 + s * 512 + i];
    __syncthreads();
    float acc = 0.f;
    const float* Wp = W3 + (size_t)(s * 512 + half * 256) * DIM + d;
    const float* pp = ps + half * 256;
#pragma unroll 4
    for (int kk = 0; kk < 256; kk++) acc += pp[kk] * Wp[(size_t)kk * DIM];
    red[t] = acc;
    __syncthreads();
    if (t < 128) part[((size_t)b * 8 + s) * DIM + t] = red[t] + red[t + 128];
}

__global__ __launch_bounds__(128) void ft_reduce(
    const float* __restrict__ part, const float* __restrict__ al3,
    const float* __restrict__ ar3, float* __restrict__ ft,
    float* __restrict__ sl, float* __restrict__ sr) {
    __shared__ float r1[128], r2[128];
    int b = blockIdx.x, d = threadIdx.x;
    float acc = 0.f;
#pragma unroll
    for (int s = 0; s < 8; s++) acc += part[((size_t)b * 8 + s) * DIM + d];
    ft[b * DIM + d] = acc;
    r1[d] = acc * al3[d];
    r2[d] = acc * ar3[d];
    __syncthreads();
    for (int s = 64; s > 0; s >>= 1) {
        if (d < s) { r1[d] += r1[d + s]; r2[d] += r2[d + s]; }
        __syncthreads();
    }
    if (d == 0) { sl[b] = r1[0]; sr[b] = r2[0]; }
}

// ---------------- final-graph GAT ----------------
__global__ __launch_bounds__(128) void fg_kernel(
    const int* __restrict__ fg_src, const int* __restrict__ fg_dst,
    const float* __restrict__ sl, const float* __restrict__ sr,
    const float* __restrict__ ft, const float* __restrict__ b3,
    float* __restrict__ g) {
    __shared__ int list[EFE];
    __shared__ float wgt[EFE];
    __shared__ float red[128];
    __shared__ int cnt;
    int b = blockIdx.x, t = threadIdx.x;
    if (t == 0) cnt = 0;
    __syncthreads();
    for (int e = t; e < EFE; e += 128)
        if (fg_dst[e] == b) { int p = atomicAdd(&cnt, 1); list[p] = e; }
    __syncthreads();
    int deg = cnt;
    float srb = sr[b];
    float m = -1e30f;
    for (int j = t; j < deg; j += 128) {
        float s = sl[fg_src[list[j]]] + srb;
        s = s > 0.f ? s : 0.2f * s;
        m = fmaxf(m, s);
    }
    red[t] = m;
    __syncthreads();
    for (int s = 64; s > 0; s >>= 1) { if (t < s) red[t] = fmaxf(red[t], red[t + s]); __syncthreads(); }
    m = red[0];
    __syncthreads();
    float se = 0.f;
    for (int j = t; j < deg; j += 128) {
        float s = sl[fg_src[list[j]]] + srb;
        s = s > 0.f ? s : 0.2f * s;
        se += __expf(s - m);
    }
    red[t] = se;
    __syncthreads();
    for (int s = 64; s > 0; s >>= 1) { if (t < s) red[t] += red[t + s]; __syncthreads(); }
    float inv = (deg > 0) ? 1.f / red[0] : 0.f;
    __syncthreads();
    for (int j = t; j < deg; j += 128) {
        float s = sl[fg_src[list[j]]] + srb;
        s = s > 0.f ? s : 0.2f * s;
        wgt[j] = __expf(s - m) * inv;
    }
    __syncthreads();
    float acc = 0.f;
    for (int j = 0; j < deg; j++) acc += wgt[j] * ft[(size_t)fg_src[list[j]] * DIM + t];
    g[b * DIM + t] = fmaxf(acc + b3[t], 0.f);
}

// ---------------- fused: g2 = relu(g @ Wl + bl); out = g2 @ Wc + bc ----------------
__global__ __launch_bounds__(128) void gl_out_kernel(const float* __restrict__ g,
                                                     const float* __restrict__ Wl,
                                                     const float* __restrict__ bl,
                                                     const float* __restrict__ Wc,
                                                     const float* __restrict__ bc,
                                                     float* __restrict__ out) {
    __shared__ float gs[128];
    __shared__ float r1[128], r2[128];
    int b = blockIdx.x, d = threadIdx.x;
    gs[d] = g[b * DIM + d];
    __syncthreads();
    float acc = 0.f;
    for (int k = 0; k < 128; k++) acc += gs[k] * Wl[k * DIM + d];
    float g2 = fmaxf(acc + bl[d], 0.f);
    r1[d] = g2 * Wc[d * 2];
    r2[d] = g2 * Wc[d * 2 + 1];
    __syncthreads();
    for (int s = 64; s > 0; s >>= 1) {
        if (d < s) { r1[d] += r1[d + s]; r2[d] += r2[d + s]; }
        __syncthreads();
    }
    if (d == 0) {
        out[b * 2] = r1[0] + bc[0];
        out[b * 2 + 1] = r2[0] + bc[1];
    }
}

extern "C" void kernel_launch(void* const* d_in, const int* in_sizes, int n_in,
                              void* d_out, int out_size, void* d_ws, size_t ws_size,
                              hipStream_t stream) {
    const int* tokens_h = (const int*)d_in[0];
    const int* tokens_e = (const int*)d_in[1];
    const int* src = (const int*)d_in[2];
    const int* dst = (const int*)d_in[3];
    const int* fg_src = (const int*)d_in[4];
    const int* fg_dst = (const int*)d_in[5];
    const float* token_emb = (const float*)d_in[6];
    const float* e_token_emb = (const float*)d_in[7];
    const float* W_ni = (const float*)d_in[8];
    const float* W_nj = (const float*)d_in[9];
    const float* W_fij = (const float*)d_in[10];
    const float* W_node = (const float*)d_in[11];
    const float* attn_e = (const float*)d_in[12];
    const float* bias_e = (const float*)d_in[13];
    const float* Wf = (const float*)d_in[14];
    const float* bf_ = (const float*)d_in[15];
    const float* W3 = (const float*)d_in[16];
    const float* al3 = (const float*)d_in[17];
    const float* ar3 = (const float*)d_in[18];
    const float* b3 = (const float*)d_in[19];
    const float* Wl = (const float*)d_in[20];
    const float* bl = (const float*)d_in[21];
    const float* Wc = (const float*)d_in[22];
    const float* bc = (const float*)d_in[23];
    float* out = (float*)d_out;

    char* w = (char*)d_ws;
    auto alloc = [&](size_t b) -> char* {
        char* p = w;
        w += (b + 255) & ~(size_t)255;
        return p;
    };
    uchar_t* h = (uchar_t*)alloc((size_t)N_NODES * DIM);       // fp8 x16
    uchar_t* fni = (uchar_t*)alloc((size_t)N_NODES * DIM);     // fp8
    uchar_t* fnj = (uchar_t*)alloc((size_t)N_NODES * DIM);     // fp8
    uchar_t* hs = (uchar_t*)alloc((size_t)N_NODES * DIM);      // fp8
    uchar_t* e = (uchar_t*)alloc((size_t)N_EDGES * DIM);       // fp8
    float* escore = (float*)alloc((size_t)N_EDGES * 4);
    int* deg = (int*)alloc((size_t)N_NODES * 4);
    int* off = (int*)alloc((size_t)(N_NODES + 1) * 4);
    int* cursor = (int*)alloc((size_t)N_NODES * 4);
    int* bsum = (int*)alloc(64 * 4);
    int* psrc = (int*)alloc((size_t)N_EDGES * 4);
    int* pdst = (int*)alloc((size_t)N_EDGES * 4);
    int* ptok = (int*)alloc((size_t)N_EDGES * 4);
    float* eftab = (float*)alloc(100 * DIM * 4);
    float* maxval = (float*)alloc((size_t)N_NODES * 4);
    float* pooled = (float*)alloc((size_t)BGR * KPOOL * DIM * 4);
    float* ft = (float*)alloc(BGR * DIM * 4);
    float* part = (float*)alloc((size_t)BGR * 8 * DIM * 4);
    float* sl = (float*)alloc(BGR * 4);
    float* sr = (float*)alloc(BGR * 4);
    float* g = (float*)alloc(BGR * DIM * 4);
    uchar_t* Wf7 = (uchar_t*)alloc((size_t)NLAYERS * DIM * DIM);
    uchar_t* Wn = (uchar_t*)alloc((size_t)3 * NLAYERS * DIM * DIM);
    // h2/hsort (fp32, 13.1 MB each) live in the e region (52 MB) after the layer loop
    float* h2 = (float*)e;
    float* hsort = (float*)((char*)e + (size_t)16 * 1024 * 1024);

    // weight prep
    wfprep8<<<(NLAYERS * DIM * DIM) / 256, 256, 0, stream>>>(W_fij, Wf7);
    wnprep8<<<(3 * NLAYERS * DIM * DIM) / 256, 256, 0, stream>>>(W_ni, W_nj, W_node, Wn);

    // CSR build + edge permutation (dst-sorted order), hierarchical scan
    zero_deg<<<(N_NODES + 255) / 256, 256, 0, stream>>>(deg, N_NODES);
    count_deg<<<N_EDGES / 256, 256, 0, stream>>>(dst, deg, N_EDGES);
    scan_local<<<(N_NODES + 1023) / 1024, 1024, 0, stream>>>(deg, off, bsum, N_NODES);
    scan_add<<<(N_NODES + 255) / 256, 256, 0, stream>>>(off, bsum, cursor, N_NODES, N_EDGES);
    scatter_perm<<<N_EDGES / 256, 256, 0, stream>>>(src, dst, tokens_e, cursor,
                                                    psrc, pdst, ptok, N_EDGES);

    init_h<<<(N_NODES * DIM / 4) / 256, 256, 0, stream>>>(tokens_h, token_emb, h);
    eftab_kernel<<<100, 128, 0, stream>>>(e_token_emb, W_fij, eftab);

    for (int l = 0; l < NLAYERS; l++) {
        node_gemm_mfma<<<dim3(N_NODES / 64, 3), 256, 0, stream>>>(
            h, Wn + l * 16384, fni, fnj, hs);
        if (l == 0) {
            edge0<<<(N_EDGES * 16) / 256, 256, 0, stream>>>(
                ptok, eftab, fni, fnj, psrc, pdst, attn_e, bias_e, e, escore);
        } else {
            edge_gemm_fp8<<<N_EDGES / 64, 256, 0, stream>>>(
                e, fni, fnj, psrc, pdst, Wf7 + (size_t)l * DIM * DIM,
                attn_e + l * DIM, bias_e + l * DIM, escore);
        }
        agg_wave<<<N_NODES / 4, 256, 0, stream>>>(off, psrc, escore, hs, h);
    }

    node_gemm1<<<N_NODES / 64, 256, 0, stream>>>(h, Wf, bf_, h2);
    sort_wave<<<N_NODES / 4, 256, 0, stream>>>(h2, hsort, maxval);
    topk_pool<<<BGR, 256, 0, stream>>>(maxval, hsort, pooled);
    ft_partial<<<dim3(BGR, 8), 256, 0, stream>>>(pooled, W3, part);
    ft_reduce<<<BGR, 128, 0, stream>>>(part, al3, ar3, ft, sl, sr);
    fg_kernel<<<BGR, 128, 0, stream>>>(fg_src, fg_dst, sl, sr, ft, b3, g);
    gl_out_kernel<<<BGR, 128, 0, stream>>>(g, Wl, bl, Wc, bc, out);
}